// Round 9
// baseline (1768.877 us; speedup 1.0000x reference)
//
#include <hip/hip_runtime.h>
#include <hip/hip_bf16.h>
#include <math.h>

typedef __hip_bfloat16 bf16;
typedef __attribute__((ext_vector_type(8))) short bf16x8;   // MFMA A/B frag (8 bf16)
typedef __attribute__((ext_vector_type(4))) float f32x4;    // MFMA C/D frag

// Problem constants
#define Bsz 4
#define Lseq 2048
#define DM 256       // d_model == per-head D
#define HH 8
#define HD 2048      // H * DM
#define DFF 1024
#define SK 40
#define NTOP 5
#define MROWS 8192   // B * L
#define NBT (Bsz * HH * NTOP)   // 160
#define NCHUNK 8

// ---------------------------------------------------------------------------
// Static device scratch. __align__(256) REQUIRED (float4 casts).
__device__ __align__(256) float g_X  [MROWS * DM];    //   8 MB activations
__device__ __align__(256) float g_TMP[MROWS * DM];    //   8 MB residual accum
__device__ __align__(256) float g_Q  [MROWS * HD];    //  64 MB all-head Q (fp32: selection path)
__device__ __align__(256) float g_K  [MROWS * HD];    //  64 MB all-head K (fp32: selection path)
__device__ __align__(256) float g_V  [MROWS * HD];    //  64 MB all-head V
__device__ __align__(256) float g_HF [MROWS * DFF];   //  32 MB FFN hidden
__device__ __align__(256) float g_MB [Bsz * HH * Lseq];
__device__ __align__(256) float g_SC [NBT * Lseq];
__device__ __align__(256) float g_CTXP[NBT * NCHUNK * DM];
__device__ __align__(256) int   g_MTOP[NBT];

__device__ __forceinline__ float ld(const float* p, size_t i) { return p[i]; }
__device__ __forceinline__ float ld(const bf16* p, size_t i) { return __bfloat162float(p[i]); }
__device__ __forceinline__ void st(float* p, size_t i, float v) { p[i] = v; }
__device__ __forceinline__ void st(bf16* p, size_t i, float v) { p[i] = __float2bfloat16(v); }
__device__ __forceinline__ short f2bf(float v) {
    union { bf16 h; short s; } u; u.h = __float2bfloat16(v); return u.s;
}

// ---------------------------------------------------------------------------
// fp32 tiled GEMM, 128x128 tile, BK=16, 8x8 per thread, 256 threads.
// Round-9: bigger tile halves staged bytes/FLOP vs 128x64. Per-thread
// k-ascending accumulation order identical to rounds 5-8 (selection-safe).
template<typename TA, typename TC, bool GELU, bool RES>
__device__ __forceinline__ void gemm_body(
    const TA* __restrict__ A, const float* __restrict__ W,
    const float* __restrict__ bias, const float* __restrict__ res,
    TC* __restrict__ C, int K, int ldw, int ldc, int bx, int by)
{
    const int BM = 128, BN = 128, BK = 16;
    __shared__ __align__(16) float As[BK][BM + 4];
    __shared__ __align__(16) float Bs[BK][BN];
    int tid = threadIdx.x;
    int tx = tid & 15, ty = tid >> 4;
    int row0 = by * BM, col0 = bx * BN;
    float acc[8][8] = {};
    for (int k0 = 0; k0 < K; k0 += BK) {
        #pragma unroll
        for (int i = 0; i < 8; i++) {                // stage A: 128x16
            int idx = tid + i * 256;
            int r = idx >> 4, c = idx & 15;
            As[c][r] = ld(A, (size_t)(row0 + r) * K + k0 + c);
        }
        #pragma unroll
        for (int i = 0; i < 8; i++) {                // stage B: 16x128
            int idx = tid + i * 256;
            int r = idx >> 7, c = idx & 127;
            Bs[r][c] = W[(size_t)(k0 + r) * ldw + col0 + c];
        }
        __syncthreads();
        #pragma unroll
        for (int kk = 0; kk < BK; kk++) {
            float4 a0 = *(const float4*)&As[kk][ty * 8];
            float4 a1 = *(const float4*)&As[kk][ty * 8 + 4];
            float4 b0 = *(const float4*)&Bs[kk][tx * 8];
            float4 b1 = *(const float4*)&Bs[kk][tx * 8 + 4];
            float av[8] = {a0.x, a0.y, a0.z, a0.w, a1.x, a1.y, a1.z, a1.w};
            float bv[8] = {b0.x, b0.y, b0.z, b0.w, b1.x, b1.y, b1.z, b1.w};
            #pragma unroll
            for (int i = 0; i < 8; i++)
                #pragma unroll
                for (int j = 0; j < 8; j++) acc[i][j] += av[i] * bv[j];
        }
        __syncthreads();
    }
    #pragma unroll
    for (int i = 0; i < 8; i++) {
        int r = row0 + ty * 8 + i;
        #pragma unroll
        for (int j = 0; j < 8; j++) {
            int c = col0 + tx * 8 + j;
            float v = acc[i][j] + bias[c];
            if (RES) v += res[(size_t)r * ldc + c];
            if (GELU) v = 0.5f * v * (1.0f + erff(v * 0.70710678118654752440f));
            st(C, (size_t)r * ldc + c, v);
        }
    }
}

__global__ __launch_bounds__(256) void emb_gemm(const float* __restrict__ A,
                                                const float* __restrict__ W,
                                                const float* __restrict__ bias) {
    gemm_body<float, float, false, false>(A, W, bias, nullptr, g_X, 32, DM, DM,
                                          blockIdx.x, blockIdx.y);
}

// Q and K only (z in {0,1}) — fp32, selection path.
__global__ __launch_bounds__(256) void qk_gemm(
    const float* __restrict__ Wq, const float* __restrict__ Wk,
    const float* __restrict__ bq, const float* __restrict__ bk)
{
    int z = blockIdx.z;
    const float* W  = z ? Wk : Wq;
    const float* bb = z ? bk : bq;
    float* C = z ? g_K : g_Q;
    gemm_body<float, float, false, false>(g_X, W, bb, nullptr, C, DM, HD, HD,
                                          blockIdx.x, blockIdx.y);
}

// ---------------------------------------------------------------------------
// bf16 MFMA GEMM (V / FFN paths only — smooth numerics): 128x128 tile, BK=32,
// 4 waves (2x2 of 64x64), mfma_f32_16x16x32_bf16, fp32 accum.
template<typename TC, bool GELU, bool RES>
__device__ __forceinline__ void mf_gemm_body(
    const float* __restrict__ A, const float* __restrict__ W,
    const float* __restrict__ bias, const float* __restrict__ res,
    TC* __restrict__ C, int K, int ldw, int ldc, int bx, int by)
{
    __shared__ __align__(16) short As[128][40];
    __shared__ __align__(16) short Bs[128][40];
    int tid = threadIdx.x;
    int wid = tid >> 6, lane = tid & 63;
    int wm = wid >> 1, wn = wid & 1;
    int quad = lane >> 4, l16 = lane & 15;
    int row0 = by * 128, col0 = bx * 128;
    f32x4 acc[4][4] = {};
    for (int k0 = 0; k0 < K; k0 += 32) {
        int ar = tid >> 3, ac = (tid & 7) * 4;
        #pragma unroll
        for (int i = 0; i < 4; i++) {
            float4 v = *(const float4*)&A[(size_t)(row0 + ar + i * 32) * K + k0 + ac];
            short4 s4 = {f2bf(v.x), f2bf(v.y), f2bf(v.z), f2bf(v.w)};
            *(short4*)&As[ar + i * 32][ac] = s4;
        }
        int bk = tid >> 5, bn = (tid & 31) * 4;
        #pragma unroll
        for (int i = 0; i < 4; i++) {
            int kk = bk + i * 8;
            float4 v = *(const float4*)&W[(size_t)(k0 + kk) * ldw + col0 + bn];
            Bs[bn + 0][kk] = f2bf(v.x);
            Bs[bn + 1][kk] = f2bf(v.y);
            Bs[bn + 2][kk] = f2bf(v.z);
            Bs[bn + 3][kk] = f2bf(v.w);
        }
        __syncthreads();
        bf16x8 af[4], bf_[4];
        #pragma unroll
        for (int mt = 0; mt < 4; mt++)
            af[mt] = *(const bf16x8*)&As[wm * 64 + mt * 16 + l16][quad * 8];
        #pragma unroll
        for (int nt = 0; nt < 4; nt++)
            bf_[nt] = *(const bf16x8*)&Bs[wn * 64 + nt * 16 + l16][quad * 8];
        #pragma unroll
        for (int mt = 0; mt < 4; mt++)
            #pragma unroll
            for (int nt = 0; nt < 4; nt++)
                acc[mt][nt] = __builtin_amdgcn_mfma_f32_16x16x32_bf16(
                    af[mt], bf_[nt], acc[mt][nt], 0, 0, 0);
        __syncthreads();
    }
    #pragma unroll
    for (int mt = 0; mt < 4; mt++) {
        #pragma unroll
        for (int nt = 0; nt < 4; nt++) {
            int col = col0 + wn * 64 + nt * 16 + l16;
            float bv = bias[col];
            #pragma unroll
            for (int r = 0; r < 4; r++) {
                int row = row0 + wm * 64 + mt * 16 + quad * 4 + r;
                float v = acc[mt][nt][r] + bv;
                if (RES) v += res[(size_t)row * ldc + col];
                if (GELU) v = 0.5f * v * (1.0f + erff(v * 0.70710678118654752440f));
                st(C, (size_t)row * ldc + col, v);
            }
        }
    }
}

__global__ __launch_bounds__(256) void v_mf(const float* __restrict__ W,
                                            const float* __restrict__ bias) {
    mf_gemm_body<float, false, false>(g_X, W, bias, nullptr, g_V, DM, HD, HD,
                                      blockIdx.x, blockIdx.y);
}
__global__ __launch_bounds__(256) void ffn1_mf(const float* __restrict__ W,
                                               const float* __restrict__ bias) {
    mf_gemm_body<float, true, false>(g_X, W, bias, nullptr, g_HF, DM, DFF, DFF,
                                     blockIdx.x, blockIdx.y);
}
__global__ __launch_bounds__(256) void ffn2_mf(const float* __restrict__ W,
                                               const float* __restrict__ bias) {
    mf_gemm_body<float, false, true>(g_HF, W, bias, g_X, g_TMP, DFF, DM, DM,
                                     blockIdx.x, blockIdx.y);
}

// ---------------------------------------------------------------------------
// Sampled scores + sparsity M, all heads. One wave per (b,h,l).
// Round-9: LANE-PER-SAMPLE. Lane u<40 owns sample u: full 256-dim dot with
// 64 sequential dwordx4 loads (unroll 8 -> 8 in flight), Q row via LDS
// broadcast. No mid-loop shuffles; one 6-step reduction at the end.
__global__ __launch_bounds__(256) void sampm_kernel(const int* __restrict__ idx)
{
    __shared__ __align__(16) float qs[4][DM];
    int wly = threadIdx.x >> 6;
    int lane = threadIdx.x & 63;
    int wid = blockIdx.x * 4 + wly;                  // (b*H+h)*L + l
    int l = wid & (Lseq - 1);
    int bh = wid >> 11;
    int b = bh >> 3, h = bh & 7;
    const float4* qrow = (const float4*)(g_Q + ((size_t)(b * Lseq + l)) * HD + h * DM);
    ((float4*)qs[wly])[lane] = qrow[lane];
    __syncthreads();
    float dot = 0.f;
    bool active = lane < SK;
    if (active) {
        int s = idx[l * SK + lane] & (Lseq - 1);
        const float4* krow = (const float4*)(g_K + ((size_t)(b * Lseq + s)) * HD + h * DM);
        const float4* qq = (const float4*)qs[wly];
        #pragma unroll 8
        for (int d4 = 0; d4 < DM / 4; d4++) {
            float4 kf = krow[d4];
            float4 qf = qq[d4];
            dot += qf.x * kf.x + qf.y * kf.y + qf.z * kf.z + qf.w * kf.w;
        }
    }
    float mx = active ? dot : -INFINITY;
    float sm = active ? dot : 0.f;
    #pragma unroll
    for (int off = 32; off > 0; off >>= 1) {
        mx = fmaxf(mx, __shfl_xor(mx, off, 64));
        sm += __shfl_xor(sm, off, 64);
    }
    if (lane == 0) g_MB[wid] = mx - sm * (1.0f / (float)Lseq);
}

// ---------------------------------------------------------------------------
// Top-5 per (b,h): grid 32. 5 masked argmax passes (ties -> lower index).
__global__ __launch_bounds__(256) void topk_kernel(int dummy)
{
    (void)dummy;
    __shared__ float vals[Lseq];
    __shared__ float rv[256];
    __shared__ int ri[256];
    int bh = blockIdx.x, tid = threadIdx.x;
    for (int i = tid; i < Lseq; i += 256) vals[i] = g_MB[bh * Lseq + i];
    __syncthreads();
    for (int t = 0; t < NTOP; t++) {
        float bv = -INFINITY; int bi = Lseq - 1;
        for (int i = tid; i < Lseq; i += 256) {
            float v = vals[i];
            if (v > bv || (v == bv && i < bi)) { bv = v; bi = i; }
        }
        rv[tid] = bv; ri[tid] = bi;
        __syncthreads();
        for (int s = 128; s > 0; s >>= 1) {
            if (tid < s) {
                float ov = rv[tid + s]; int oi = ri[tid + s];
                if (ov > rv[tid] || (ov == rv[tid] && oi < ri[tid])) { rv[tid] = ov; ri[tid] = oi; }
            }
            __syncthreads();
        }
        if (tid == 0) { g_MTOP[bh * NTOP + t] = ri[0]; vals[ri[0] & (Lseq - 1)] = -INFINITY; }
        __syncthreads();
    }
}

// ---------------------------------------------------------------------------
// Scores for top queries: grid (NBT, NCHUNK). Thread = one key.
__global__ __launch_bounds__(256) void attn_scores(int dummy)
{
    (void)dummy;
    __shared__ __align__(16) float qs[DM];
    int bt = blockIdx.x, chunk = blockIdx.y, tid = threadIdx.x;
    int bh = bt / NTOP;
    int b = bh >> 3, h = bh & 7;
    int l = g_MTOP[bt] & (Lseq - 1);
    qs[tid] = g_Q[((size_t)(b * Lseq + l)) * HD + h * DM + tid];
    __syncthreads();
    int j = chunk * 256 + tid;
    const float4* krow = (const float4*)(g_K + ((size_t)(b * Lseq + j)) * HD + h * DM);
    float acc = 0.f;
    for (int d4 = 0; d4 < DM / 4; d4++) {
        float4 kf = krow[d4];
        float4 qf = ((const float4*)qs)[d4];
        acc += qf.x * kf.x + qf.y * kf.y + qf.z * kf.z + qf.w * kf.w;
    }
    g_SC[(size_t)bt * Lseq + j] = acc;
}

// Softmax in place over g_SC row: grid NBT.
__global__ __launch_bounds__(256) void attn_softmax(int dummy)
{
    (void)dummy;
    __shared__ float sc[Lseq];
    __shared__ float red[256];
    int bt = blockIdx.x, tid = threadIdx.x;
    for (int i = tid; i < Lseq; i += 256) sc[i] = g_SC[(size_t)bt * Lseq + i];
    __syncthreads();
    float m = -INFINITY;
    for (int i = tid; i < Lseq; i += 256) m = fmaxf(m, sc[i]);
    red[tid] = m; __syncthreads();
    for (int s = 128; s > 0; s >>= 1) { if (tid < s) red[tid] = fmaxf(red[tid], red[tid + s]); __syncthreads(); }
    m = red[0]; __syncthreads();
    float sum = 0.f;
    for (int i = tid; i < Lseq; i += 256) { float e = expf(sc[i] - m); sc[i] = e; sum += e; }
    red[tid] = sum; __syncthreads();
    for (int s = 128; s > 0; s >>= 1) { if (tid < s) red[tid] += red[tid + s]; __syncthreads(); }
    float inv = 1.0f / red[0]; __syncthreads();
    for (int i = tid; i < Lseq; i += 256) g_SC[(size_t)bt * Lseq + i] = sc[i] * inv;
}

// Partial ctx over one key chunk: grid (NBT, NCHUNK). Thread = dim.
__global__ __launch_bounds__(256) void attn_ctx(int dummy)
{
    (void)dummy;
    __shared__ float ps[256];
    int bt = blockIdx.x, chunk = blockIdx.y, tid = threadIdx.x;
    int bh = bt / NTOP;
    int b = bh >> 3, h = bh & 7;
    int j0 = chunk * 256;
    ps[tid] = g_SC[(size_t)bt * Lseq + j0 + tid];
    __syncthreads();
    float accv = 0.f;
    const float* vbase = g_V + ((size_t)(b * Lseq + j0)) * HD + h * DM + tid;
    for (int j = 0; j < 256; j++) accv += ps[j] * vbase[(size_t)j * HD];
    g_CTXP[((size_t)bt * NCHUNK + chunk) * DM + tid] = accv;
}

// ---------------------------------------------------------------------------
// g_TMP = g_X + bo (broadcast)
__global__ __launch_bounds__(256) void add_bias_kernel(const float* __restrict__ bo)
{
    int i = blockIdx.x * 256 + threadIdx.x;
    g_TMP[i] = g_X[i] + bo[i & (DM - 1)];
}

// Reduce ctx partials, project through Wo_h, scatter-add: grid NBT.
__global__ __launch_bounds__(256) void scatter_kernel(const float* __restrict__ Wo_l)
{
    __shared__ float cs[DM];
    int bt = blockIdx.x, tid = threadIdx.x;
    int bh = bt / NTOP;
    int b = bh >> 3, h = bh & 7;
    float s = 0.f;
    #pragma unroll
    for (int c = 0; c < NCHUNK; c++) s += g_CTXP[((size_t)bt * NCHUNK + c) * DM + tid];
    cs[tid] = s;
    __syncthreads();
    int row = g_MTOP[bt] & (Lseq - 1);
    float acc = 0.f;
    const float* w = Wo_l + (size_t)h * DM * DM + tid;
    for (int d = 0; d < DM; d++) acc += cs[d] * w[(size_t)d * DM];
    atomicAdd(&g_TMP[((size_t)(b * Lseq) + row) * DM + tid], acc);
}

// ---------------------------------------------------------------------------
// LayerNorm g_TMP -> g_X, one wave per row of 256
__global__ __launch_bounds__(256) void ln_kernel(const float* __restrict__ g,
                                                 const float* __restrict__ bb)
{
    int wid = blockIdx.x * 4 + (threadIdx.x >> 6);
    if (wid >= MROWS) return;
    int lane = threadIdx.x & 63;
    const float4* row = (const float4*)(g_TMP + (size_t)wid * DM);
    float4 v = row[lane];
    float s = v.x + v.y + v.z + v.w;
    #pragma unroll
    for (int off = 32; off > 0; off >>= 1) s += __shfl_down(s, off, 64);
    s = __shfl(s, 0, 64);
    float mean = s * (1.f / DM);
    float4 d = {v.x - mean, v.y - mean, v.z - mean, v.w - mean};
    float q = d.x * d.x + d.y * d.y + d.z * d.z + d.w * d.w;
    #pragma unroll
    for (int off = 32; off > 0; off >>= 1) q += __shfl_down(q, off, 64);
    q = __shfl(q, 0, 64);
    float inv = rsqrtf(q * (1.f / DM) + 1e-5f);
    int c = lane * 4;
    float4 o;
    o.x = d.x * inv * g[c + 0] + bb[c + 0];
    o.y = d.y * inv * g[c + 1] + bb[c + 1];
    o.z = d.z * inv * g[c + 2] + bb[c + 2];
    o.w = d.w * inv * g[c + 3] + bb[c + 3];
    ((float4*)(g_X + (size_t)wid * DM))[lane] = o;
}

// ---------------------------------------------------------------------------
// Final: LN(nf) on row L-1 of each batch, dot with proj_W, + proj_b -> out[b]
__global__ __launch_bounds__(256) void final_kernel(
    const float* __restrict__ g, const float* __restrict__ bb,
    const float* __restrict__ pw, const float* __restrict__ pb,
    float* __restrict__ out)
{
    __shared__ float red[256];
    int b = blockIdx.x, tid = threadIdx.x;
    const float* row = g_X + ((size_t)(b * Lseq + Lseq - 1)) * DM;
    float v = row[tid];
    red[tid] = v; __syncthreads();
    for (int s = 128; s > 0; s >>= 1) { if (tid < s) red[tid] += red[tid + s]; __syncthreads(); }
    float mean = red[0] * (1.f / DM); __syncthreads();
    float d = v - mean;
    red[tid] = d * d; __syncthreads();
    for (int s = 128; s > 0; s >>= 1) { if (tid < s) red[tid] += red[tid + s]; __syncthreads(); }
    float var = red[0] * (1.f / DM); __syncthreads();
    float xn = d * rsqrtf(var + 1e-5f) * g[tid] + bb[tid];
    red[tid] = xn * pw[tid]; __syncthreads();
    for (int s = 128; s > 0; s >>= 1) { if (tid < s) red[tid] += red[tid + s]; __syncthreads(); }
    if (tid == 0) out[b] = red[0] + pb[0];
}

// ---------------------------------------------------------------------------
extern "C" void kernel_launch(void* const* d_in, const int* in_sizes, int n_in,
                              void* d_out, int out_size, void* d_ws, size_t ws_size,
                              hipStream_t stream)
{
    const float* x_enc = (const float*)d_in[0];
    const int*   isamp = (const int*)d_in[1];
    const float* emb_W = (const float*)d_in[2];
    const float* emb_b = (const float*)d_in[3];
    const float* Wq = (const float*)d_in[4];
    const float* bq = (const float*)d_in[5];
    const float* Wk = (const float*)d_in[6];
    const float* bk = (const float*)d_in[7];
    const float* Wv = (const float*)d_in[8];
    const float* bv = (const float*)d_in[9];
    const float* Wo = (const float*)d_in[10];
    const float* bo = (const float*)d_in[11];
    const float* c1W = (const float*)d_in[12];
    const float* c1b = (const float*)d_in[13];
    const float* c2W = (const float*)d_in[14];
    const float* c2b = (const float*)d_in[15];
    const float* ln1g = (const float*)d_in[16];
    const float* ln1b = (const float*)d_in[17];
    const float* ln2g = (const float*)d_in[18];
    const float* ln2b = (const float*)d_in[19];
    const float* nfg  = (const float*)d_in[20];
    const float* nfb  = (const float*)d_in[21];
    const float* projW = (const float*)d_in[22];
    const float* projb = (const float*)d_in[23];
    (void)d_ws; (void)ws_size; (void)in_sizes; (void)n_in; (void)out_size;

    dim3 blk(256);
    emb_gemm<<<dim3(DM / 128, MROWS / 128), blk, 0, stream>>>(x_enc, emb_W, emb_b);

    for (int l = 0; l < 2; l++) {
        const float* Wq_l = Wq + (size_t)l * DM * HD;
        const float* Wk_l = Wk + (size_t)l * DM * HD;
        const float* Wv_l = Wv + (size_t)l * DM * HD;
        const float* Wo_l = Wo + (size_t)l * HD * DM;

        qk_gemm<<<dim3(HD / 128, MROWS / 128, 2), blk, 0, stream>>>(
            Wq_l, Wk_l, bq + l * HD, bk + l * HD);
        v_mf<<<dim3(HD / 128, MROWS / 128), blk, 0, stream>>>(Wv_l, bv + l * HD);

        sampm_kernel<<<dim3(Bsz * HH * Lseq / 4), blk, 0, stream>>>(isamp);
        topk_kernel<<<dim3(Bsz * HH), blk, 0, stream>>>(0);

        attn_scores<<<dim3(NBT, NCHUNK), blk, 0, stream>>>(0);
        attn_softmax<<<dim3(NBT), blk, 0, stream>>>(0);
        attn_ctx<<<dim3(NBT, NCHUNK), blk, 0, stream>>>(0);

        add_bias_kernel<<<dim3(MROWS), blk, 0, stream>>>(bo + l * DM);
        scatter_kernel<<<dim3(NBT), blk, 0, stream>>>(Wo_l);
        ln_kernel<<<dim3(MROWS / 4), blk, 0, stream>>>(ln1g + l * DM, ln1b + l * DM);

        ffn1_mf<<<dim3(DFF / 128, MROWS / 128), blk, 0, stream>>>(
            c1W + (size_t)l * DM * DFF, c1b + l * DFF);
        ffn2_mf<<<dim3(DM / 128, MROWS / 128), blk, 0, stream>>>(
            c2W + (size_t)l * DFF * DM, c2b + l * DM);
        ln_kernel<<<dim3(MROWS / 4), blk, 0, stream>>>(ln2g + l * DM, ln2b + l * DM);
    }

    final_kernel<<<dim3(Bsz), blk, 0, stream>>>(nfg, nfb, projW, projb, (float*)d_out);
}

// Round 10
// 1266.089 us; speedup vs baseline: 1.3971x; 1.3971x over previous
//
#include <hip/hip_runtime.h>
#include <hip/hip_bf16.h>
#include <math.h>

typedef __hip_bfloat16 bf16;
typedef __attribute__((ext_vector_type(8))) short bf16x8;   // MFMA A/B frag
typedef __attribute__((ext_vector_type(4))) float f32x4;    // MFMA C/D frag

// Problem constants
#define Bsz 4
#define Lseq 2048
#define DM 256       // d_model == per-head D
#define HH 8
#define HD 2048      // H * DM
#define DFF 1024
#define SK 40
#define NTOP 5
#define MROWS 8192   // B * L
#define NBT (Bsz * HH * NTOP)   // 160
#define NCHUNK 8

// ---------------------------------------------------------------------------
// Static device scratch. __align__(256) REQUIRED (float4 casts).
// Round-10: Q/K never materialized. score = y·x + u + v + c with
// G=Wq_h Wk_h^T, y=X·G, u=X·(Wq·bk), v=X·(Wk·bq), c=bq·bk.
__device__ __align__(256) float g_X  [MROWS * DM];    //   8 MB activations
__device__ __align__(256) float g_TMP[MROWS * DM];    //   8 MB residual accum
__device__ __align__(256) float g_Y  [MROWS * HD];    //  64 MB y = X @ G
__device__ __align__(256) float g_V  [MROWS * HD];    //  64 MB all-head V
__device__ __align__(256) float g_HF [MROWS * DFF];   //  32 MB FFN hidden
__device__ __align__(256) float g_G  [DM * HD];       //   2 MB concat_h(Wq_h Wk_h^T)
__device__ __align__(256) float g_UV [MROWS * 16];    // [l][0..7]=u_h, [8..15]=v_h
__device__ __align__(256) float g_W12[DM * 16];       // [i][0..7]=Wq·bk, [8..15]=Wk·bq
__device__ __align__(256) float g_C  [HH];            // bq_h · bk_h
__device__ __align__(256) float g_ZB [HD];            // stays 0 (BSS) — y bias
__device__ __align__(256) float g_MB [Bsz * HH * Lseq];
__device__ __align__(256) float g_SC [NBT * Lseq];
__device__ __align__(256) float g_CTXP[NBT * NCHUNK * DM];
__device__ __align__(256) int   g_MTOP[NBT];

__device__ __forceinline__ float ld(const float* p, size_t i) { return p[i]; }
__device__ __forceinline__ float ld(const bf16* p, size_t i) { return __bfloat162float(p[i]); }
__device__ __forceinline__ void st(float* p, size_t i, float v) { p[i] = v; }
__device__ __forceinline__ void st(bf16* p, size_t i, float v) { p[i] = __float2bfloat16(v); }
__device__ __forceinline__ short f2bf(float v) {
    union { bf16 h; short s; } u; u.h = __float2bfloat16(v); return u.s;
}

// ---------------------------------------------------------------------------
// fp32 tiled GEMM, 128x128 tile, BK=16, 8x8 per thread, 256 threads.
template<typename TA, typename TC, bool GELU, bool RES>
__device__ __forceinline__ void gemm_body(
    const TA* __restrict__ A, const float* __restrict__ W,
    const float* __restrict__ bias, const float* __restrict__ res,
    TC* __restrict__ C, int K, int ldw, int ldc, int bx, int by)
{
    const int BM = 128, BN = 128, BK = 16;
    __shared__ __align__(16) float As[BK][BM + 4];
    __shared__ __align__(16) float Bs[BK][BN];
    int tid = threadIdx.x;
    int tx = tid & 15, ty = tid >> 4;
    int row0 = by * BM, col0 = bx * BN;
    float acc[8][8] = {};
    for (int k0 = 0; k0 < K; k0 += BK) {
        #pragma unroll
        for (int i = 0; i < 8; i++) {
            int idx = tid + i * 256;
            int r = idx >> 4, c = idx & 15;
            As[c][r] = ld(A, (size_t)(row0 + r) * K + k0 + c);
        }
        #pragma unroll
        for (int i = 0; i < 8; i++) {
            int idx = tid + i * 256;
            int r = idx >> 7, c = idx & 127;
            Bs[r][c] = W[(size_t)(k0 + r) * ldw + col0 + c];
        }
        __syncthreads();
        #pragma unroll
        for (int kk = 0; kk < BK; kk++) {
            float4 a0 = *(const float4*)&As[kk][ty * 8];
            float4 a1 = *(const float4*)&As[kk][ty * 8 + 4];
            float4 b0 = *(const float4*)&Bs[kk][tx * 8];
            float4 b1 = *(const float4*)&Bs[kk][tx * 8 + 4];
            float av[8] = {a0.x, a0.y, a0.z, a0.w, a1.x, a1.y, a1.z, a1.w};
            float bv[8] = {b0.x, b0.y, b0.z, b0.w, b1.x, b1.y, b1.z, b1.w};
            #pragma unroll
            for (int i = 0; i < 8; i++)
                #pragma unroll
                for (int j = 0; j < 8; j++) acc[i][j] += av[i] * bv[j];
        }
        __syncthreads();
    }
    #pragma unroll
    for (int i = 0; i < 8; i++) {
        int r = row0 + ty * 8 + i;
        #pragma unroll
        for (int j = 0; j < 8; j++) {
            int c = col0 + tx * 8 + j;
            float v = acc[i][j] + bias[c];
            if (RES) v += res[(size_t)r * ldc + c];
            if (GELU) v = 0.5f * v * (1.0f + erff(v * 0.70710678118654752440f));
            st(C, (size_t)r * ldc + c, v);
        }
    }
}

__global__ __launch_bounds__(256) void emb_gemm(const float* __restrict__ A,
                                                const float* __restrict__ W,
                                                const float* __restrict__ bias) {
    gemm_body<float, float, false, false>(A, W, bias, nullptr, g_X, 32, DM, DM,
                                          blockIdx.x, blockIdx.y);
}

// y = X @ G : [8192,256]@[256,2048] (replaces BOTH Q and K GEMMs)
__global__ __launch_bounds__(256) void y_gemm(int dummy) {
    (void)dummy;
    gemm_body<float, float, false, false>(g_X, g_G, g_ZB, nullptr, g_Y, DM, HD, HD,
                                          blockIdx.x, blockIdx.y);
}

// ---------------------------------------------------------------------------
// G_h = Wq_h @ Wk_h^T (NT), 64x64 tiles: grid (4,4,8). ~268 MF total.
__global__ __launch_bounds__(256) void gt_gemm(const float* __restrict__ Wq,
                                               const float* __restrict__ Wk)
{
    __shared__ float Aq[16][68];
    __shared__ float Ak[16][68];
    int h = blockIdx.z;
    int jt = blockIdx.x * 64, it = blockIdx.y * 64;
    int tid = threadIdx.x, tx = tid & 15, ty = tid >> 4;
    float acc[4][4] = {};
    for (int d0 = 0; d0 < DM; d0 += 16) {
        #pragma unroll
        for (int p = 0; p < 4; p++) {
            int idx = tid + p * 256;
            int i = idx >> 4, d = idx & 15;
            Aq[d][i] = Wq[(size_t)(it + i) * HD + h * DM + d0 + d];
            Ak[d][i] = Wk[(size_t)(jt + i) * HD + h * DM + d0 + d];
        }
        __syncthreads();
        #pragma unroll
        for (int d = 0; d < 16; d++) {
            float a[4], b[4];
            #pragma unroll
            for (int p = 0; p < 4; p++) { a[p] = Aq[d][ty * 4 + p]; b[p] = Ak[d][tx * 4 + p]; }
            #pragma unroll
            for (int i2 = 0; i2 < 4; i2++)
                #pragma unroll
                for (int j2 = 0; j2 < 4; j2++) acc[i2][j2] += a[i2] * b[j2];
        }
        __syncthreads();
    }
    #pragma unroll
    for (int i2 = 0; i2 < 4; i2++)
        #pragma unroll
        for (int j2 = 0; j2 < 4; j2++)
            g_G[(size_t)(it + ty * 4 + i2) * HD + h * DM + jt + tx * 4 + j2] = acc[i2][j2];
}

// w1[i,h]=Wq_h[i,:]·bk_h, w2[i,h]=Wk_h[i,:]·bq_h, c[h]=bq_h·bk_h. grid 8.
__global__ __launch_bounds__(256) void wc_kernel(const float* __restrict__ Wq,
                                                 const float* __restrict__ Wk,
                                                 const float* __restrict__ bq,
                                                 const float* __restrict__ bk)
{
    __shared__ float red[256];
    int h = blockIdx.x, i = threadIdx.x;
    const float4* qr  = (const float4*)(Wq + (size_t)i * HD + h * DM);
    const float4* kr  = (const float4*)(Wk + (size_t)i * HD + h * DM);
    const float4* bkr = (const float4*)(bk + h * DM);
    const float4* bqr = (const float4*)(bq + h * DM);
    float s1 = 0.f, s2 = 0.f;
    for (int j = 0; j < DM / 4; j++) {
        float4 q4 = qr[j], k4 = kr[j], b1 = bkr[j], b2 = bqr[j];
        s1 += q4.x * b1.x + q4.y * b1.y + q4.z * b1.z + q4.w * b1.w;
        s2 += k4.x * b2.x + k4.y * b2.y + k4.z * b2.z + k4.w * b2.w;
    }
    g_W12[i * 16 + h] = s1;
    g_W12[i * 16 + 8 + h] = s2;
    red[i] = bq[h * DM + i] * bk[h * DM + i];
    __syncthreads();
    for (int s = 128; s > 0; s >>= 1) { if (i < s) red[i] += red[i + s]; __syncthreads(); }
    if (i == 0) g_C[h] = red[0];
}

// u[l,h]=x_l·w1[:,h], v[l,h]=x_l·w2[:,h]. One wave per row; grid MROWS/4.
__global__ __launch_bounds__(256) void uv_kernel(int dummy)
{
    (void)dummy;
    int w = threadIdx.x >> 6, lane = threadIdx.x & 63;
    int l = blockIdx.x * 4 + w;
    float wrf[4][16];
    #pragma unroll
    for (int r = 0; r < 4; r++) {
        const float4* wp = (const float4*)(g_W12 + (size_t)(lane * 4 + r) * 16);
        float4 a = wp[0], b = wp[1], c = wp[2], d = wp[3];
        wrf[r][0]=a.x; wrf[r][1]=a.y; wrf[r][2]=a.z; wrf[r][3]=a.w;
        wrf[r][4]=b.x; wrf[r][5]=b.y; wrf[r][6]=b.z; wrf[r][7]=b.w;
        wrf[r][8]=c.x; wrf[r][9]=c.y; wrf[r][10]=c.z; wrf[r][11]=c.w;
        wrf[r][12]=d.x; wrf[r][13]=d.y; wrf[r][14]=d.z; wrf[r][15]=d.w;
    }
    float4 x4 = ((const float4*)(g_X + (size_t)l * DM))[lane];
    float xv[4] = {x4.x, x4.y, x4.z, x4.w};
    float uv[16];
    #pragma unroll
    for (int k = 0; k < 16; k++) {
        float acc = xv[0] * wrf[0][k] + xv[1] * wrf[1][k]
                  + xv[2] * wrf[2][k] + xv[3] * wrf[3][k];
        #pragma unroll
        for (int off = 32; off > 0; off >>= 1) acc += __shfl_xor(acc, off, 64);
        uv[k] = acc;
    }
    if (lane == 0) {
        float* o = g_UV + (size_t)l * 16;
        *(float4*)(o + 0)  = make_float4(uv[0], uv[1], uv[2], uv[3]);
        *(float4*)(o + 4)  = make_float4(uv[4], uv[5], uv[6], uv[7]);
        *(float4*)(o + 8)  = make_float4(uv[8], uv[9], uv[10], uv[11]);
        *(float4*)(o + 12) = make_float4(uv[12], uv[13], uv[14], uv[15]);
    }
}

// ---------------------------------------------------------------------------
// bf16 MFMA GEMM (V / FFN paths — smooth numerics): 128x128 tile, BK=32.
template<typename TC, bool GELU, bool RES>
__device__ __forceinline__ void mf_gemm_body(
    const float* __restrict__ A, const float* __restrict__ W,
    const float* __restrict__ bias, const float* __restrict__ res,
    TC* __restrict__ C, int K, int ldw, int ldc, int bx, int by)
{
    __shared__ __align__(16) short As[128][40];
    __shared__ __align__(16) short Bs[128][40];
    int tid = threadIdx.x;
    int wid = tid >> 6, lane = tid & 63;
    int wm = wid >> 1, wn = wid & 1;
    int quad = lane >> 4, l16 = lane & 15;
    int row0 = by * 128, col0 = bx * 128;
    f32x4 acc[4][4] = {};
    for (int k0 = 0; k0 < K; k0 += 32) {
        int ar = tid >> 3, ac = (tid & 7) * 4;
        #pragma unroll
        for (int i = 0; i < 4; i++) {
            float4 v = *(const float4*)&A[(size_t)(row0 + ar + i * 32) * K + k0 + ac];
            short4 s4 = {f2bf(v.x), f2bf(v.y), f2bf(v.z), f2bf(v.w)};
            *(short4*)&As[ar + i * 32][ac] = s4;
        }
        int bk = tid >> 5, bn = (tid & 31) * 4;
        #pragma unroll
        for (int i = 0; i < 4; i++) {
            int kk = bk + i * 8;
            float4 v = *(const float4*)&W[(size_t)(k0 + kk) * ldw + col0 + bn];
            Bs[bn + 0][kk] = f2bf(v.x);
            Bs[bn + 1][kk] = f2bf(v.y);
            Bs[bn + 2][kk] = f2bf(v.z);
            Bs[bn + 3][kk] = f2bf(v.w);
        }
        __syncthreads();
        bf16x8 af[4], bf_[4];
        #pragma unroll
        for (int mt = 0; mt < 4; mt++)
            af[mt] = *(const bf16x8*)&As[wm * 64 + mt * 16 + l16][quad * 8];
        #pragma unroll
        for (int nt = 0; nt < 4; nt++)
            bf_[nt] = *(const bf16x8*)&Bs[wn * 64 + nt * 16 + l16][quad * 8];
        #pragma unroll
        for (int mt = 0; mt < 4; mt++)
            #pragma unroll
            for (int nt = 0; nt < 4; nt++)
                acc[mt][nt] = __builtin_amdgcn_mfma_f32_16x16x32_bf16(
                    af[mt], bf_[nt], acc[mt][nt], 0, 0, 0);
        __syncthreads();
    }
    #pragma unroll
    for (int mt = 0; mt < 4; mt++) {
        #pragma unroll
        for (int nt = 0; nt < 4; nt++) {
            int col = col0 + wn * 64 + nt * 16 + l16;
            float bv = bias[col];
            #pragma unroll
            for (int r = 0; r < 4; r++) {
                int row = row0 + wm * 64 + mt * 16 + quad * 4 + r;
                float v = acc[mt][nt][r] + bv;
                if (RES) v += res[(size_t)row * ldc + col];
                if (GELU) v = 0.5f * v * (1.0f + erff(v * 0.70710678118654752440f));
                st(C, (size_t)row * ldc + col, v);
            }
        }
    }
}

__global__ __launch_bounds__(256) void v_mf(const float* __restrict__ W,
                                            const float* __restrict__ bias) {
    mf_gemm_body<float, false, false>(g_X, W, bias, nullptr, g_V, DM, HD, HD,
                                      blockIdx.x, blockIdx.y);
}
__global__ __launch_bounds__(256) void ffn1_mf(const float* __restrict__ W,
                                               const float* __restrict__ bias) {
    mf_gemm_body<float, true, false>(g_X, W, bias, nullptr, g_HF, DM, DFF, DFF,
                                     blockIdx.x, blockIdx.y);
}
__global__ __launch_bounds__(256) void ffn2_mf(const float* __restrict__ W,
                                               const float* __restrict__ bias) {
    mf_gemm_body<float, false, true>(g_HF, W, bias, g_X, g_TMP, DFF, DM, DM,
                                     blockIdx.x, blockIdx.y);
}

// ---------------------------------------------------------------------------
// Sampled scores + sparsity M. ONE BLOCK per (b,l) covers ALL 8 heads:
// the 40 gathered x-rows are staged once in LDS (8x less L2 gather traffic
// than per-head Q·K). score = y·x + u + v + c.
__global__ __launch_bounds__(256) void sampm_kernel(const int* __restrict__ idx)
{
    __shared__ __align__(16) float xs[SK][DM];   // 40 KB
    __shared__ float vs[SK][8];
    __shared__ int idxs[SK];
    int tid = threadIdx.x;
    int bl = blockIdx.x;                  // b*Lseq + l
    int b = bl >> 11, l = bl & (Lseq - 1);
    if (tid < SK) idxs[tid] = idx[l * SK + tid] & (Lseq - 1);
    __syncthreads();
    int w = tid >> 6, lane = tid & 63;
    for (int rr = w; rr < SK; rr += 4) {
        int s = idxs[rr];
        ((float4*)xs[rr])[lane] = ((const float4*)(g_X + (size_t)(b * Lseq + s) * DM))[lane];
    }
    if (tid < SK) {
        int s = idxs[tid];
        const float4* vp = (const float4*)(g_UV + (size_t)(b * Lseq + s) * 16 + 8);
        float4 v0 = vp[0], v1 = vp[1];
        vs[tid][0] = v0.x; vs[tid][1] = v0.y; vs[tid][2] = v0.z; vs[tid][3] = v0.w;
        vs[tid][4] = v1.x; vs[tid][5] = v1.y; vs[tid][6] = v1.z; vs[tid][7] = v1.w;
    }
    int h = tid >> 5, l32 = tid & 31;     // 32 lanes per head, dims l32+32k
    float yr[8];
    #pragma unroll
    for (int k = 0; k < 8; k++)
        yr[k] = g_Y[(size_t)(b * Lseq + l) * HD + h * DM + l32 + 32 * k];
    float uu = g_UV[(size_t)(b * Lseq + l) * 16 + h];
    float cc = g_C[h];
    __syncthreads();
    float mx = -INFINITY, sm = 0.f;
    for (int u = 0; u < SK; u++) {
        float p = 0.f;
        #pragma unroll
        for (int k = 0; k < 8; k++) p += yr[k] * xs[u][l32 + 32 * k];  // bank l32: conflict-free
        p += __shfl_xor(p, 1, 64);
        p += __shfl_xor(p, 2, 64);
        p += __shfl_xor(p, 4, 64);
        p += __shfl_xor(p, 8, 64);
        p += __shfl_xor(p, 16, 64);       // stays within each 32-lane half
        float sc = p + uu + vs[u][h] + cc;
        mx = fmaxf(mx, sc);
        sm += sc;
    }
    if (l32 == 0) g_MB[((size_t)(b * HH + h)) * Lseq + l] = mx - sm * (1.0f / (float)Lseq);
}

// ---------------------------------------------------------------------------
// Top-5 per (b,h): grid 32. 5 masked argmax passes (ties -> lower index).
__global__ __launch_bounds__(256) void topk_kernel(int dummy)
{
    (void)dummy;
    __shared__ float vals[Lseq];
    __shared__ float rv[256];
    __shared__ int ri[256];
    int bh = blockIdx.x, tid = threadIdx.x;
    for (int i = tid; i < Lseq; i += 256) vals[i] = g_MB[bh * Lseq + i];
    __syncthreads();
    for (int t = 0; t < NTOP; t++) {
        float bv = -INFINITY; int bi = Lseq - 1;
        for (int i = tid; i < Lseq; i += 256) {
            float v = vals[i];
            if (v > bv || (v == bv && i < bi)) { bv = v; bi = i; }
        }
        rv[tid] = bv; ri[tid] = bi;
        __syncthreads();
        for (int s = 128; s > 0; s >>= 1) {
            if (tid < s) {
                float ov = rv[tid + s]; int oi = ri[tid + s];
                if (ov > rv[tid] || (ov == rv[tid] && oi < ri[tid])) { rv[tid] = ov; ri[tid] = oi; }
            }
            __syncthreads();
        }
        if (tid == 0) { g_MTOP[bh * NTOP + t] = ri[0]; vals[ri[0] & (Lseq - 1)] = -INFINITY; }
        __syncthreads();
    }
}

// ---------------------------------------------------------------------------
// Scores for top queries via y·x + affine: grid (NBT, NCHUNK). Thread = key.
__global__ __launch_bounds__(256) void attn_scores(int dummy)
{
    (void)dummy;
    __shared__ __align__(16) float ys[DM];
    int bt = blockIdx.x, chunk = blockIdx.y, tid = threadIdx.x;
    int bh = bt / NTOP;
    int b = bh >> 3, h = bh & 7;
    int ltop = g_MTOP[bt] & (Lseq - 1);
    ys[tid] = g_Y[(size_t)(b * Lseq + ltop) * HD + h * DM + tid];
    __syncthreads();
    float uu = g_UV[(size_t)(b * Lseq + ltop) * 16 + h];
    float cc = g_C[h];
    int j = chunk * 256 + tid;
    const float4* xrow = (const float4*)(g_X + (size_t)(b * Lseq + j) * DM);
    float acc = 0.f;
    for (int d4 = 0; d4 < DM / 4; d4++) {
        float4 xf = xrow[d4];
        float4 yf = ((const float4*)ys)[d4];
        acc += yf.x * xf.x + yf.y * xf.y + yf.z * xf.z + yf.w * xf.w;
    }
    float vv = g_UV[(size_t)(b * Lseq + j) * 16 + 8 + h];
    g_SC[(size_t)bt * Lseq + j] = acc + uu + vv + cc;
}

// Softmax in place over g_SC row: grid NBT.
__global__ __launch_bounds__(256) void attn_softmax(int dummy)
{
    (void)dummy;
    __shared__ float sc[Lseq];
    __shared__ float red[256];
    int bt = blockIdx.x, tid = threadIdx.x;
    for (int i = tid; i < Lseq; i += 256) sc[i] = g_SC[(size_t)bt * Lseq + i];
    __syncthreads();
    float m = -INFINITY;
    for (int i = tid; i < Lseq; i += 256) m = fmaxf(m, sc[i]);
    red[tid] = m; __syncthreads();
    for (int s = 128; s > 0; s >>= 1) { if (tid < s) red[tid] = fmaxf(red[tid], red[tid + s]); __syncthreads(); }
    m = red[0]; __syncthreads();
    float sum = 0.f;
    for (int i = tid; i < Lseq; i += 256) { float e = expf(sc[i] - m); sc[i] = e; sum += e; }
    red[tid] = sum; __syncthreads();
    for (int s = 128; s > 0; s >>= 1) { if (tid < s) red[tid] += red[tid + s]; __syncthreads(); }
    float inv = 1.0f / red[0]; __syncthreads();
    for (int i = tid; i < Lseq; i += 256) g_SC[(size_t)bt * Lseq + i] = sc[i] * inv;
}

// Partial ctx over one key chunk: grid (NBT, NCHUNK). Thread = dim.
__global__ __launch_bounds__(256) void attn_ctx(int dummy)
{
    (void)dummy;
    __shared__ float ps[256];
    int bt = blockIdx.x, chunk = blockIdx.y, tid = threadIdx.x;
    int bh = bt / NTOP;
    int b = bh >> 3, h = bh & 7;
    int j0 = chunk * 256;
    ps[tid] = g_SC[(size_t)bt * Lseq + j0 + tid];
    __syncthreads();
    float accv = 0.f;
    const float* vbase = g_V + ((size_t)(b * Lseq + j0)) * HD + h * DM + tid;
    for (int j = 0; j < 256; j++) accv += ps[j] * vbase[(size_t)j * HD];
    g_CTXP[((size_t)bt * NCHUNK + chunk) * DM + tid] = accv;
}

// ---------------------------------------------------------------------------
__global__ __launch_bounds__(256) void add_bias_kernel(const float* __restrict__ bo)
{
    int i = blockIdx.x * 256 + threadIdx.x;
    g_TMP[i] = g_X[i] + bo[i & (DM - 1)];
}

__global__ __launch_bounds__(256) void scatter_kernel(const float* __restrict__ Wo_l)
{
    __shared__ float cs[DM];
    int bt = blockIdx.x, tid = threadIdx.x;
    int bh = bt / NTOP;
    int b = bh >> 3, h = bh & 7;
    float s = 0.f;
    #pragma unroll
    for (int c = 0; c < NCHUNK; c++) s += g_CTXP[((size_t)bt * NCHUNK + c) * DM + tid];
    cs[tid] = s;
    __syncthreads();
    int row = g_MTOP[bt] & (Lseq - 1);
    float acc = 0.f;
    const float* w = Wo_l + (size_t)h * DM * DM + tid;
    for (int d = 0; d < DM; d++) acc += cs[d] * w[(size_t)d * DM];
    atomicAdd(&g_TMP[((size_t)(b * Lseq) + row) * DM + tid], acc);
}

// ---------------------------------------------------------------------------
__global__ __launch_bounds__(256) void ln_kernel(const float* __restrict__ g,
                                                 const float* __restrict__ bb)
{
    int wid = blockIdx.x * 4 + (threadIdx.x >> 6);
    if (wid >= MROWS) return;
    int lane = threadIdx.x & 63;
    const float4* row = (const float4*)(g_TMP + (size_t)wid * DM);
    float4 v = row[lane];
    float s = v.x + v.y + v.z + v.w;
    #pragma unroll
    for (int off = 32; off > 0; off >>= 1) s += __shfl_down(s, off, 64);
    s = __shfl(s, 0, 64);
    float mean = s * (1.f / DM);
    float4 d = {v.x - mean, v.y - mean, v.z - mean, v.w - mean};
    float q = d.x * d.x + d.y * d.y + d.z * d.z + d.w * d.w;
    #pragma unroll
    for (int off = 32; off > 0; off >>= 1) q += __shfl_down(q, off, 64);
    q = __shfl(q, 0, 64);
    float inv = rsqrtf(q * (1.f / DM) + 1e-5f);
    int c = lane * 4;
    float4 o;
    o.x = d.x * inv * g[c + 0] + bb[c + 0];
    o.y = d.y * inv * g[c + 1] + bb[c + 1];
    o.z = d.z * inv * g[c + 2] + bb[c + 2];
    o.w = d.w * inv * g[c + 3] + bb[c + 3];
    ((float4*)(g_X + (size_t)wid * DM))[lane] = o;
}

// ---------------------------------------------------------------------------
__global__ __launch_bounds__(256) void final_kernel(
    const float* __restrict__ g, const float* __restrict__ bb,
    const float* __restrict__ pw, const float* __restrict__ pb,
    float* __restrict__ out)
{
    __shared__ float red[256];
    int b = blockIdx.x, tid = threadIdx.x;
    const float* row = g_X + ((size_t)(b * Lseq + Lseq - 1)) * DM;
    float v = row[tid];
    red[tid] = v; __syncthreads();
    for (int s = 128; s > 0; s >>= 1) { if (tid < s) red[tid] += red[tid + s]; __syncthreads(); }
    float mean = red[0] * (1.f / DM); __syncthreads();
    float d = v - mean;
    red[tid] = d * d; __syncthreads();
    for (int s = 128; s > 0; s >>= 1) { if (tid < s) red[tid] += red[tid + s]; __syncthreads(); }
    float var = red[0] * (1.f / DM); __syncthreads();
    float xn = d * rsqrtf(var + 1e-5f) * g[tid] + bb[tid];
    red[tid] = xn * pw[tid]; __syncthreads();
    for (int s = 128; s > 0; s >>= 1) { if (tid < s) red[tid] += red[tid + s]; __syncthreads(); }
    if (tid == 0) out[b] = red[0] + pb[0];
}

// ---------------------------------------------------------------------------
extern "C" void kernel_launch(void* const* d_in, const int* in_sizes, int n_in,
                              void* d_out, int out_size, void* d_ws, size_t ws_size,
                              hipStream_t stream)
{
    const float* x_enc = (const float*)d_in[0];
    const int*   isamp = (const int*)d_in[1];
    const float* emb_W = (const float*)d_in[2];
    const float* emb_b = (const float*)d_in[3];
    const float* Wq = (const float*)d_in[4];
    const float* bq = (const float*)d_in[5];
    const float* Wk = (const float*)d_in[6];
    const float* bk = (const float*)d_in[7];
    const float* Wv = (const float*)d_in[8];
    const float* bv = (const float*)d_in[9];
    const float* Wo = (const float*)d_in[10];
    const float* bo = (const float*)d_in[11];
    const float* c1W = (const float*)d_in[12];
    const float* c1b = (const float*)d_in[13];
    const float* c2W = (const float*)d_in[14];
    const float* c2b = (const float*)d_in[15];
    const float* ln1g = (const float*)d_in[16];
    const float* ln1b = (const float*)d_in[17];
    const float* ln2g = (const float*)d_in[18];
    const float* ln2b = (const float*)d_in[19];
    const float* nfg  = (const float*)d_in[20];
    const float* nfb  = (const float*)d_in[21];
    const float* projW = (const float*)d_in[22];
    const float* projb = (const float*)d_in[23];
    (void)d_ws; (void)ws_size; (void)in_sizes; (void)n_in; (void)out_size;

    dim3 blk(256);
    emb_gemm<<<dim3(DM / 128, MROWS / 128), blk, 0, stream>>>(x_enc, emb_W, emb_b);

    for (int l = 0; l < 2; l++) {
        const float* Wq_l = Wq + (size_t)l * DM * HD;
        const float* Wk_l = Wk + (size_t)l * DM * HD;
        const float* Wv_l = Wv + (size_t)l * DM * HD;
        const float* Wo_l = Wo + (size_t)l * HD * DM;

        gt_gemm<<<dim3(4, 4, 8), blk, 0, stream>>>(Wq_l, Wk_l);
        wc_kernel<<<dim3(HH), blk, 0, stream>>>(Wq_l, Wk_l, bq + l * HD, bk + l * HD);
        y_gemm<<<dim3(HD / 128, MROWS / 128), blk, 0, stream>>>(0);
        uv_kernel<<<dim3(MROWS / 4), blk, 0, stream>>>(0);
        v_mf<<<dim3(HD / 128, MROWS / 128), blk, 0, stream>>>(Wv_l, bv + l * HD);

        sampm_kernel<<<dim3(MROWS), blk, 0, stream>>>(isamp);
        topk_kernel<<<dim3(Bsz * HH), blk, 0, stream>>>(0);

        attn_scores<<<dim3(NBT, NCHUNK), blk, 0, stream>>>(0);
        attn_softmax<<<dim3(NBT), blk, 0, stream>>>(0);
        attn_ctx<<<dim3(NBT, NCHUNK), blk, 0, stream>>>(0);

        add_bias_kernel<<<dim3(MROWS), blk, 0, stream>>>(bo + l * DM);
        scatter_kernel<<<dim3(NBT), blk, 0, stream>>>(Wo_l);
        ln_kernel<<<dim3(MROWS / 4), blk, 0, stream>>>(ln1g + l * DM, ln1b + l * DM);

        ffn1_mf<<<dim3(DFF / 128, MROWS / 128), blk, 0, stream>>>(
            c1W + (size_t)l * DM * DFF, c1b + l * DFF);
        ffn2_mf<<<dim3(DM / 128, MROWS / 128), blk, 0, stream>>>(
            c2W + (size_t)l * DFF * DM, c2b + l * DM);
        ln_kernel<<<dim3(MROWS / 4), blk, 0, stream>>>(ln2g + l * DM, ln2b + l * DM);
    }

    final_kernel<<<dim3(Bsz), blk, 0, stream>>>(nfg, nfb, projW, projb, (float*)d_out);
}

// Round 11
// 1141.474 us; speedup vs baseline: 1.5496x; 1.1092x over previous
//
#include <hip/hip_runtime.h>
#include <hip/hip_bf16.h>
#include <math.h>

typedef __hip_bfloat16 bf16;
typedef __attribute__((ext_vector_type(8))) short bf16x8;   // MFMA A/B frag
typedef __attribute__((ext_vector_type(8))) short short8v;  // 16B bf16 vector
typedef __attribute__((ext_vector_type(4))) float f32x4;    // MFMA C/D frag

// Problem constants
#define Bsz 4
#define Lseq 2048
#define DM 256       // d_model == per-head D
#define HH 8
#define HD 2048      // H * DM
#define DFF 1024
#define SK 40
#define NTOP 5
#define MROWS 8192   // B * L
#define NBT (Bsz * HH * NTOP)   // 160
#define NCHUNK 8

// ---------------------------------------------------------------------------
// Static device scratch. __align__(256) REQUIRED (float4 casts).
// score = y·x + u + v + c with G=Wq_h Wk_h^T, y=X·G (bf16x3 MFMA), u=X·(Wq·bk),
// v=X·(Wk·bq), c=bq·bk. Q/K never materialized.
__device__ __align__(256) float g_X  [MROWS * DM];    //   8 MB activations (fp32)
__device__ __align__(256) bf16  g_Xhi[MROWS * DM];    //   4 MB bf16(X)
__device__ __align__(256) bf16  g_Xlo[MROWS * DM];    //   4 MB bf16(X - hi)
__device__ __align__(256) float g_TMP[MROWS * DM];    //   8 MB residual accum
__device__ __align__(256) float g_Y  [MROWS * HD];    //  64 MB y = X @ G
__device__ __align__(256) float g_V  [MROWS * HD];    //  64 MB all-head V
__device__ __align__(256) float g_HF [MROWS * DFF];   //  32 MB FFN hidden
__device__ __align__(256) bf16  g_GhiT[HD * DM];      //   1 MB G^T hi (n-major)
__device__ __align__(256) bf16  g_GloT[HD * DM];      //   1 MB G^T lo
__device__ __align__(256) float g_UV [MROWS * 16];    // [l][0..7]=u_h, [8..15]=v_h
__device__ __align__(256) float g_W12[DM * 16];
__device__ __align__(256) float g_C  [HH];
__device__ __align__(256) float g_MB [Bsz * HH * Lseq];
__device__ __align__(256) float g_SC [NBT * Lseq];
__device__ __align__(256) float g_CTXP[NBT * NCHUNK * DM];
__device__ __align__(256) int   g_MTOP[NBT];

__device__ __forceinline__ float ld(const float* p, size_t i) { return p[i]; }
__device__ __forceinline__ float ld(const bf16* p, size_t i) { return __bfloat162float(p[i]); }
__device__ __forceinline__ void st(float* p, size_t i, float v) { p[i] = v; }
__device__ __forceinline__ void st(bf16* p, size_t i, float v) { p[i] = __float2bfloat16(v); }
__device__ __forceinline__ short f2bf(float v) {
    union { bf16 h; short s; } u; u.h = __float2bfloat16(v); return u.s;
}

// ---------------------------------------------------------------------------
// fp32 tiled GEMM, 128x128 tile, BK=16, 8x8 per thread (embedding only now).
template<typename TA, typename TC, bool GELU, bool RES>
__device__ __forceinline__ void gemm_body(
    const TA* __restrict__ A, const float* __restrict__ W,
    const float* __restrict__ bias, const float* __restrict__ res,
    TC* __restrict__ C, int K, int ldw, int ldc, int bx, int by)
{
    const int BM = 128, BN = 128, BK = 16;
    __shared__ __align__(16) float As[BK][BM + 4];
    __shared__ __align__(16) float Bs[BK][BN];
    int tid = threadIdx.x;
    int tx = tid & 15, ty = tid >> 4;
    int row0 = by * BM, col0 = bx * BN;
    float acc[8][8] = {};
    for (int k0 = 0; k0 < K; k0 += BK) {
        #pragma unroll
        for (int i = 0; i < 8; i++) {
            int idx = tid + i * 256;
            int r = idx >> 4, c = idx & 15;
            As[c][r] = ld(A, (size_t)(row0 + r) * K + k0 + c);
        }
        #pragma unroll
        for (int i = 0; i < 8; i++) {
            int idx = tid + i * 256;
            int r = idx >> 7, c = idx & 127;
            Bs[r][c] = W[(size_t)(k0 + r) * ldw + col0 + c];
        }
        __syncthreads();
        #pragma unroll
        for (int kk = 0; kk < BK; kk++) {
            float4 a0 = *(const float4*)&As[kk][ty * 8];
            float4 a1 = *(const float4*)&As[kk][ty * 8 + 4];
            float4 b0 = *(const float4*)&Bs[kk][tx * 8];
            float4 b1 = *(const float4*)&Bs[kk][tx * 8 + 4];
            float av[8] = {a0.x, a0.y, a0.z, a0.w, a1.x, a1.y, a1.z, a1.w};
            float bv[8] = {b0.x, b0.y, b0.z, b0.w, b1.x, b1.y, b1.z, b1.w};
            #pragma unroll
            for (int i = 0; i < 8; i++)
                #pragma unroll
                for (int j = 0; j < 8; j++) acc[i][j] += av[i] * bv[j];
        }
        __syncthreads();
    }
    #pragma unroll
    for (int i = 0; i < 8; i++) {
        int r = row0 + ty * 8 + i;
        #pragma unroll
        for (int j = 0; j < 8; j++) {
            int c = col0 + tx * 8 + j;
            float v = acc[i][j] + bias[c];
            if (RES) v += res[(size_t)r * ldc + c];
            if (GELU) v = 0.5f * v * (1.0f + erff(v * 0.70710678118654752440f));
            st(C, (size_t)r * ldc + c, v);
        }
    }
}

// embedding: also emits Xhi/Xlo bf16 splits for the MFMA consumers.
__global__ __launch_bounds__(256) void emb_gemm(const float* __restrict__ A,
                                                const float* __restrict__ W,
                                                const float* __restrict__ bias)
{
    const int BM = 128;
    int tid = threadIdx.x;
    gemm_body<float, float, false, false>(A, W, bias, nullptr, g_X, 32, DM, DM,
                                          blockIdx.x, blockIdx.y);
    // split-write (re-read the tile we just wrote; cheap)
    int row0 = blockIdx.y * BM, col0 = blockIdx.x * 128;
    for (int i = 0; i < 8; i++) {
        int idx = tid + i * 256;
        int r = row0 + (idx >> 7), c = col0 + (idx & 127);
        float v = g_X[(size_t)r * DM + c];
        bf16 hi = __float2bfloat16(v);
        g_Xhi[(size_t)r * DM + c] = hi;
        g_Xlo[(size_t)r * DM + c] = __float2bfloat16(v - __bfloat162float(hi));
    }
}

// ---------------------------------------------------------------------------
// G^T_h = (Wq_h @ Wk_h^T)^T, written pre-split bf16 (hi/lo), n-major [HD][DM].
__global__ __launch_bounds__(256) void gt_gemm(const float* __restrict__ Wq,
                                               const float* __restrict__ Wk)
{
    __shared__ float Aq[16][68];
    __shared__ float Ak[16][68];
    int h = blockIdx.z;
    int jt = blockIdx.x * 64, it = blockIdx.y * 64;
    int tid = threadIdx.x, tx = tid & 15, ty = tid >> 4;
    float acc[4][4] = {};
    for (int d0 = 0; d0 < DM; d0 += 16) {
        #pragma unroll
        for (int p = 0; p < 4; p++) {
            int idx = tid + p * 256;
            int i = idx >> 4, d = idx & 15;
            Aq[d][i] = Wq[(size_t)(it + i) * HD + h * DM + d0 + d];
            Ak[d][i] = Wk[(size_t)(jt + i) * HD + h * DM + d0 + d];
        }
        __syncthreads();
        #pragma unroll
        for (int d = 0; d < 16; d++) {
            float a[4], b[4];
            #pragma unroll
            for (int p = 0; p < 4; p++) { a[p] = Aq[d][ty * 4 + p]; b[p] = Ak[d][tx * 4 + p]; }
            #pragma unroll
            for (int i2 = 0; i2 < 4; i2++)
                #pragma unroll
                for (int j2 = 0; j2 < 4; j2++) acc[i2][j2] += a[i2] * b[j2];
        }
        __syncthreads();
    }
    #pragma unroll
    for (int i2 = 0; i2 < 4; i2++)
        #pragma unroll
        for (int j2 = 0; j2 < 4; j2++) {
            float v = acc[i2][j2];
            bf16 hi = __float2bfloat16(v);
            size_t gi = (size_t)(h * DM + jt + tx * 4 + j2) * DM + (it + ty * 4 + i2);
            g_GhiT[gi] = hi;
            g_GloT[gi] = __float2bfloat16(v - __bfloat162float(hi));
        }
}

// w1[i,h]=Wq_h[i,:]·bk_h, w2[i,h]=Wk_h[i,:]·bq_h, c[h]=bq_h·bk_h. grid 8.
__global__ __launch_bounds__(256) void wc_kernel(const float* __restrict__ Wq,
                                                 const float* __restrict__ Wk,
                                                 const float* __restrict__ bq,
                                                 const float* __restrict__ bk)
{
    __shared__ float red[256];
    int h = blockIdx.x, i = threadIdx.x;
    const float4* qr  = (const float4*)(Wq + (size_t)i * HD + h * DM);
    const float4* kr  = (const float4*)(Wk + (size_t)i * HD + h * DM);
    const float4* bkr = (const float4*)(bk + h * DM);
    const float4* bqr = (const float4*)(bq + h * DM);
    float s1 = 0.f, s2 = 0.f;
    for (int j = 0; j < DM / 4; j++) {
        float4 q4 = qr[j], k4 = kr[j], b1 = bkr[j], b2 = bqr[j];
        s1 += q4.x * b1.x + q4.y * b1.y + q4.z * b1.z + q4.w * b1.w;
        s2 += k4.x * b2.x + k4.y * b2.y + k4.z * b2.z + k4.w * b2.w;
    }
    g_W12[i * 16 + h] = s1;
    g_W12[i * 16 + 8 + h] = s2;
    red[i] = bq[h * DM + i] * bk[h * DM + i];
    __syncthreads();
    for (int s = 128; s > 0; s >>= 1) { if (i < s) red[i] += red[i + s]; __syncthreads(); }
    if (i == 0) g_C[h] = red[0];
}

// u[l,h]=x_l·w1[:,h], v[l,h]=x_l·w2[:,h]. One wave per row; grid MROWS/4.
__global__ __launch_bounds__(256) void uv_kernel(int dummy)
{
    (void)dummy;
    int w = threadIdx.x >> 6, lane = threadIdx.x & 63;
    int l = blockIdx.x * 4 + w;
    float wrf[4][16];
    #pragma unroll
    for (int r = 0; r < 4; r++) {
        const float4* wp = (const float4*)(g_W12 + (size_t)(lane * 4 + r) * 16);
        float4 a = wp[0], b = wp[1], c = wp[2], d = wp[3];
        wrf[r][0]=a.x; wrf[r][1]=a.y; wrf[r][2]=a.z; wrf[r][3]=a.w;
        wrf[r][4]=b.x; wrf[r][5]=b.y; wrf[r][6]=b.z; wrf[r][7]=b.w;
        wrf[r][8]=c.x; wrf[r][9]=c.y; wrf[r][10]=c.z; wrf[r][11]=c.w;
        wrf[r][12]=d.x; wrf[r][13]=d.y; wrf[r][14]=d.z; wrf[r][15]=d.w;
    }
    float4 x4 = ((const float4*)(g_X + (size_t)l * DM))[lane];
    float xv[4] = {x4.x, x4.y, x4.z, x4.w};
    float uv[16];
    #pragma unroll
    for (int k = 0; k < 16; k++) {
        float acc = xv[0] * wrf[0][k] + xv[1] * wrf[1][k]
                  + xv[2] * wrf[2][k] + xv[3] * wrf[3][k];
        #pragma unroll
        for (int off = 32; off > 0; off >>= 1) acc += __shfl_xor(acc, off, 64);
        uv[k] = acc;
    }
    if (lane == 0) {
        float* o = g_UV + (size_t)l * 16;
        *(float4*)(o + 0)  = make_float4(uv[0], uv[1], uv[2], uv[3]);
        *(float4*)(o + 4)  = make_float4(uv[4], uv[5], uv[6], uv[7]);
        *(float4*)(o + 8)  = make_float4(uv[8], uv[9], uv[10], uv[11]);
        *(float4*)(o + 12) = make_float4(uv[12], uv[13], uv[14], uv[15]);
    }
}

// ---------------------------------------------------------------------------
// y = X @ G via bf16x3 split MFMA: y = Xhi·GhiT + Xhi·GloT + Xlo·GhiT.
// Raw bf16 staging (no cvt), B pre-transposed [n][k]. 128x128, BK=32.
// Relative error ~2^-17 — selection-safe (M-gaps ~0.045).
__global__ __launch_bounds__(256) void y_mf(int dummy)
{
    (void)dummy;
    __shared__ __align__(16) short As[128][40];
    __shared__ __align__(16) short Bs[128][40];
    int tid = threadIdx.x;
    int wid = tid >> 6, lane = tid & 63;
    int wm = wid >> 1, wn = wid & 1;
    int quad = lane >> 4, l16 = lane & 15;
    int row0 = blockIdx.y * 128, col0 = blockIdx.x * 128;
    f32x4 acc[4][4] = {};
    const short* Alist[3] = {(const short*)g_Xhi, (const short*)g_Xhi, (const short*)g_Xlo};
    const short* Blist[3] = {(const short*)g_GhiT, (const short*)g_GloT, (const short*)g_GhiT};
    #pragma unroll 1
    for (int pass = 0; pass < 3; pass++) {
        const short* A = Alist[pass];
        const short* B = Blist[pass];
        for (int k0 = 0; k0 < DM; k0 += 32) {
            __syncthreads();
            int r = tid >> 2, c = (tid & 3) * 8;
            #pragma unroll
            for (int p = 0; p < 2; p++) {
                *(short8v*)&As[r + p * 64][c] =
                    *(const short8v*)&A[(size_t)(row0 + r + p * 64) * DM + k0 + c];
                *(short8v*)&Bs[r + p * 64][c] =
                    *(const short8v*)&B[(size_t)(col0 + r + p * 64) * DM + k0 + c];
            }
            __syncthreads();
            bf16x8 af[4], bf_[4];
            #pragma unroll
            for (int mt = 0; mt < 4; mt++)
                af[mt] = *(const bf16x8*)&As[wm * 64 + mt * 16 + l16][quad * 8];
            #pragma unroll
            for (int nt = 0; nt < 4; nt++)
                bf_[nt] = *(const bf16x8*)&Bs[wn * 64 + nt * 16 + l16][quad * 8];
            #pragma unroll
            for (int mt = 0; mt < 4; mt++)
                #pragma unroll
                for (int nt = 0; nt < 4; nt++)
                    acc[mt][nt] = __builtin_amdgcn_mfma_f32_16x16x32_bf16(
                        af[mt], bf_[nt], acc[mt][nt], 0, 0, 0);
        }
    }
    #pragma unroll
    for (int mt = 0; mt < 4; mt++)
        #pragma unroll
        for (int nt = 0; nt < 4; nt++) {
            int col = col0 + wn * 64 + nt * 16 + l16;
            #pragma unroll
            for (int r = 0; r < 4; r++) {
                int row = row0 + wm * 64 + mt * 16 + quad * 4 + r;
                g_Y[(size_t)row * HD + col] = acc[mt][nt][r];
            }
        }
}

// ---------------------------------------------------------------------------
// bf16 MFMA GEMM (V / FFN — smooth numerics): 128x128 tile, BK=32, cvt-staging.
template<typename TC, bool GELU, bool RES>
__device__ __forceinline__ void mf_gemm_body(
    const float* __restrict__ A, const float* __restrict__ W,
    const float* __restrict__ bias, const float* __restrict__ res,
    TC* __restrict__ C, int K, int ldw, int ldc, int bx, int by)
{
    __shared__ __align__(16) short As[128][40];
    __shared__ __align__(16) short Bs[128][40];
    int tid = threadIdx.x;
    int wid = tid >> 6, lane = tid & 63;
    int wm = wid >> 1, wn = wid & 1;
    int quad = lane >> 4, l16 = lane & 15;
    int row0 = by * 128, col0 = bx * 128;
    f32x4 acc[4][4] = {};
    for (int k0 = 0; k0 < K; k0 += 32) {
        int ar = tid >> 3, ac = (tid & 7) * 4;
        #pragma unroll
        for (int i = 0; i < 4; i++) {
            float4 v = *(const float4*)&A[(size_t)(row0 + ar + i * 32) * K + k0 + ac];
            short4 s4 = {f2bf(v.x), f2bf(v.y), f2bf(v.z), f2bf(v.w)};
            *(short4*)&As[ar + i * 32][ac] = s4;
        }
        int bk = tid >> 5, bn = (tid & 31) * 4;
        #pragma unroll
        for (int i = 0; i < 4; i++) {
            int kk = bk + i * 8;
            float4 v = *(const float4*)&W[(size_t)(k0 + kk) * ldw + col0 + bn];
            Bs[bn + 0][kk] = f2bf(v.x);
            Bs[bn + 1][kk] = f2bf(v.y);
            Bs[bn + 2][kk] = f2bf(v.z);
            Bs[bn + 3][kk] = f2bf(v.w);
        }
        __syncthreads();
        bf16x8 af[4], bf_[4];
        #pragma unroll
        for (int mt = 0; mt < 4; mt++)
            af[mt] = *(const bf16x8*)&As[wm * 64 + mt * 16 + l16][quad * 8];
        #pragma unroll
        for (int nt = 0; nt < 4; nt++)
            bf_[nt] = *(const bf16x8*)&Bs[wn * 64 + nt * 16 + l16][quad * 8];
        #pragma unroll
        for (int mt = 0; mt < 4; mt++)
            #pragma unroll
            for (int nt = 0; nt < 4; nt++)
                acc[mt][nt] = __builtin_amdgcn_mfma_f32_16x16x32_bf16(
                    af[mt], bf_[nt], acc[mt][nt], 0, 0, 0);
        __syncthreads();
    }
    #pragma unroll
    for (int mt = 0; mt < 4; mt++) {
        #pragma unroll
        for (int nt = 0; nt < 4; nt++) {
            int col = col0 + wn * 64 + nt * 16 + l16;
            float bv = bias[col];
            #pragma unroll
            for (int r = 0; r < 4; r++) {
                int row = row0 + wm * 64 + mt * 16 + quad * 4 + r;
                float v = acc[mt][nt][r] + bv;
                if (RES) v += res[(size_t)row * ldc + col];
                if (GELU) v = 0.5f * v * (1.0f + erff(v * 0.70710678118654752440f));
                st(C, (size_t)row * ldc + col, v);
            }
        }
    }
}

__global__ __launch_bounds__(256) void v_mf(const float* __restrict__ W,
                                            const float* __restrict__ bias) {
    mf_gemm_body<float, false, false>(g_X, W, bias, nullptr, g_V, DM, HD, HD,
                                      blockIdx.x, blockIdx.y);
}
__global__ __launch_bounds__(256) void ffn1_mf(const float* __restrict__ W,
                                               const float* __restrict__ bias) {
    mf_gemm_body<float, true, false>(g_X, W, bias, nullptr, g_HF, DM, DFF, DFF,
                                     blockIdx.x, blockIdx.y);
}
__global__ __launch_bounds__(256) void ffn2_mf(const float* __restrict__ W,
                                               const float* __restrict__ bias) {
    mf_gemm_body<float, false, true>(g_HF, W, bias, g_X, g_TMP, DFF, DM, DM,
                                     blockIdx.x, blockIdx.y);
}

// ---------------------------------------------------------------------------
// Sampled scores + sparsity M. One block per (b,l), all 8 heads, TWO-STAGE
// staging (20 rows at a time): LDS 42.5 -> 21.9 KB => 7 blocks/CU (was 3).
__global__ __launch_bounds__(256) void sampm_kernel(const int* __restrict__ idx)
{
    __shared__ __align__(16) float xs[20][DM];   // 20 KB
    __shared__ float vs[SK][8];
    __shared__ int idxs[SK];
    int tid = threadIdx.x;
    int bl = blockIdx.x;                  // b*Lseq + l
    int b = bl >> 11, l = bl & (Lseq - 1);
    if (tid < SK) idxs[tid] = idx[l * SK + tid] & (Lseq - 1);
    __syncthreads();
    if (tid < SK) {
        int s = idxs[tid];
        const float4* vp = (const float4*)(g_UV + (size_t)(b * Lseq + s) * 16 + 8);
        float4 v0 = vp[0], v1 = vp[1];
        vs[tid][0] = v0.x; vs[tid][1] = v0.y; vs[tid][2] = v0.z; vs[tid][3] = v0.w;
        vs[tid][4] = v1.x; vs[tid][5] = v1.y; vs[tid][6] = v1.z; vs[tid][7] = v1.w;
    }
    int h = tid >> 5, l32 = tid & 31;     // 32 lanes per head, dims l32+32k
    float yr[8];
    #pragma unroll
    for (int k = 0; k < 8; k++)
        yr[k] = g_Y[(size_t)(b * Lseq + l) * HD + h * DM + l32 + 32 * k];
    float uu = g_UV[(size_t)(b * Lseq + l) * 16 + h];
    float cc = g_C[h];
    int w = tid >> 6, lane = tid & 63;
    float mx = -INFINITY, sm = 0.f;
    #pragma unroll 1
    for (int half = 0; half < 2; half++) {
        __syncthreads();                  // protect xs from previous compute
        for (int rr = w; rr < 20; rr += 4) {
            int s = idxs[half * 20 + rr];
            ((float4*)xs[rr])[lane] =
                ((const float4*)(g_X + (size_t)(b * Lseq + s) * DM))[lane];
        }
        __syncthreads();
        for (int u = 0; u < 20; u++) {
            float p = 0.f;
            #pragma unroll
            for (int k = 0; k < 8; k++) p += yr[k] * xs[u][l32 + 32 * k];
            p += __shfl_xor(p, 1, 64);
            p += __shfl_xor(p, 2, 64);
            p += __shfl_xor(p, 4, 64);
            p += __shfl_xor(p, 8, 64);
            p += __shfl_xor(p, 16, 64);
            float sc = p + uu + vs[half * 20 + u][h] + cc;
            mx = fmaxf(mx, sc);
            sm += sc;
        }
    }
    if (l32 == 0) g_MB[((size_t)(b * HH + h)) * Lseq + l] = mx - sm * (1.0f / (float)Lseq);
}

// ---------------------------------------------------------------------------
// Top-5 per (b,h): grid 32. 5 masked argmax passes (ties -> lower index).
__global__ __launch_bounds__(256) void topk_kernel(int dummy)
{
    (void)dummy;
    __shared__ float vals[Lseq];
    __shared__ float rv[256];
    __shared__ int ri[256];
    int bh = blockIdx.x, tid = threadIdx.x;
    for (int i = tid; i < Lseq; i += 256) vals[i] = g_MB[bh * Lseq + i];
    __syncthreads();
    for (int t = 0; t < NTOP; t++) {
        float bv = -INFINITY; int bi = Lseq - 1;
        for (int i = tid; i < Lseq; i += 256) {
            float v = vals[i];
            if (v > bv || (v == bv && i < bi)) { bv = v; bi = i; }
        }
        rv[tid] = bv; ri[tid] = bi;
        __syncthreads();
        for (int s = 128; s > 0; s >>= 1) {
            if (tid < s) {
                float ov = rv[tid + s]; int oi = ri[tid + s];
                if (ov > rv[tid] || (ov == rv[tid] && oi < ri[tid])) { rv[tid] = ov; ri[tid] = oi; }
            }
            __syncthreads();
        }
        if (tid == 0) { g_MTOP[bh * NTOP + t] = ri[0]; vals[ri[0] & (Lseq - 1)] = -INFINITY; }
        __syncthreads();
    }
}

// ---------------------------------------------------------------------------
// Scores for top queries via y·x + affine: grid (NBT, NCHUNK). Thread = key.
__global__ __launch_bounds__(256) void attn_scores(int dummy)
{
    (void)dummy;
    __shared__ __align__(16) float ys[DM];
    int bt = blockIdx.x, chunk = blockIdx.y, tid = threadIdx.x;
    int bh = bt / NTOP;
    int b = bh >> 3, h = bh & 7;
    int ltop = g_MTOP[bt] & (Lseq - 1);
    ys[tid] = g_Y[(size_t)(b * Lseq + ltop) * HD + h * DM + tid];
    __syncthreads();
    float uu = g_UV[(size_t)(b * Lseq + ltop) * 16 + h];
    float cc = g_C[h];
    int j = chunk * 256 + tid;
    const float4* xrow = (const float4*)(g_X + (size_t)(b * Lseq + j) * DM);
    float acc = 0.f;
    for (int d4 = 0; d4 < DM / 4; d4++) {
        float4 xf = xrow[d4];
        float4 yf = ((const float4*)ys)[d4];
        acc += yf.x * xf.x + yf.y * xf.y + yf.z * xf.z + yf.w * xf.w;
    }
    float vv = g_UV[(size_t)(b * Lseq + j) * 16 + 8 + h];
    g_SC[(size_t)bt * Lseq + j] = acc + uu + vv + cc;
}

// Softmax in place over g_SC row: grid NBT.
__global__ __launch_bounds__(256) void attn_softmax(int dummy)
{
    (void)dummy;
    __shared__ float sc[Lseq];
    __shared__ float red[256];
    int bt = blockIdx.x, tid = threadIdx.x;
    for (int i = tid; i < Lseq; i += 256) sc[i] = g_SC[(size_t)bt * Lseq + i];
    __syncthreads();
    float m = -INFINITY;
    for (int i = tid; i < Lseq; i += 256) m = fmaxf(m, sc[i]);
    red[tid] = m; __syncthreads();
    for (int s = 128; s > 0; s >>= 1) { if (tid < s) red[tid] = fmaxf(red[tid], red[tid + s]); __syncthreads(); }
    m = red[0]; __syncthreads();
    float sum = 0.f;
    for (int i = tid; i < Lseq; i += 256) { float e = expf(sc[i] - m); sc[i] = e; sum += e; }
    red[tid] = sum; __syncthreads();
    for (int s = 128; s > 0; s >>= 1) { if (tid < s) red[tid] += red[tid + s]; __syncthreads(); }
    float inv = 1.0f / red[0]; __syncthreads();
    for (int i = tid; i < Lseq; i += 256) g_SC[(size_t)bt * Lseq + i] = sc[i] * inv;
}

// Partial ctx over one key chunk: grid (NBT, NCHUNK). Thread = dim.
__global__ __launch_bounds__(256) void attn_ctx(int dummy)
{
    (void)dummy;
    __shared__ float ps[256];
    int bt = blockIdx.x, chunk = blockIdx.y, tid = threadIdx.x;
    int bh = bt / NTOP;
    int b = bh >> 3, h = bh & 7;
    int j0 = chunk * 256;
    ps[tid] = g_SC[(size_t)bt * Lseq + j0 + tid];
    __syncthreads();
    float accv = 0.f;
    const float* vbase = g_V + ((size_t)(b * Lseq + j0)) * HD + h * DM + tid;
    for (int j = 0; j < 256; j++) accv += ps[j] * vbase[(size_t)j * HD];
    g_CTXP[((size_t)bt * NCHUNK + chunk) * DM + tid] = accv;
}

// ---------------------------------------------------------------------------
__global__ __launch_bounds__(256) void add_bias_kernel(const float* __restrict__ bo)
{
    int i = blockIdx.x * 256 + threadIdx.x;
    g_TMP[i] = g_X[i] + bo[i & (DM - 1)];
}

__global__ __launch_bounds__(256) void scatter_kernel(const float* __restrict__ Wo_l)
{
    __shared__ float cs[DM];
    int bt = blockIdx.x, tid = threadIdx.x;
    int bh = bt / NTOP;
    int b = bh >> 3, h = bh & 7;
    float s = 0.f;
    #pragma unroll
    for (int c = 0; c < NCHUNK; c++) s += g_CTXP[((size_t)bt * NCHUNK + c) * DM + tid];
    cs[tid] = s;
    __syncthreads();
    int row = g_MTOP[bt] & (Lseq - 1);
    float acc = 0.f;
    const float* w = Wo_l + (size_t)h * DM * DM + tid;
    for (int d = 0; d < DM; d++) acc += cs[d] * w[(size_t)d * DM];
    atomicAdd(&g_TMP[((size_t)(b * Lseq) + row) * DM + tid], acc);
}

// ---------------------------------------------------------------------------
// LayerNorm g_TMP -> g_X (+ Xhi/Xlo bf16 splits), one wave per row of 256.
__global__ __launch_bounds__(256) void ln_kernel(const float* __restrict__ g,
                                                 const float* __restrict__ bb)
{
    int wid = blockIdx.x * 4 + (threadIdx.x >> 6);
    if (wid >= MROWS) return;
    int lane = threadIdx.x & 63;
    const float4* row = (const float4*)(g_TMP + (size_t)wid * DM);
    float4 v = row[lane];
    float s = v.x + v.y + v.z + v.w;
    #pragma unroll
    for (int off = 32; off > 0; off >>= 1) s += __shfl_down(s, off, 64);
    s = __shfl(s, 0, 64);
    float mean = s * (1.f / DM);
    float4 d = {v.x - mean, v.y - mean, v.z - mean, v.w - mean};
    float q = d.x * d.x + d.y * d.y + d.z * d.z + d.w * d.w;
    #pragma unroll
    for (int off = 32; off > 0; off >>= 1) q += __shfl_down(q, off, 64);
    q = __shfl(q, 0, 64);
    float inv = rsqrtf(q * (1.f / DM) + 1e-5f);
    int c = lane * 4;
    float4 o;
    o.x = d.x * inv * g[c + 0] + bb[c + 0];
    o.y = d.y * inv * g[c + 1] + bb[c + 1];
    o.z = d.z * inv * g[c + 2] + bb[c + 2];
    o.w = d.w * inv * g[c + 3] + bb[c + 3];
    ((float4*)(g_X + (size_t)wid * DM))[lane] = o;
    float ov[4] = {o.x, o.y, o.z, o.w};
    short hi[4], lo[4];
    #pragma unroll
    for (int t = 0; t < 4; t++) {
        bf16 hb = __float2bfloat16(ov[t]);
        hi[t] = *(short*)&hb;
        bf16 lb = __float2bfloat16(ov[t] - __bfloat162float(hb));
        lo[t] = *(short*)&lb;
    }
    *(short4*)((short*)g_Xhi + (size_t)wid * DM + c) = make_short4(hi[0], hi[1], hi[2], hi[3]);
    *(short4*)((short*)g_Xlo + (size_t)wid * DM + c) = make_short4(lo[0], lo[1], lo[2], lo[3]);
}

// ---------------------------------------------------------------------------
__global__ __launch_bounds__(256) void final_kernel(
    const float* __restrict__ g, const float* __restrict__ bb,
    const float* __restrict__ pw, const float* __restrict__ pb,
    float* __restrict__ out)
{
    __shared__ float red[256];
    int b = blockIdx.x, tid = threadIdx.x;
    const float* row = g_X + ((size_t)(b * Lseq + Lseq - 1)) * DM;
    float v = row[tid];
    red[tid] = v; __syncthreads();
    for (int s = 128; s > 0; s >>= 1) { if (tid < s) red[tid] += red[tid + s]; __syncthreads(); }
    float mean = red[0] * (1.f / DM); __syncthreads();
    float d = v - mean;
    red[tid] = d * d; __syncthreads();
    for (int s = 128; s > 0; s >>= 1) { if (tid < s) red[tid] += red[tid + s]; __syncthreads(); }
    float var = red[0] * (1.f / DM); __syncthreads();
    float xn = d * rsqrtf(var + 1e-5f) * g[tid] + bb[tid];
    red[tid] = xn * pw[tid]; __syncthreads();
    for (int s = 128; s > 0; s >>= 1) { if (tid < s) red[tid] += red[tid + s]; __syncthreads(); }
    if (tid == 0) out[b] = red[0] + pb[0];
}

// ---------------------------------------------------------------------------
extern "C" void kernel_launch(void* const* d_in, const int* in_sizes, int n_in,
                              void* d_out, int out_size, void* d_ws, size_t ws_size,
                              hipStream_t stream)
{
    const float* x_enc = (const float*)d_in[0];
    const int*   isamp = (const int*)d_in[1];
    const float* emb_W = (const float*)d_in[2];
    const float* emb_b = (const float*)d_in[3];
    const float* Wq = (const float*)d_in[4];
    const float* bq = (const float*)d_in[5];
    const float* Wk = (const float*)d_in[6];
    const float* bk = (const float*)d_in[7];
    const float* Wv = (const float*)d_in[8];
    const float* bv = (const float*)d_in[9];
    const float* Wo = (const float*)d_in[10];
    const float* bo = (const float*)d_in[11];
    const float* c1W = (const float*)d_in[12];
    const float* c1b = (const float*)d_in[13];
    const float* c2W = (const float*)d_in[14];
    const float* c2b = (const float*)d_in[15];
    const float* ln1g = (const float*)d_in[16];
    const float* ln1b = (const float*)d_in[17];
    const float* ln2g = (const float*)d_in[18];
    const float* ln2b = (const float*)d_in[19];
    const float* nfg  = (const float*)d_in[20];
    const float* nfb  = (const float*)d_in[21];
    const float* projW = (const float*)d_in[22];
    const float* projb = (const float*)d_in[23];
    (void)d_ws; (void)ws_size; (void)in_sizes; (void)n_in; (void)out_size;

    dim3 blk(256);
    emb_gemm<<<dim3(DM / 128, MROWS / 128), blk, 0, stream>>>(x_enc, emb_W, emb_b);

    for (int l = 0; l < 2; l++) {
        const float* Wq_l = Wq + (size_t)l * DM * HD;
        const float* Wk_l = Wk + (size_t)l * DM * HD;
        const float* Wv_l = Wv + (size_t)l * DM * HD;
        const float* Wo_l = Wo + (size_t)l * HD * DM;

        gt_gemm<<<dim3(4, 4, 8), blk, 0, stream>>>(Wq_l, Wk_l);
        wc_kernel<<<dim3(HH), blk, 0, stream>>>(Wq_l, Wk_l, bq + l * HD, bk + l * HD);
        y_mf<<<dim3(HD / 128, MROWS / 128), blk, 0, stream>>>(0);
        uv_kernel<<<dim3(MROWS / 4), blk, 0, stream>>>(0);
        v_mf<<<dim3(HD / 128, MROWS / 128), blk, 0, stream>>>(Wv_l, bv + l * HD);

        sampm_kernel<<<dim3(MROWS), blk, 0, stream>>>(isamp);
        topk_kernel<<<dim3(Bsz * HH), blk, 0, stream>>>(0);

        attn_scores<<<dim3(NBT, NCHUNK), blk, 0, stream>>>(0);
        attn_softmax<<<dim3(NBT), blk, 0, stream>>>(0);
        attn_ctx<<<dim3(NBT, NCHUNK), blk, 0, stream>>>(0);

        add_bias_kernel<<<dim3(MROWS), blk, 0, stream>>>(bo + l * DM);
        scatter_kernel<<<dim3(NBT), blk, 0, stream>>>(Wo_l);
        ln_kernel<<<dim3(MROWS / 4), blk, 0, stream>>>(ln1g + l * DM, ln1b + l * DM);

        ffn1_mf<<<dim3(DFF / 128, MROWS / 128), blk, 0, stream>>>(
            c1W + (size_t)l * DM * DFF, c1b + l * DFF);
        ffn2_mf<<<dim3(DM / 128, MROWS / 128), blk, 0, stream>>>(
            c2W + (size_t)l * DFF * DM, c2b + l * DM);
        ln_kernel<<<dim3(MROWS / 4), blk, 0, stream>>>(ln2g + l * DM, ln2b + l * DM);
    }

    final_kernel<<<dim3(Bsz), blk, 0, stream>>>(nfg, nfb, projW, projb, (float*)d_out);
}

// Round 12
// 1032.156 us; speedup vs baseline: 1.7138x; 1.1059x over previous
//
#include <hip/hip_runtime.h>
#include <hip/hip_bf16.h>
#include <math.h>

typedef __hip_bfloat16 bf16;
typedef __attribute__((ext_vector_type(8))) short bf16x8;   // MFMA A/B frag
typedef __attribute__((ext_vector_type(8))) short short8v;  // 16B bf16 vector
typedef __attribute__((ext_vector_type(4))) float f32x4;    // MFMA C/D frag

// Problem constants
#define Bsz 4
#define Lseq 2048
#define DM 256       // d_model == per-head D
#define HH 8
#define HD 2048      // H * DM
#define DFF 1024
#define SK 40
#define NTOP 5
#define MROWS 8192   // B * L
#define NBT (Bsz * HH * NTOP)   // 160
#define NCHUNK 8

// ---------------------------------------------------------------------------
// Static device scratch. __align__(256) REQUIRED (float4 casts).
// score = y·x + u + v + c with G=Wq_h Wk_h^T, y=X·G (bf16x3 MFMA, stored as
// hi/lo bf16 split), u=X·(Wq·bk), v=X·(Wk·bq), c=bq·bk. Q/K never materialized.
__device__ __align__(256) float g_X  [MROWS * DM];    //   8 MB activations (fp32)
__device__ __align__(256) bf16  g_Xhi[MROWS * DM];    //   4 MB bf16(X)
__device__ __align__(256) bf16  g_Xlo[MROWS * DM];    //   4 MB bf16(X - hi)
__device__ __align__(256) float g_TMP[MROWS * DM];    //   8 MB residual accum
__device__ __align__(256) bf16  g_Yhi[MROWS * HD];    //  32 MB bf16(y)
__device__ __align__(256) bf16  g_Ylo[MROWS * HD];    //  32 MB bf16(y - hi)
__device__ __align__(256) float g_V  [MROWS * HD];    //  64 MB all-head V
__device__ __align__(256) float g_HF [MROWS * DFF];   //  32 MB FFN hidden
__device__ __align__(256) bf16  g_GhiT[HD * DM];      //   1 MB G^T hi (n-major)
__device__ __align__(256) bf16  g_GloT[HD * DM];      //   1 MB G^T lo
__device__ __align__(256) float g_UV [MROWS * 16];    // [l][0..7]=u_h, [8..15]=v_h
__device__ __align__(256) float g_W12[DM * 16];
__device__ __align__(256) float g_C  [HH];
__device__ __align__(256) float g_MB [Bsz * HH * Lseq];
__device__ __align__(256) float g_SC [NBT * Lseq];
__device__ __align__(256) float g_CTXP[NBT * NCHUNK * DM];
__device__ __align__(256) int   g_MTOP[NBT];

__device__ __forceinline__ float ld(const float* p, size_t i) { return p[i]; }
__device__ __forceinline__ float ld(const bf16* p, size_t i) { return __bfloat162float(p[i]); }
__device__ __forceinline__ float b2f(bf16 x) { return __bfloat162float(x); }
__device__ __forceinline__ void st(float* p, size_t i, float v) { p[i] = v; }
__device__ __forceinline__ void st(bf16* p, size_t i, float v) { p[i] = __float2bfloat16(v); }
__device__ __forceinline__ short f2bf(float v) {
    union { bf16 h; short s; } u; u.h = __float2bfloat16(v); return u.s;
}

// ---------------------------------------------------------------------------
// fp32 tiled GEMM, 128x128 tile, BK=16, 8x8 per thread (embedding only).
template<typename TA, typename TC, bool GELU, bool RES>
__device__ __forceinline__ void gemm_body(
    const TA* __restrict__ A, const float* __restrict__ W,
    const float* __restrict__ bias, const float* __restrict__ res,
    TC* __restrict__ C, int K, int ldw, int ldc, int bx, int by)
{
    const int BM = 128, BN = 128, BK = 16;
    __shared__ __align__(16) float As[BK][BM + 4];
    __shared__ __align__(16) float Bs[BK][BN];
    int tid = threadIdx.x;
    int tx = tid & 15, ty = tid >> 4;
    int row0 = by * BM, col0 = bx * BN;
    float acc[8][8] = {};
    for (int k0 = 0; k0 < K; k0 += BK) {
        #pragma unroll
        for (int i = 0; i < 8; i++) {
            int idx = tid + i * 256;
            int r = idx >> 4, c = idx & 15;
            As[c][r] = ld(A, (size_t)(row0 + r) * K + k0 + c);
        }
        #pragma unroll
        for (int i = 0; i < 8; i++) {
            int idx = tid + i * 256;
            int r = idx >> 7, c = idx & 127;
            Bs[r][c] = W[(size_t)(k0 + r) * ldw + col0 + c];
        }
        __syncthreads();
        #pragma unroll
        for (int kk = 0; kk < BK; kk++) {
            float4 a0 = *(const float4*)&As[kk][ty * 8];
            float4 a1 = *(const float4*)&As[kk][ty * 8 + 4];
            float4 b0 = *(const float4*)&Bs[kk][tx * 8];
            float4 b1 = *(const float4*)&Bs[kk][tx * 8 + 4];
            float av[8] = {a0.x, a0.y, a0.z, a0.w, a1.x, a1.y, a1.z, a1.w};
            float bv[8] = {b0.x, b0.y, b0.z, b0.w, b1.x, b1.y, b1.z, b1.w};
            #pragma unroll
            for (int i = 0; i < 8; i++)
                #pragma unroll
                for (int j = 0; j < 8; j++) acc[i][j] += av[i] * bv[j];
        }
        __syncthreads();
    }
    #pragma unroll
    for (int i = 0; i < 8; i++) {
        int r = row0 + ty * 8 + i;
        #pragma unroll
        for (int j = 0; j < 8; j++) {
            int c = col0 + tx * 8 + j;
            float v = acc[i][j] + bias[c];
            if (RES) v += res[(size_t)r * ldc + c];
            if (GELU) v = 0.5f * v * (1.0f + erff(v * 0.70710678118654752440f));
            st(C, (size_t)r * ldc + c, v);
        }
    }
}

// embedding: also emits Xhi/Xlo bf16 splits for the MFMA consumers.
__global__ __launch_bounds__(256) void emb_gemm(const float* __restrict__ A,
                                                const float* __restrict__ W,
                                                const float* __restrict__ bias)
{
    const int BM = 128;
    int tid = threadIdx.x;
    gemm_body<float, float, false, false>(A, W, bias, nullptr, g_X, 32, DM, DM,
                                          blockIdx.x, blockIdx.y);
    int row0 = blockIdx.y * BM, col0 = blockIdx.x * 128;
    for (int i = 0; i < 8; i++) {
        int idx = tid + i * 256;
        int r = row0 + (idx >> 7), c = col0 + (idx & 127);
        float v = g_X[(size_t)r * DM + c];
        bf16 hi = __float2bfloat16(v);
        g_Xhi[(size_t)r * DM + c] = hi;
        g_Xlo[(size_t)r * DM + c] = __float2bfloat16(v - __bfloat162float(hi));
    }
}

// ---------------------------------------------------------------------------
// G^T_h = (Wq_h @ Wk_h^T)^T, written pre-split bf16 (hi/lo), n-major [HD][DM].
__global__ __launch_bounds__(256) void gt_gemm(const float* __restrict__ Wq,
                                               const float* __restrict__ Wk)
{
    __shared__ float Aq[16][68];
    __shared__ float Ak[16][68];
    int h = blockIdx.z;
    int jt = blockIdx.x * 64, it = blockIdx.y * 64;
    int tid = threadIdx.x, tx = tid & 15, ty = tid >> 4;
    float acc[4][4] = {};
    for (int d0 = 0; d0 < DM; d0 += 16) {
        #pragma unroll
        for (int p = 0; p < 4; p++) {
            int idx = tid + p * 256;
            int i = idx >> 4, d = idx & 15;
            Aq[d][i] = Wq[(size_t)(it + i) * HD + h * DM + d0 + d];
            Ak[d][i] = Wk[(size_t)(jt + i) * HD + h * DM + d0 + d];
        }
        __syncthreads();
        #pragma unroll
        for (int d = 0; d < 16; d++) {
            float a[4], b[4];
            #pragma unroll
            for (int p = 0; p < 4; p++) { a[p] = Aq[d][ty * 4 + p]; b[p] = Ak[d][tx * 4 + p]; }
            #pragma unroll
            for (int i2 = 0; i2 < 4; i2++)
                #pragma unroll
                for (int j2 = 0; j2 < 4; j2++) acc[i2][j2] += a[i2] * b[j2];
        }
        __syncthreads();
    }
    #pragma unroll
    for (int i2 = 0; i2 < 4; i2++)
        #pragma unroll
        for (int j2 = 0; j2 < 4; j2++) {
            float v = acc[i2][j2];
            bf16 hi = __float2bfloat16(v);
            size_t gi = (size_t)(h * DM + jt + tx * 4 + j2) * DM + (it + ty * 4 + i2);
            g_GhiT[gi] = hi;
            g_GloT[gi] = __float2bfloat16(v - __bfloat162float(hi));
        }
}

// w1[i,h]=Wq_h[i,:]·bk_h, w2[i,h]=Wk_h[i,:]·bq_h, c[h]=bq_h·bk_h. grid 8.
__global__ __launch_bounds__(256) void wc_kernel(const float* __restrict__ Wq,
                                                 const float* __restrict__ Wk,
                                                 const float* __restrict__ bq,
                                                 const float* __restrict__ bk)
{
    __shared__ float red[256];
    int h = blockIdx.x, i = threadIdx.x;
    const float4* qr  = (const float4*)(Wq + (size_t)i * HD + h * DM);
    const float4* kr  = (const float4*)(Wk + (size_t)i * HD + h * DM);
    const float4* bkr = (const float4*)(bk + h * DM);
    const float4* bqr = (const float4*)(bq + h * DM);
    float s1 = 0.f, s2 = 0.f;
    for (int j = 0; j < DM / 4; j++) {
        float4 q4 = qr[j], k4 = kr[j], b1 = bkr[j], b2 = bqr[j];
        s1 += q4.x * b1.x + q4.y * b1.y + q4.z * b1.z + q4.w * b1.w;
        s2 += k4.x * b2.x + k4.y * b2.y + k4.z * b2.z + k4.w * b2.w;
    }
    g_W12[i * 16 + h] = s1;
    g_W12[i * 16 + 8 + h] = s2;
    red[i] = bq[h * DM + i] * bk[h * DM + i];
    __syncthreads();
    for (int s = 128; s > 0; s >>= 1) { if (i < s) red[i] += red[i + s]; __syncthreads(); }
    if (i == 0) g_C[h] = red[0];
}

// u[l,h]=x_l·w1[:,h], v[l,h]=x_l·w2[:,h]. One wave per row; grid MROWS/4.
__global__ __launch_bounds__(256) void uv_kernel(int dummy)
{
    (void)dummy;
    int w = threadIdx.x >> 6, lane = threadIdx.x & 63;
    int l = blockIdx.x * 4 + w;
    float wrf[4][16];
    #pragma unroll
    for (int r = 0; r < 4; r++) {
        const float4* wp = (const float4*)(g_W12 + (size_t)(lane * 4 + r) * 16);
        float4 a = wp[0], b = wp[1], c = wp[2], d = wp[3];
        wrf[r][0]=a.x; wrf[r][1]=a.y; wrf[r][2]=a.z; wrf[r][3]=a.w;
        wrf[r][4]=b.x; wrf[r][5]=b.y; wrf[r][6]=b.z; wrf[r][7]=b.w;
        wrf[r][8]=c.x; wrf[r][9]=c.y; wrf[r][10]=c.z; wrf[r][11]=c.w;
        wrf[r][12]=d.x; wrf[r][13]=d.y; wrf[r][14]=d.z; wrf[r][15]=d.w;
    }
    float4 x4 = ((const float4*)(g_X + (size_t)l * DM))[lane];
    float xv[4] = {x4.x, x4.y, x4.z, x4.w};
    float uv[16];
    #pragma unroll
    for (int k = 0; k < 16; k++) {
        float acc = xv[0] * wrf[0][k] + xv[1] * wrf[1][k]
                  + xv[2] * wrf[2][k] + xv[3] * wrf[3][k];
        #pragma unroll
        for (int off = 32; off > 0; off >>= 1) acc += __shfl_xor(acc, off, 64);
        uv[k] = acc;
    }
    if (lane == 0) {
        float* o = g_UV + (size_t)l * 16;
        *(float4*)(o + 0)  = make_float4(uv[0], uv[1], uv[2], uv[3]);
        *(float4*)(o + 4)  = make_float4(uv[4], uv[5], uv[6], uv[7]);
        *(float4*)(o + 8)  = make_float4(uv[8], uv[9], uv[10], uv[11]);
        *(float4*)(o + 12) = make_float4(uv[12], uv[13], uv[14], uv[15]);
    }
}

// ---------------------------------------------------------------------------
// y = X @ G via bf16x3 split MFMA; OUTPUT pre-split hi/lo bf16 (consumers:
// sampm MFMA A-operand, attn_scores reconstruction). 128x128, BK=32.
__global__ __launch_bounds__(256) void y_mf(int dummy)
{
    (void)dummy;
    __shared__ __align__(16) short As[128][40];
    __shared__ __align__(16) short Bs[128][40];
    int tid = threadIdx.x;
    int wid = tid >> 6, lane = tid & 63;
    int wm = wid >> 1, wn = wid & 1;
    int quad = lane >> 4, l16 = lane & 15;
    int row0 = blockIdx.y * 128, col0 = blockIdx.x * 128;
    f32x4 acc[4][4] = {};
    const short* Alist[3] = {(const short*)g_Xhi, (const short*)g_Xhi, (const short*)g_Xlo};
    const short* Blist[3] = {(const short*)g_GhiT, (const short*)g_GloT, (const short*)g_GhiT};
    #pragma unroll 1
    for (int pass = 0; pass < 3; pass++) {
        const short* A = Alist[pass];
        const short* B = Blist[pass];
        for (int k0 = 0; k0 < DM; k0 += 32) {
            __syncthreads();
            int r = tid >> 2, c = (tid & 3) * 8;
            #pragma unroll
            for (int p = 0; p < 2; p++) {
                *(short8v*)&As[r + p * 64][c] =
                    *(const short8v*)&A[(size_t)(row0 + r + p * 64) * DM + k0 + c];
                *(short8v*)&Bs[r + p * 64][c] =
                    *(const short8v*)&B[(size_t)(col0 + r + p * 64) * DM + k0 + c];
            }
            __syncthreads();
            bf16x8 af[4], bf_[4];
            #pragma unroll
            for (int mt = 0; mt < 4; mt++)
                af[mt] = *(const bf16x8*)&As[wm * 64 + mt * 16 + l16][quad * 8];
            #pragma unroll
            for (int nt = 0; nt < 4; nt++)
                bf_[nt] = *(const bf16x8*)&Bs[wn * 64 + nt * 16 + l16][quad * 8];
            #pragma unroll
            for (int mt = 0; mt < 4; mt++)
                #pragma unroll
                for (int nt = 0; nt < 4; nt++)
                    acc[mt][nt] = __builtin_amdgcn_mfma_f32_16x16x32_bf16(
                        af[mt], bf_[nt], acc[mt][nt], 0, 0, 0);
        }
    }
    #pragma unroll
    for (int mt = 0; mt < 4; mt++)
        #pragma unroll
        for (int nt = 0; nt < 4; nt++) {
            int col = col0 + wn * 64 + nt * 16 + l16;
            #pragma unroll
            for (int r = 0; r < 4; r++) {
                int row = row0 + wm * 64 + mt * 16 + quad * 4 + r;
                float v = acc[mt][nt][r];
                bf16 hi = __float2bfloat16(v);
                g_Yhi[(size_t)row * HD + col] = hi;
                g_Ylo[(size_t)row * HD + col] = __float2bfloat16(v - __bfloat162float(hi));
            }
        }
}

// ---------------------------------------------------------------------------
// bf16 MFMA GEMM (V / FFN — smooth numerics): 128x128 tile, BK=32, cvt-staging.
template<typename TC, bool GELU, bool RES>
__device__ __forceinline__ void mf_gemm_body(
    const float* __restrict__ A, const float* __restrict__ W,
    const float* __restrict__ bias, const float* __restrict__ res,
    TC* __restrict__ C, int K, int ldw, int ldc, int bx, int by)
{
    __shared__ __align__(16) short As[128][40];
    __shared__ __align__(16) short Bs[128][40];
    int tid = threadIdx.x;
    int wid = tid >> 6, lane = tid & 63;
    int wm = wid >> 1, wn = wid & 1;
    int quad = lane >> 4, l16 = lane & 15;
    int row0 = by * 128, col0 = bx * 128;
    f32x4 acc[4][4] = {};
    for (int k0 = 0; k0 < K; k0 += 32) {
        int ar = tid >> 3, ac = (tid & 7) * 4;
        #pragma unroll
        for (int i = 0; i < 4; i++) {
            float4 v = *(const float4*)&A[(size_t)(row0 + ar + i * 32) * K + k0 + ac];
            short4 s4 = {f2bf(v.x), f2bf(v.y), f2bf(v.z), f2bf(v.w)};
            *(short4*)&As[ar + i * 32][ac] = s4;
        }
        int bk = tid >> 5, bn = (tid & 31) * 4;
        #pragma unroll
        for (int i = 0; i < 4; i++) {
            int kk = bk + i * 8;
            float4 v = *(const float4*)&W[(size_t)(k0 + kk) * ldw + col0 + bn];
            Bs[bn + 0][kk] = f2bf(v.x);
            Bs[bn + 1][kk] = f2bf(v.y);
            Bs[bn + 2][kk] = f2bf(v.z);
            Bs[bn + 3][kk] = f2bf(v.w);
        }
        __syncthreads();
        bf16x8 af[4], bf_[4];
        #pragma unroll
        for (int mt = 0; mt < 4; mt++)
            af[mt] = *(const bf16x8*)&As[wm * 64 + mt * 16 + l16][quad * 8];
        #pragma unroll
        for (int nt = 0; nt < 4; nt++)
            bf_[nt] = *(const bf16x8*)&Bs[wn * 64 + nt * 16 + l16][quad * 8];
        #pragma unroll
        for (int mt = 0; mt < 4; mt++)
            #pragma unroll
            for (int nt = 0; nt < 4; nt++)
                acc[mt][nt] = __builtin_amdgcn_mfma_f32_16x16x32_bf16(
                    af[mt], bf_[nt], acc[mt][nt], 0, 0, 0);
        __syncthreads();
    }
    #pragma unroll
    for (int mt = 0; mt < 4; mt++) {
        #pragma unroll
        for (int nt = 0; nt < 4; nt++) {
            int col = col0 + wn * 64 + nt * 16 + l16;
            float bv = bias[col];
            #pragma unroll
            for (int r = 0; r < 4; r++) {
                int row = row0 + wm * 64 + mt * 16 + quad * 4 + r;
                float v = acc[mt][nt][r] + bv;
                if (RES) v += res[(size_t)row * ldc + col];
                if (GELU) v = 0.5f * v * (1.0f + erff(v * 0.70710678118654752440f));
                st(C, (size_t)row * ldc + col, v);
            }
        }
    }
}

__global__ __launch_bounds__(256) void v_mf(const float* __restrict__ W,
                                            const float* __restrict__ bias) {
    mf_gemm_body<float, false, false>(g_X, W, bias, nullptr, g_V, DM, HD, HD,
                                      blockIdx.x, blockIdx.y);
}
__global__ __launch_bounds__(256) void ffn1_mf(const float* __restrict__ W,
                                               const float* __restrict__ bias) {
    mf_gemm_body<float, true, false>(g_X, W, bias, nullptr, g_HF, DM, DFF, DFF,
                                     blockIdx.x, blockIdx.y);
}
__global__ __launch_bounds__(256) void ffn2_mf(const float* __restrict__ W,
                                               const float* __restrict__ bias) {
    mf_gemm_body<float, false, true>(g_HF, W, bias, g_X, g_TMP, DFF, DM, DM,
                                     blockIdx.x, blockIdx.y);
}

// ---------------------------------------------------------------------------
// Sampled scores + sparsity M via MFMA. ONE WAVE per (b,l): S[h][u] =
// Y_l[h,:]·X_{s_u} as 16x16x32 MFMAs (M=16: heads 0-7 + dup, N=3x16 u-slots,
// K=256), bf16x3 split (Yhi·Xhi + Ylo·Xhi + Yhi·Xlo). A/B frags loaded
// DIRECTLY from global (no LDS, no per-sample shuffles — round-11 was
// DS-pipe-bound at ~520 DS ops/wave; this is ~70).
__global__ __launch_bounds__(256) void sampm_kernel(const int* __restrict__ idx)
{
    int wly = threadIdx.x >> 6, lane = threadIdx.x & 63;
    int bl = blockIdx.x * 4 + wly;        // b*Lseq + l
    int b = bl >> 11, l = bl & (Lseq - 1);
    int quad = lane >> 4, l16 = lane & 15;

    // A-frags: Y row (8 heads; lanes l16>=8 duplicate heads 0-7 — their C
    // rows are discarded).  A[m][k] = Y[l][(m&7)*256 + k].
    const short* yh = (const short*)g_Yhi + (size_t)bl * HD + (l16 & 7) * DM;
    const short* yl = (const short*)g_Ylo + (size_t)bl * HD + (l16 & 7) * DM;
    bf16x8 ah[8], al[8];
    #pragma unroll
    for (int kk = 0; kk < 8; kk++) {
        ah[kk] = *(const bf16x8*)&yh[kk * 32 + quad * 8];
        al[kk] = *(const bf16x8*)&yl[kk * 32 + quad * 8];
    }
    // sample index registers: lane j holds idx[l][j] (j<40; clamped above).
    int myidx = idx[l * SK + (lane < SK ? lane : SK - 1)] & (Lseq - 1);

    f32x4 acc[3];
    float4 v4[3];
    #pragma unroll 1
    for (int t = 0; t < 3; t++) {
        int su = t * 16 + l16; if (su >= SK) su = SK - 1;
        int s = __shfl(myidx, su, 64);
        const short* xh = (const short*)g_Xhi + (size_t)(b * Lseq + s) * DM;
        const short* xl = (const short*)g_Xlo + (size_t)(b * Lseq + s) * DM;
        f32x4 a = {0.f, 0.f, 0.f, 0.f};
        #pragma unroll
        for (int kk = 0; kk < 8; kk++) {
            bf16x8 bh  = *(const bf16x8*)&xh[kk * 32 + quad * 8];
            bf16x8 blo = *(const bf16x8*)&xl[kk * 32 + quad * 8];
            a = __builtin_amdgcn_mfma_f32_16x16x32_bf16(ah[kk], bh,  a, 0, 0, 0);
            a = __builtin_amdgcn_mfma_f32_16x16x32_bf16(al[kk], bh,  a, 0, 0, 0);
            a = __builtin_amdgcn_mfma_f32_16x16x32_bf16(ah[kk], blo, a, 0, 0, 0);
        }
        acc[t] = a;
        // v terms for this sample, heads (quad&1)*4 .. +3
        v4[t] = *(const float4*)(g_UV + (size_t)(b * Lseq + s) * 16 + 8 + (quad & 1) * 4);
    }
    // per-r (head = quad*4+r for quad<2) max/sum over valid u
    float mxs[4] = {-INFINITY, -INFINITY, -INFINITY, -INFINITY};
    float sms[4] = {0.f, 0.f, 0.f, 0.f};
    #pragma unroll
    for (int t = 0; t < 3; t++) {
        int u = t * 16 + l16;
        bool valid = u < SK;
        float vv[4] = {v4[t].x, v4[t].y, v4[t].z, v4[t].w};
        #pragma unroll
        for (int r = 0; r < 4; r++) {
            float sc = acc[t][r] + vv[r];
            if (valid) { mxs[r] = fmaxf(mxs[r], sc); sms[r] += sc; }
        }
    }
    // reduce over the 16 lanes of each quad (xor 1,2,4,8 stays in-quad)
    #pragma unroll
    for (int off = 1; off <= 8; off <<= 1)
        #pragma unroll
        for (int r = 0; r < 4; r++) {
            mxs[r] = fmaxf(mxs[r], __shfl_xor(mxs[r], off, 64));
            sms[r] += __shfl_xor(sms[r], off, 64);
        }
    if (quad < 2 && l16 < 4) {
        int h = quad * 4 + l16;
        float mx = (l16 == 0) ? mxs[0] : (l16 == 1) ? mxs[1] : (l16 == 2) ? mxs[2] : mxs[3];
        float sm = (l16 == 0) ? sms[0] : (l16 == 1) ? sms[1] : (l16 == 2) ? sms[2] : sms[3];
        float uu = g_UV[(size_t)bl * 16 + h];
        float cc = g_C[h];
        g_MB[(size_t)(b * HH + h) * Lseq + l] =
            (mx + uu + cc) - (sm + (float)SK * (uu + cc)) * (1.0f / (float)Lseq);
    }
}

// ---------------------------------------------------------------------------
// Top-5 per (b,h): grid 32. 5 masked argmax passes (ties -> lower index).
__global__ __launch_bounds__(256) void topk_kernel(int dummy)
{
    (void)dummy;
    __shared__ float vals[Lseq];
    __shared__ float rv[256];
    __shared__ int ri[256];
    int bh = blockIdx.x, tid = threadIdx.x;
    for (int i = tid; i < Lseq; i += 256) vals[i] = g_MB[bh * Lseq + i];
    __syncthreads();
    for (int t = 0; t < NTOP; t++) {
        float bv = -INFINITY; int bi = Lseq - 1;
        for (int i = tid; i < Lseq; i += 256) {
            float v = vals[i];
            if (v > bv || (v == bv && i < bi)) { bv = v; bi = i; }
        }
        rv[tid] = bv; ri[tid] = bi;
        __syncthreads();
        for (int s = 128; s > 0; s >>= 1) {
            if (tid < s) {
                float ov = rv[tid + s]; int oi = ri[tid + s];
                if (ov > rv[tid] || (ov == rv[tid] && oi < ri[tid])) { rv[tid] = ov; ri[tid] = oi; }
            }
            __syncthreads();
        }
        if (tid == 0) { g_MTOP[bh * NTOP + t] = ri[0]; vals[ri[0] & (Lseq - 1)] = -INFINITY; }
        __syncthreads();
    }
}

// ---------------------------------------------------------------------------
// Scores for top queries via y·x + affine: grid (NBT, NCHUNK). Thread = key.
__global__ __launch_bounds__(256) void attn_scores(int dummy)
{
    (void)dummy;
    __shared__ __align__(16) float ys[DM];
    int bt = blockIdx.x, chunk = blockIdx.y, tid = threadIdx.x;
    int bh = bt / NTOP;
    int b = bh >> 3, h = bh & 7;
    int ltop = g_MTOP[bt] & (Lseq - 1);
    size_t yi = (size_t)(b * Lseq + ltop) * HD + h * DM + tid;
    ys[tid] = b2f(g_Yhi[yi]) + b2f(g_Ylo[yi]);
    __syncthreads();
    float uu = g_UV[(size_t)(b * Lseq + ltop) * 16 + h];
    float cc = g_C[h];
    int j = chunk * 256 + tid;
    const float4* xrow = (const float4*)(g_X + (size_t)(b * Lseq + j) * DM);
    float acc = 0.f;
    for (int d4 = 0; d4 < DM / 4; d4++) {
        float4 xf = xrow[d4];
        float4 yf = ((const float4*)ys)[d4];
        acc += yf.x * xf.x + yf.y * xf.y + yf.z * xf.z + yf.w * xf.w;
    }
    float vv = g_UV[(size_t)(b * Lseq + j) * 16 + 8 + h];
    g_SC[(size_t)bt * Lseq + j] = acc + uu + vv + cc;
}

// Softmax in place over g_SC row: grid NBT.
__global__ __launch_bounds__(256) void attn_softmax(int dummy)
{
    (void)dummy;
    __shared__ float sc[Lseq];
    __shared__ float red[256];
    int bt = blockIdx.x, tid = threadIdx.x;
    for (int i = tid; i < Lseq; i += 256) sc[i] = g_SC[(size_t)bt * Lseq + i];
    __syncthreads();
    float m = -INFINITY;
    for (int i = tid; i < Lseq; i += 256) m = fmaxf(m, sc[i]);
    red[tid] = m; __syncthreads();
    for (int s = 128; s > 0; s >>= 1) { if (tid < s) red[tid] = fmaxf(red[tid], red[tid + s]); __syncthreads(); }
    m = red[0]; __syncthreads();
    float sum = 0.f;
    for (int i = tid; i < Lseq; i += 256) { float e = expf(sc[i] - m); sc[i] = e; sum += e; }
    red[tid] = sum; __syncthreads();
    for (int s = 128; s > 0; s >>= 1) { if (tid < s) red[tid] += red[tid + s]; __syncthreads(); }
    float inv = 1.0f / red[0]; __syncthreads();
    for (int i = tid; i < Lseq; i += 256) g_SC[(size_t)bt * Lseq + i] = sc[i] * inv;
}

// Partial ctx over one key chunk: grid (NBT, NCHUNK). Thread = dim.
__global__ __launch_bounds__(256) void attn_ctx(int dummy)
{
    (void)dummy;
    __shared__ float ps[256];
    int bt = blockIdx.x, chunk = blockIdx.y, tid = threadIdx.x;
    int bh = bt / NTOP;
    int b = bh >> 3, h = bh & 7;
    int j0 = chunk * 256;
    ps[tid] = g_SC[(size_t)bt * Lseq + j0 + tid];
    __syncthreads();
    float accv = 0.f;
    const float* vbase = g_V + ((size_t)(b * Lseq + j0)) * HD + h * DM + tid;
    for (int j = 0; j < 256; j++) accv += ps[j] * vbase[(size_t)j * HD];
    g_CTXP[((size_t)bt * NCHUNK + chunk) * DM + tid] = accv;
}

// ---------------------------------------------------------------------------
__global__ __launch_bounds__(256) void add_bias_kernel(const float* __restrict__ bo)
{
    int i = blockIdx.x * 256 + threadIdx.x;
    g_TMP[i] = g_X[i] + bo[i & (DM - 1)];
}

__global__ __launch_bounds__(256) void scatter_kernel(const float* __restrict__ Wo_l)
{
    __shared__ float cs[DM];
    int bt = blockIdx.x, tid = threadIdx.x;
    int bh = bt / NTOP;
    int b = bh >> 3, h = bh & 7;
    float s = 0.f;
    #pragma unroll
    for (int c = 0; c < NCHUNK; c++) s += g_CTXP[((size_t)bt * NCHUNK + c) * DM + tid];
    cs[tid] = s;
    __syncthreads();
    int row = g_MTOP[bt] & (Lseq - 1);
    float acc = 0.f;
    const float* w = Wo_l + (size_t)h * DM * DM + tid;
    for (int d = 0; d < DM; d++) acc += cs[d] * w[(size_t)d * DM];
    atomicAdd(&g_TMP[((size_t)(b * Lseq) + row) * DM + tid], acc);
}

// ---------------------------------------------------------------------------
// LayerNorm g_TMP -> g_X (+ Xhi/Xlo bf16 splits), one wave per row of 256.
__global__ __launch_bounds__(256) void ln_kernel(const float* __restrict__ g,
                                                 const float* __restrict__ bb)
{
    int wid = blockIdx.x * 4 + (threadIdx.x >> 6);
    if (wid >= MROWS) return;
    int lane = threadIdx.x & 63;
    const float4* row = (const float4*)(g_TMP + (size_t)wid * DM);
    float4 v = row[lane];
    float s = v.x + v.y + v.z + v.w;
    #pragma unroll
    for (int off = 32; off > 0; off >>= 1) s += __shfl_down(s, off, 64);
    s = __shfl(s, 0, 64);
    float mean = s * (1.f / DM);
    float4 d = {v.x - mean, v.y - mean, v.z - mean, v.w - mean};
    float q = d.x * d.x + d.y * d.y + d.z * d.z + d.w * d.w;
    #pragma unroll
    for (int off = 32; off > 0; off >>= 1) q += __shfl_down(q, off, 64);
    q = __shfl(q, 0, 64);
    float inv = rsqrtf(q * (1.f / DM) + 1e-5f);
    int c = lane * 4;
    float4 o;
    o.x = d.x * inv * g[c + 0] + bb[c + 0];
    o.y = d.y * inv * g[c + 1] + bb[c + 1];
    o.z = d.z * inv * g[c + 2] + bb[c + 2];
    o.w = d.w * inv * g[c + 3] + bb[c + 3];
    ((float4*)(g_X + (size_t)wid * DM))[lane] = o;
    float ov[4] = {o.x, o.y, o.z, o.w};
    short hi[4], lo[4];
    #pragma unroll
    for (int t = 0; t < 4; t++) {
        bf16 hb = __float2bfloat16(ov[t]);
        hi[t] = *(short*)&hb;
        bf16 lb = __float2bfloat16(ov[t] - __bfloat162float(hb));
        lo[t] = *(short*)&lb;
    }
    *(short4*)((short*)g_Xhi + (size_t)wid * DM + c) = make_short4(hi[0], hi[1], hi[2], hi[3]);
    *(short4*)((short*)g_Xlo + (size_t)wid * DM + c) = make_short4(lo[0], lo[1], lo[2], lo[3]);
}

// ---------------------------------------------------------------------------
__global__ __launch_bounds__(256) void final_kernel(
    const float* __restrict__ g, const float* __restrict__ bb,
    const float* __restrict__ pw, const float* __restrict__ pb,
    float* __restrict__ out)
{
    __shared__ float red[256];
    int b = blockIdx.x, tid = threadIdx.x;
    const float* row = g_X + ((size_t)(b * Lseq + Lseq - 1)) * DM;
    float v = row[tid];
    red[tid] = v; __syncthreads();
    for (int s = 128; s > 0; s >>= 1) { if (tid < s) red[tid] += red[tid + s]; __syncthreads(); }
    float mean = red[0] * (1.f / DM); __syncthreads();
    float d = v - mean;
    red[tid] = d * d; __syncthreads();
    for (int s = 128; s > 0; s >>= 1) { if (tid < s) red[tid] += red[tid + s]; __syncthreads(); }
    float var = red[0] * (1.f / DM); __syncthreads();
    float xn = d * rsqrtf(var + 1e-5f) * g[tid] + bb[tid];
    red[tid] = xn * pw[tid]; __syncthreads();
    for (int s = 128; s > 0; s >>= 1) { if (tid < s) red[tid] += red[tid + s]; __syncthreads(); }
    if (tid == 0) out[b] = red[0] + pb[0];
}

// ---------------------------------------------------------------------------
extern "C" void kernel_launch(void* const* d_in, const int* in_sizes, int n_in,
                              void* d_out, int out_size, void* d_ws, size_t ws_size,
                              hipStream_t stream)
{
    const float* x_enc = (const float*)d_in[0];
    const int*   isamp = (const int*)d_in[1];
    const float* emb_W = (const float*)d_in[2];
    const float* emb_b = (const float*)d_in[3];
    const float* Wq = (const float*)d_in[4];
    const float* bq = (const float*)d_in[5];
    const float* Wk = (const float*)d_in[6];
    const float* bk = (const float*)d_in[7];
    const float* Wv = (const float*)d_in[8];
    const float* bv = (const float*)d_in[9];
    const float* Wo = (const float*)d_in[10];
    const float* bo = (const float*)d_in[11];
    const float* c1W = (const float*)d_in[12];
    const float* c1b = (const float*)d_in[13];
    const float* c2W = (const float*)d_in[14];
    const float* c2b = (const float*)d_in[15];
    const float* ln1g = (const float*)d_in[16];
    const float* ln1b = (const float*)d_in[17];
    const float* ln2g = (const float*)d_in[18];
    const float* ln2b = (const float*)d_in[19];
    const float* nfg  = (const float*)d_in[20];
    const float* nfb  = (const float*)d_in[21];
    const float* projW = (const float*)d_in[22];
    const float* projb = (const float*)d_in[23];
    (void)d_ws; (void)ws_size; (void)in_sizes; (void)n_in; (void)out_size;

    dim3 blk(256);
    emb_gemm<<<dim3(DM / 128, MROWS / 128), blk, 0, stream>>>(x_enc, emb_W, emb_b);

    for (int l = 0; l < 2; l++) {
        const float* Wq_l = Wq + (size_t)l * DM * HD;
        const float* Wk_l = Wk + (size_t)l * DM * HD;
        const float* Wv_l = Wv + (size_t)l * DM * HD;
        const float* Wo_l = Wo + (size_t)l * HD * DM;

        gt_gemm<<<dim3(4, 4, 8), blk, 0, stream>>>(Wq_l, Wk_l);
        wc_kernel<<<dim3(HH), blk, 0, stream>>>(Wq_l, Wk_l, bq + l * HD, bk + l * HD);
        y_mf<<<dim3(HD / 128, MROWS / 128), blk, 0, stream>>>(0);
        uv_kernel<<<dim3(MROWS / 4), blk, 0, stream>>>(0);
        v_mf<<<dim3(HD / 128, MROWS / 128), blk, 0, stream>>>(Wv_l, bv + l * HD);

        sampm_kernel<<<dim3(MROWS / 4), blk, 0, stream>>>(isamp);
        topk_kernel<<<dim3(Bsz * HH), blk, 0, stream>>>(0);

        attn_scores<<<dim3(NBT, NCHUNK), blk, 0, stream>>>(0);
        attn_softmax<<<dim3(NBT), blk, 0, stream>>>(0);
        attn_ctx<<<dim3(NBT, NCHUNK), blk, 0, stream>>>(0);

        add_bias_kernel<<<dim3(MROWS), blk, 0, stream>>>(bo + l * DM);
        scatter_kernel<<<dim3(NBT), blk, 0, stream>>>(Wo_l);
        ln_kernel<<<dim3(MROWS / 4), blk, 0, stream>>>(ln1g + l * DM, ln1b + l * DM);

        ffn1_mf<<<dim3(DFF / 128, MROWS / 128), blk, 0, stream>>>(
            c1W + (size_t)l * DM * DFF, c1b + l * DFF);
        ffn2_mf<<<dim3(DM / 128, MROWS / 128), blk, 0, stream>>>(
            c2W + (size_t)l * DFF * DM, c2b + l * DM);
        ln_kernel<<<dim3(MROWS / 4), blk, 0, stream>>>(ln2g + l * DM, ln2b + l * DM);
    }

    final_kernel<<<dim3(Bsz), blk, 0, stream>>>(nfg, nfb, projW, projb, (float*)d_out);
}

// Round 13
// 849.126 us; speedup vs baseline: 2.0832x; 1.2156x over previous
//
#include <hip/hip_runtime.h>
#include <hip/hip_bf16.h>
#include <math.h>

typedef __hip_bfloat16 bf16;
typedef __attribute__((ext_vector_type(8))) short bf16x8;   // MFMA A/B frag
typedef __attribute__((ext_vector_type(8))) short short8v;  // 16B bf16 vector
typedef __attribute__((ext_vector_type(4))) float f32x4;    // MFMA C/D frag

// Problem constants
#define Bsz 4
#define Lseq 2048
#define DM 256       // d_model == per-head D
#define HH 8
#define HD 2048      // H * DM
#define DFF 1024
#define SK 40
#define NTOP 5
#define MROWS 8192   // B * L
#define NBT (Bsz * HH * NTOP)   // 160
#define NCHUNK 8

// ---------------------------------------------------------------------------
// Static device scratch. __align__(256) REQUIRED (float4 casts).
// score = y·x + u + v + c (G=Wq Wk^T factoring; Q/K never materialized).
// V never materialized either: ctx = (P@X)·Wv + bv  (ΣP=1).
__device__ __align__(256) float g_X  [MROWS * DM];    //   8 MB activations (fp32)
__device__ __align__(256) bf16  g_Xhi[MROWS * DM];    //   4 MB bf16(X)
__device__ __align__(256) bf16  g_Xlo[MROWS * DM];    //   4 MB bf16(X - hi)
__device__ __align__(256) float g_TMP[MROWS * DM];    //   8 MB residual accum
__device__ __align__(256) bf16  g_Yhi[MROWS * HD];    //  32 MB bf16(y)
__device__ __align__(256) bf16  g_Ylo[MROWS * HD];    //  32 MB bf16(y - hi)
__device__ __align__(256) bf16  g_HFb[MROWS * DFF];   //  16 MB FFN hidden (bf16)
__device__ __align__(256) bf16  g_GhiT[HD * DM];      //   1 MB G^T hi (n-major)
__device__ __align__(256) bf16  g_GloT[HD * DM];      //   1 MB G^T lo
__device__ __align__(256) float g_UV [MROWS * 16];    // [l][0..7]=u_h, [8..15]=v_h
__device__ __align__(256) float g_W12[DM * 16];
__device__ __align__(256) float g_C  [HH];
__device__ __align__(256) float g_MB [Bsz * HH * Lseq];
__device__ __align__(256) float g_SC [NBT * Lseq];
__device__ __align__(256) float g_CTXP[NBT * NCHUNK * DM];  // partial P@X
__device__ __align__(256) int   g_MTOP[NBT];

__device__ __forceinline__ float ld(const float* p, size_t i) { return p[i]; }
__device__ __forceinline__ float ld(const bf16* p, size_t i) { return __bfloat162float(p[i]); }
__device__ __forceinline__ float b2f(bf16 x) { return __bfloat162float(x); }
__device__ __forceinline__ void st(float* p, size_t i, float v) { p[i] = v; }
__device__ __forceinline__ void st(bf16* p, size_t i, float v) { p[i] = __float2bfloat16(v); }
__device__ __forceinline__ short f2bf(float v) {
    union { bf16 h; short s; } u; u.h = __float2bfloat16(v); return u.s;
}

// ---------------------------------------------------------------------------
// fp32 tiled GEMM, 128x128 tile, BK=16, 8x8 per thread (embedding only).
template<typename TA, typename TC, bool GELU, bool RES>
__device__ __forceinline__ void gemm_body(
    const TA* __restrict__ A, const float* __restrict__ W,
    const float* __restrict__ bias, const float* __restrict__ res,
    TC* __restrict__ C, int K, int ldw, int ldc, int bx, int by)
{
    const int BM = 128, BN = 128, BK = 16;
    __shared__ __align__(16) float As[BK][BM + 4];
    __shared__ __align__(16) float Bs[BK][BN];
    int tid = threadIdx.x;
    int tx = tid & 15, ty = tid >> 4;
    int row0 = by * BM, col0 = bx * BN;
    float acc[8][8] = {};
    for (int k0 = 0; k0 < K; k0 += BK) {
        #pragma unroll
        for (int i = 0; i < 8; i++) {
            int idx = tid + i * 256;
            int r = idx >> 4, c = idx & 15;
            As[c][r] = ld(A, (size_t)(row0 + r) * K + k0 + c);
        }
        #pragma unroll
        for (int i = 0; i < 8; i++) {
            int idx = tid + i * 256;
            int r = idx >> 7, c = idx & 127;
            Bs[r][c] = W[(size_t)(k0 + r) * ldw + col0 + c];
        }
        __syncthreads();
        #pragma unroll
        for (int kk = 0; kk < BK; kk++) {
            float4 a0 = *(const float4*)&As[kk][ty * 8];
            float4 a1 = *(const float4*)&As[kk][ty * 8 + 4];
            float4 b0 = *(const float4*)&Bs[kk][tx * 8];
            float4 b1 = *(const float4*)&Bs[kk][tx * 8 + 4];
            float av[8] = {a0.x, a0.y, a0.z, a0.w, a1.x, a1.y, a1.z, a1.w};
            float bv[8] = {b0.x, b0.y, b0.z, b0.w, b1.x, b1.y, b1.z, b1.w};
            #pragma unroll
            for (int i = 0; i < 8; i++)
                #pragma unroll
                for (int j = 0; j < 8; j++) acc[i][j] += av[i] * bv[j];
        }
        __syncthreads();
    }
    #pragma unroll
    for (int i = 0; i < 8; i++) {
        int r = row0 + ty * 8 + i;
        #pragma unroll
        for (int j = 0; j < 8; j++) {
            int c = col0 + tx * 8 + j;
            float v = acc[i][j] + bias[c];
            if (RES) v += res[(size_t)r * ldc + c];
            if (GELU) v = 0.5f * v * (1.0f + erff(v * 0.70710678118654752440f));
            st(C, (size_t)r * ldc + c, v);
        }
    }
}

// embedding: also emits Xhi/Xlo bf16 splits for the MFMA consumers.
__global__ __launch_bounds__(256) void emb_gemm(const float* __restrict__ A,
                                                const float* __restrict__ W,
                                                const float* __restrict__ bias)
{
    const int BM = 128;
    int tid = threadIdx.x;
    gemm_body<float, float, false, false>(A, W, bias, nullptr, g_X, 32, DM, DM,
                                          blockIdx.x, blockIdx.y);
    int row0 = blockIdx.y * BM, col0 = blockIdx.x * 128;
    for (int i = 0; i < 8; i++) {
        int idx = tid + i * 256;
        int r = row0 + (idx >> 7), c = col0 + (idx & 127);
        float v = g_X[(size_t)r * DM + c];
        bf16 hi = __float2bfloat16(v);
        g_Xhi[(size_t)r * DM + c] = hi;
        g_Xlo[(size_t)r * DM + c] = __float2bfloat16(v - __bfloat162float(hi));
    }
}

// ---------------------------------------------------------------------------
// G^T_h = (Wq_h @ Wk_h^T)^T, written pre-split bf16 (hi/lo), n-major [HD][DM].
__global__ __launch_bounds__(256) void gt_gemm(const float* __restrict__ Wq,
                                               const float* __restrict__ Wk)
{
    __shared__ float Aq[16][68];
    __shared__ float Ak[16][68];
    int h = blockIdx.z;
    int jt = blockIdx.x * 64, it = blockIdx.y * 64;
    int tid = threadIdx.x, tx = tid & 15, ty = tid >> 4;
    float acc[4][4] = {};
    for (int d0 = 0; d0 < DM; d0 += 16) {
        #pragma unroll
        for (int p = 0; p < 4; p++) {
            int idx = tid + p * 256;
            int i = idx >> 4, d = idx & 15;
            Aq[d][i] = Wq[(size_t)(it + i) * HD + h * DM + d0 + d];
            Ak[d][i] = Wk[(size_t)(jt + i) * HD + h * DM + d0 + d];
        }
        __syncthreads();
        #pragma unroll
        for (int d = 0; d < 16; d++) {
            float a[4], b[4];
            #pragma unroll
            for (int p = 0; p < 4; p++) { a[p] = Aq[d][ty * 4 + p]; b[p] = Ak[d][tx * 4 + p]; }
            #pragma unroll
            for (int i2 = 0; i2 < 4; i2++)
                #pragma unroll
                for (int j2 = 0; j2 < 4; j2++) acc[i2][j2] += a[i2] * b[j2];
        }
        __syncthreads();
    }
    #pragma unroll
    for (int i2 = 0; i2 < 4; i2++)
        #pragma unroll
        for (int j2 = 0; j2 < 4; j2++) {
            float v = acc[i2][j2];
            bf16 hi = __float2bfloat16(v);
            size_t gi = (size_t)(h * DM + jt + tx * 4 + j2) * DM + (it + ty * 4 + i2);
            g_GhiT[gi] = hi;
            g_GloT[gi] = __float2bfloat16(v - __bfloat162float(hi));
        }
}

// w1[i,h]=Wq_h[i,:]·bk_h, w2[i,h]=Wk_h[i,:]·bq_h, c[h]=bq_h·bk_h. grid 8.
__global__ __launch_bounds__(256) void wc_kernel(const float* __restrict__ Wq,
                                                 const float* __restrict__ Wk,
                                                 const float* __restrict__ bq,
                                                 const float* __restrict__ bk)
{
    __shared__ float red[256];
    int h = blockIdx.x, i = threadIdx.x;
    const float4* qr  = (const float4*)(Wq + (size_t)i * HD + h * DM);
    const float4* kr  = (const float4*)(Wk + (size_t)i * HD + h * DM);
    const float4* bkr = (const float4*)(bk + h * DM);
    const float4* bqr = (const float4*)(bq + h * DM);
    float s1 = 0.f, s2 = 0.f;
    for (int j = 0; j < DM / 4; j++) {
        float4 q4 = qr[j], k4 = kr[j], b1 = bkr[j], b2 = bqr[j];
        s1 += q4.x * b1.x + q4.y * b1.y + q4.z * b1.z + q4.w * b1.w;
        s2 += k4.x * b2.x + k4.y * b2.y + k4.z * b2.z + k4.w * b2.w;
    }
    g_W12[i * 16 + h] = s1;
    g_W12[i * 16 + 8 + h] = s2;
    red[i] = bq[h * DM + i] * bk[h * DM + i];
    __syncthreads();
    for (int s = 128; s > 0; s >>= 1) { if (i < s) red[i] += red[i + s]; __syncthreads(); }
    if (i == 0) g_C[h] = red[0];
}

// u[l,h]=x_l·w1[:,h], v[l,h]=x_l·w2[:,h]. One wave per row; grid MROWS/4.
__global__ __launch_bounds__(256) void uv_kernel(int dummy)
{
    (void)dummy;
    int w = threadIdx.x >> 6, lane = threadIdx.x & 63;
    int l = blockIdx.x * 4 + w;
    float wrf[4][16];
    #pragma unroll
    for (int r = 0; r < 4; r++) {
        const float4* wp = (const float4*)(g_W12 + (size_t)(lane * 4 + r) * 16);
        float4 a = wp[0], b = wp[1], c = wp[2], d = wp[3];
        wrf[r][0]=a.x; wrf[r][1]=a.y; wrf[r][2]=a.z; wrf[r][3]=a.w;
        wrf[r][4]=b.x; wrf[r][5]=b.y; wrf[r][6]=b.z; wrf[r][7]=b.w;
        wrf[r][8]=c.x; wrf[r][9]=c.y; wrf[r][10]=c.z; wrf[r][11]=c.w;
        wrf[r][12]=d.x; wrf[r][13]=d.y; wrf[r][14]=d.z; wrf[r][15]=d.w;
    }
    float4 x4 = ((const float4*)(g_X + (size_t)l * DM))[lane];
    float xv[4] = {x4.x, x4.y, x4.z, x4.w};
    float uv[16];
    #pragma unroll
    for (int k = 0; k < 16; k++) {
        float acc = xv[0] * wrf[0][k] + xv[1] * wrf[1][k]
                  + xv[2] * wrf[2][k] + xv[3] * wrf[3][k];
        #pragma unroll
        for (int off = 32; off > 0; off >>= 1) acc += __shfl_xor(acc, off, 64);
        uv[k] = acc;
    }
    if (lane == 0) {
        float* o = g_UV + (size_t)l * 16;
        *(float4*)(o + 0)  = make_float4(uv[0], uv[1], uv[2], uv[3]);
        *(float4*)(o + 4)  = make_float4(uv[4], uv[5], uv[6], uv[7]);
        *(float4*)(o + 8)  = make_float4(uv[8], uv[9], uv[10], uv[11]);
        *(float4*)(o + 12) = make_float4(uv[12], uv[13], uv[14], uv[15]);
    }
}

// ---------------------------------------------------------------------------
// y = X @ G via bf16x3 split MFMA; OUTPUT pre-split hi/lo bf16. 128x128, BK=32.
__global__ __launch_bounds__(256) void y_mf(int dummy)
{
    (void)dummy;
    __shared__ __align__(16) short As[128][40];
    __shared__ __align__(16) short Bs[128][40];
    int tid = threadIdx.x;
    int wid = tid >> 6, lane = tid & 63;
    int wm = wid >> 1, wn = wid & 1;
    int quad = lane >> 4, l16 = lane & 15;
    int row0 = blockIdx.y * 128, col0 = blockIdx.x * 128;
    f32x4 acc[4][4] = {};
    const short* Alist[3] = {(const short*)g_Xhi, (const short*)g_Xhi, (const short*)g_Xlo};
    const short* Blist[3] = {(const short*)g_GhiT, (const short*)g_GloT, (const short*)g_GhiT};
    #pragma unroll 1
    for (int pass = 0; pass < 3; pass++) {
        const short* A = Alist[pass];
        const short* B = Blist[pass];
        for (int k0 = 0; k0 < DM; k0 += 32) {
            __syncthreads();
            int r = tid >> 2, c = (tid & 3) * 8;
            #pragma unroll
            for (int p = 0; p < 2; p++) {
                *(short8v*)&As[r + p * 64][c] =
                    *(const short8v*)&A[(size_t)(row0 + r + p * 64) * DM + k0 + c];
                *(short8v*)&Bs[r + p * 64][c] =
                    *(const short8v*)&B[(size_t)(col0 + r + p * 64) * DM + k0 + c];
            }
            __syncthreads();
            bf16x8 af[4], bf_[4];
            #pragma unroll
            for (int mt = 0; mt < 4; mt++)
                af[mt] = *(const bf16x8*)&As[wm * 64 + mt * 16 + l16][quad * 8];
            #pragma unroll
            for (int nt = 0; nt < 4; nt++)
                bf_[nt] = *(const bf16x8*)&Bs[wn * 64 + nt * 16 + l16][quad * 8];
            #pragma unroll
            for (int mt = 0; mt < 4; mt++)
                #pragma unroll
                for (int nt = 0; nt < 4; nt++)
                    acc[mt][nt] = __builtin_amdgcn_mfma_f32_16x16x32_bf16(
                        af[mt], bf_[nt], acc[mt][nt], 0, 0, 0);
        }
    }
    #pragma unroll
    for (int mt = 0; mt < 4; mt++)
        #pragma unroll
        for (int nt = 0; nt < 4; nt++) {
            int col = col0 + wn * 64 + nt * 16 + l16;
            #pragma unroll
            for (int r = 0; r < 4; r++) {
                int row = row0 + wm * 64 + mt * 16 + quad * 4 + r;
                float v = acc[mt][nt][r];
                bf16 hi = __float2bfloat16(v);
                g_Yhi[(size_t)row * HD + col] = hi;
                g_Ylo[(size_t)row * HD + col] = __float2bfloat16(v - __bfloat162float(hi));
            }
        }
}

// ---------------------------------------------------------------------------
// bf16 MFMA GEMM with RAW bf16 A (no cvt) + fp32 W cvt-staging. 128x128, BK=32.
// Numerically identical to cvt-staging from fp32 (A was bf16(X) either way).
template<typename TC, bool GELU, bool RES>
__device__ __forceinline__ void mf_gemm_bfA(
    const bf16* __restrict__ A, const float* __restrict__ W,
    const float* __restrict__ bias, const float* __restrict__ res,
    TC* __restrict__ C, int K, int ldw, int ldc, int bx, int by)
{
    __shared__ __align__(16) short As[128][40];
    __shared__ __align__(16) short Bs[128][40];
    int tid = threadIdx.x;
    int wid = tid >> 6, lane = tid & 63;
    int wm = wid >> 1, wn = wid & 1;
    int quad = lane >> 4, l16 = lane & 15;
    int row0 = by * 128, col0 = bx * 128;
    f32x4 acc[4][4] = {};
    for (int k0 = 0; k0 < K; k0 += 32) {
        // A raw bf16: 128 rows x 32 k; thread -> row tid&127, chunks of 8
        int r = tid & 127, cb = (tid >> 7) * 8;
        #pragma unroll
        for (int i = 0; i < 2; i++) {
            int c = cb + i * 16;
            *(short8v*)&As[r][c] =
                *(const short8v*)&((const short*)A)[(size_t)(row0 + r) * K + k0 + c];
        }
        int bk = tid >> 5, bn = (tid & 31) * 4;
        #pragma unroll
        for (int i = 0; i < 4; i++) {
            int kk = bk + i * 8;
            float4 v = *(const float4*)&W[(size_t)(k0 + kk) * ldw + col0 + bn];
            Bs[bn + 0][kk] = f2bf(v.x);
            Bs[bn + 1][kk] = f2bf(v.y);
            Bs[bn + 2][kk] = f2bf(v.z);
            Bs[bn + 3][kk] = f2bf(v.w);
        }
        __syncthreads();
        bf16x8 af[4], bf_[4];
        #pragma unroll
        for (int mt = 0; mt < 4; mt++)
            af[mt] = *(const bf16x8*)&As[wm * 64 + mt * 16 + l16][quad * 8];
        #pragma unroll
        for (int nt = 0; nt < 4; nt++)
            bf_[nt] = *(const bf16x8*)&Bs[wn * 64 + nt * 16 + l16][quad * 8];
        #pragma unroll
        for (int mt = 0; mt < 4; mt++)
            #pragma unroll
            for (int nt = 0; nt < 4; nt++)
                acc[mt][nt] = __builtin_amdgcn_mfma_f32_16x16x32_bf16(
                    af[mt], bf_[nt], acc[mt][nt], 0, 0, 0);
        __syncthreads();
    }
    #pragma unroll
    for (int mt = 0; mt < 4; mt++) {
        #pragma unroll
        for (int nt = 0; nt < 4; nt++) {
            int col = col0 + wn * 64 + nt * 16 + l16;
            float bv = bias[col];
            #pragma unroll
            for (int r = 0; r < 4; r++) {
                int row = row0 + wm * 64 + mt * 16 + quad * 4 + r;
                float v = acc[mt][nt][r] + bv;
                if (RES) v += res[(size_t)row * ldc + col];
                if (GELU) v = 0.5f * v * (1.0f + erff(v * 0.70710678118654752440f));
                st(C, (size_t)row * ldc + col, v);
            }
        }
    }
}

// FFN1: g_HFb(bf16) = gelu(Xhi @ c1W + c1b)
__global__ __launch_bounds__(256) void ffn1_mf(const float* __restrict__ W,
                                               const float* __restrict__ bias) {
    mf_gemm_bfA<bf16, true, false>(g_Xhi, W, bias, nullptr, g_HFb, DM, DFF, DFF,
                                   blockIdx.x, blockIdx.y);
}
// FFN2: g_TMP = g_HFb @ c2W + c2b + g_X
__global__ __launch_bounds__(256) void ffn2_mf(const float* __restrict__ W,
                                               const float* __restrict__ bias) {
    mf_gemm_bfA<float, false, true>(g_HFb, W, bias, g_X, g_TMP, DFF, DM, DM,
                                    blockIdx.x, blockIdx.y);
}

// ---------------------------------------------------------------------------
// Sampled scores + sparsity M via MFMA. ONE WAVE per (b,l). Round-13: kk-outer
// loop interchange — same per-acc accumulation order (bit-identical) but all
// 3 tiles' gathers pipeline (round-12 was pass-serialized, MfmaUtil 4%).
__global__ __launch_bounds__(256) void sampm_kernel(const int* __restrict__ idx)
{
    int wly = threadIdx.x >> 6, lane = threadIdx.x & 63;
    int bl = blockIdx.x * 4 + wly;        // b*Lseq + l
    int b = bl >> 11, l = bl & (Lseq - 1);
    int quad = lane >> 4, l16 = lane & 15;

    const short* yh = (const short*)g_Yhi + (size_t)bl * HD + (l16 & 7) * DM;
    const short* yl = (const short*)g_Ylo + (size_t)bl * HD + (l16 & 7) * DM;
    bf16x8 ah[8], al[8];
    #pragma unroll
    for (int kk = 0; kk < 8; kk++) {
        ah[kk] = *(const bf16x8*)&yh[kk * 32 + quad * 8];
        al[kk] = *(const bf16x8*)&yl[kk * 32 + quad * 8];
    }
    int myidx = idx[l * SK + (lane < SK ? lane : SK - 1)] & (Lseq - 1);

    const short* xh[3];
    const short* xl[3];
    float4 v4[3];
    #pragma unroll
    for (int t = 0; t < 3; t++) {
        int su = t * 16 + l16; if (su >= SK) su = SK - 1;
        int s = __shfl(myidx, su, 64);
        xh[t] = (const short*)g_Xhi + (size_t)(b * Lseq + s) * DM;
        xl[t] = (const short*)g_Xlo + (size_t)(b * Lseq + s) * DM;
        v4[t] = *(const float4*)(g_UV + (size_t)(b * Lseq + s) * 16 + 8 + (quad & 1) * 4);
    }
    f32x4 acc[3] = {};
    #pragma unroll
    for (int kk = 0; kk < 8; kk++) {
        #pragma unroll
        for (int t = 0; t < 3; t++) {
            bf16x8 bh  = *(const bf16x8*)&xh[t][kk * 32 + quad * 8];
            bf16x8 blo = *(const bf16x8*)&xl[t][kk * 32 + quad * 8];
            acc[t] = __builtin_amdgcn_mfma_f32_16x16x32_bf16(ah[kk], bh,  acc[t], 0, 0, 0);
            acc[t] = __builtin_amdgcn_mfma_f32_16x16x32_bf16(al[kk], bh,  acc[t], 0, 0, 0);
            acc[t] = __builtin_amdgcn_mfma_f32_16x16x32_bf16(ah[kk], blo, acc[t], 0, 0, 0);
        }
    }
    float mxs[4] = {-INFINITY, -INFINITY, -INFINITY, -INFINITY};
    float sms[4] = {0.f, 0.f, 0.f, 0.f};
    #pragma unroll
    for (int t = 0; t < 3; t++) {
        int u = t * 16 + l16;
        bool valid = u < SK;
        float vv[4] = {v4[t].x, v4[t].y, v4[t].z, v4[t].w};
        #pragma unroll
        for (int r = 0; r < 4; r++) {
            float sc = acc[t][r] + vv[r];
            if (valid) { mxs[r] = fmaxf(mxs[r], sc); sms[r] += sc; }
        }
    }
    #pragma unroll
    for (int off = 1; off <= 8; off <<= 1)
        #pragma unroll
        for (int r = 0; r < 4; r++) {
            mxs[r] = fmaxf(mxs[r], __shfl_xor(mxs[r], off, 64));
            sms[r] += __shfl_xor(sms[r], off, 64);
        }
    if (quad < 2 && l16 < 4) {
        int h = quad * 4 + l16;
        float mx = (l16 == 0) ? mxs[0] : (l16 == 1) ? mxs[1] : (l16 == 2) ? mxs[2] : mxs[3];
        float sm = (l16 == 0) ? sms[0] : (l16 == 1) ? sms[1] : (l16 == 2) ? sms[2] : sms[3];
        float uu = g_UV[(size_t)bl * 16 + h];
        float cc = g_C[h];
        g_MB[(size_t)(b * HH + h) * Lseq + l] =
            (mx + uu + cc) - (sm + (float)SK * (uu + cc)) * (1.0f / (float)Lseq);
    }
}

// ---------------------------------------------------------------------------
// Top-5 per (b,h): grid 32. 5 masked argmax passes (ties -> lower index).
__global__ __launch_bounds__(256) void topk_kernel(int dummy)
{
    (void)dummy;
    __shared__ float vals[Lseq];
    __shared__ float rv[256];
    __shared__ int ri[256];
    int bh = blockIdx.x, tid = threadIdx.x;
    for (int i = tid; i < Lseq; i += 256) vals[i] = g_MB[bh * Lseq + i];
    __syncthreads();
    for (int t = 0; t < NTOP; t++) {
        float bv = -INFINITY; int bi = Lseq - 1;
        for (int i = tid; i < Lseq; i += 256) {
            float v = vals[i];
            if (v > bv || (v == bv && i < bi)) { bv = v; bi = i; }
        }
        rv[tid] = bv; ri[tid] = bi;
        __syncthreads();
        for (int s = 128; s > 0; s >>= 1) {
            if (tid < s) {
                float ov = rv[tid + s]; int oi = ri[tid + s];
                if (ov > rv[tid] || (ov == rv[tid] && oi < ri[tid])) { rv[tid] = ov; ri[tid] = oi; }
            }
            __syncthreads();
        }
        if (tid == 0) { g_MTOP[bh * NTOP + t] = ri[0]; vals[ri[0] & (Lseq - 1)] = -INFINITY; }
        __syncthreads();
    }
}

// ---------------------------------------------------------------------------
// Scores for top queries via y·x + affine: grid (NBT, NCHUNK). Thread = key.
__global__ __launch_bounds__(256) void attn_scores(int dummy)
{
    (void)dummy;
    __shared__ __align__(16) float ys[DM];
    int bt = blockIdx.x, chunk = blockIdx.y, tid = threadIdx.x;
    int bh = bt / NTOP;
    int b = bh >> 3, h = bh & 7;
    int ltop = g_MTOP[bt] & (Lseq - 1);
    size_t yi = (size_t)(b * Lseq + ltop) * HD + h * DM + tid;
    ys[tid] = b2f(g_Yhi[yi]) + b2f(g_Ylo[yi]);
    __syncthreads();
    float uu = g_UV[(size_t)(b * Lseq + ltop) * 16 + h];
    float cc = g_C[h];
    int j = chunk * 256 + tid;
    const float4* xrow = (const float4*)(g_X + (size_t)(b * Lseq + j) * DM);
    float acc = 0.f;
    for (int d4 = 0; d4 < DM / 4; d4++) {
        float4 xf = xrow[d4];
        float4 yf = ((const float4*)ys)[d4];
        acc += yf.x * xf.x + yf.y * xf.y + yf.z * xf.z + yf.w * xf.w;
    }
    float vv = g_UV[(size_t)(b * Lseq + j) * 16 + 8 + h];
    g_SC[(size_t)bt * Lseq + j] = acc + uu + vv + cc;
}

// Softmax in place over g_SC row: grid NBT.
__global__ __launch_bounds__(256) void attn_softmax(int dummy)
{
    (void)dummy;
    __shared__ float sc[Lseq];
    __shared__ float red[256];
    int bt = blockIdx.x, tid = threadIdx.x;
    for (int i = tid; i < Lseq; i += 256) sc[i] = g_SC[(size_t)bt * Lseq + i];
    __syncthreads();
    float m = -INFINITY;
    for (int i = tid; i < Lseq; i += 256) m = fmaxf(m, sc[i]);
    red[tid] = m; __syncthreads();
    for (int s = 128; s > 0; s >>= 1) { if (tid < s) red[tid] = fmaxf(red[tid], red[tid + s]); __syncthreads(); }
    m = red[0]; __syncthreads();
    float sum = 0.f;
    for (int i = tid; i < Lseq; i += 256) { float e = expf(sc[i] - m); sc[i] = e; sum += e; }
    red[tid] = sum; __syncthreads();
    for (int s = 128; s > 0; s >>= 1) { if (tid < s) red[tid] += red[tid + s]; __syncthreads(); }
    float inv = 1.0f / red[0]; __syncthreads();
    for (int i = tid; i < Lseq; i += 256) g_SC[(size_t)bt * Lseq + i] = sc[i] * inv;
}

// Partial P@X over one key chunk: grid (NBT, NCHUNK). Thread = dim.
// (head-independent X rows -> 8x L2 reuse vs per-head V; V is never built)
__global__ __launch_bounds__(256) void attn_ctx(int dummy)
{
    (void)dummy;
    __shared__ float ps[256];
    int bt = blockIdx.x, chunk = blockIdx.y, tid = threadIdx.x;
    int bh = bt / NTOP;
    int b = bh >> 3;
    int j0 = chunk * 256;
    ps[tid] = g_SC[(size_t)bt * Lseq + j0 + tid];
    __syncthreads();
    float accv = 0.f;
    const float* xbase = g_X + ((size_t)(b * Lseq + j0)) * DM + tid;
    for (int j = 0; j < 256; j++) accv += ps[j] * xbase[(size_t)j * DM];
    g_CTXP[((size_t)bt * NCHUNK + chunk) * DM + tid] = accv;
}

// ---------------------------------------------------------------------------
__global__ __launch_bounds__(256) void add_bias_kernel(const float* __restrict__ bo)
{
    int i = blockIdx.x * 256 + threadIdx.x;
    g_TMP[i] = g_X[i] + bo[i & (DM - 1)];
}

// Reduce PX partials; ctx = PX@Wv_h + bv_h; out = ctx@Wo_h; scatter-add.
__global__ __launch_bounds__(256) void scatter_kernel(const float* __restrict__ Wv_l,
                                                      const float* __restrict__ bv_l,
                                                      const float* __restrict__ Wo_l)
{
    __shared__ float px[DM];
    __shared__ float cs[DM];
    int bt = blockIdx.x, tid = threadIdx.x;
    int bh = bt / NTOP;
    int b = bh >> 3, h = bh & 7;
    float s = 0.f;
    #pragma unroll
    for (int c = 0; c < NCHUNK; c++) s += g_CTXP[((size_t)bt * NCHUNK + c) * DM + tid];
    px[tid] = s;
    __syncthreads();
    // ctx[e] = sum_d px[d] * Wv[d][h*DM+e] + bv[h*DM+e]
    float acc = 0.f;
    const float* wv = Wv_l + h * DM + tid;
    for (int d = 0; d < DM; d++) acc += px[d] * wv[(size_t)d * HD];
    cs[tid] = acc + bv_l[h * DM + tid];
    __syncthreads();
    // out[f] = sum_e cs[e] * Wo[h*DM+e][f]
    float acc2 = 0.f;
    const float* wo = Wo_l + (size_t)(h * DM) * DM + tid;
    for (int e = 0; e < DM; e++) acc2 += cs[e] * wo[(size_t)e * DM];
    int row = g_MTOP[bt] & (Lseq - 1);
    atomicAdd(&g_TMP[((size_t)(b * Lseq) + row) * DM + tid], acc2);
}

// ---------------------------------------------------------------------------
// LayerNorm g_TMP -> g_X (+ Xhi/Xlo bf16 splits), one wave per row of 256.
__global__ __launch_bounds__(256) void ln_kernel(const float* __restrict__ g,
                                                 const float* __restrict__ bb)
{
    int wid = blockIdx.x * 4 + (threadIdx.x >> 6);
    if (wid >= MROWS) return;
    int lane = threadIdx.x & 63;
    const float4* row = (const float4*)(g_TMP + (size_t)wid * DM);
    float4 v = row[lane];
    float s = v.x + v.y + v.z + v.w;
    #pragma unroll
    for (int off = 32; off > 0; off >>= 1) s += __shfl_down(s, off, 64);
    s = __shfl(s, 0, 64);
    float mean = s * (1.f / DM);
    float4 d = {v.x - mean, v.y - mean, v.z - mean, v.w - mean};
    float q = d.x * d.x + d.y * d.y + d.z * d.z + d.w * d.w;
    #pragma unroll
    for (int off = 32; off > 0; off >>= 1) q += __shfl_down(q, off, 64);
    q = __shfl(q, 0, 64);
    float inv = rsqrtf(q * (1.f / DM) + 1e-5f);
    int c = lane * 4;
    float4 o;
    o.x = d.x * inv * g[c + 0] + bb[c + 0];
    o.y = d.y * inv * g[c + 1] + bb[c + 1];
    o.z = d.z * inv * g[c + 2] + bb[c + 2];
    o.w = d.w * inv * g[c + 3] + bb[c + 3];
    ((float4*)(g_X + (size_t)wid * DM))[lane] = o;
    float ov[4] = {o.x, o.y, o.z, o.w};
    short hi[4], lo[4];
    #pragma unroll
    for (int t = 0; t < 4; t++) {
        bf16 hb = __float2bfloat16(ov[t]);
        hi[t] = *(short*)&hb;
        bf16 lb = __float2bfloat16(ov[t] - __bfloat162float(hb));
        lo[t] = *(short*)&lb;
    }
    *(short4*)((short*)g_Xhi + (size_t)wid * DM + c) = make_short4(hi[0], hi[1], hi[2], hi[3]);
    *(short4*)((short*)g_Xlo + (size_t)wid * DM + c) = make_short4(lo[0], lo[1], lo[2], lo[3]);
}

// ---------------------------------------------------------------------------
__global__ __launch_bounds__(256) void final_kernel(
    const float* __restrict__ g, const float* __restrict__ bb,
    const float* __restrict__ pw, const float* __restrict__ pb,
    float* __restrict__ out)
{
    __shared__ float red[256];
    int b = blockIdx.x, tid = threadIdx.x;
    const float* row = g_X + ((size_t)(b * Lseq + Lseq - 1)) * DM;
    float v = row[tid];
    red[tid] = v; __syncthreads();
    for (int s = 128; s > 0; s >>= 1) { if (tid < s) red[tid] += red[tid + s]; __syncthreads(); }
    float mean = red[0] * (1.f / DM); __syncthreads();
    float d = v - mean;
    red[tid] = d * d; __syncthreads();
    for (int s = 128; s > 0; s >>= 1) { if (tid < s) red[tid] += red[tid + s]; __syncthreads(); }
    float var = red[0] * (1.f / DM); __syncthreads();
    float xn = d * rsqrtf(var + 1e-5f) * g[tid] + bb[tid];
    red[tid] = xn * pw[tid]; __syncthreads();
    for (int s = 128; s > 0; s >>= 1) { if (tid < s) red[tid] += red[tid + s]; __syncthreads(); }
    if (tid == 0) out[b] = red[0] + pb[0];
}

// ---------------------------------------------------------------------------
extern "C" void kernel_launch(void* const* d_in, const int* in_sizes, int n_in,
                              void* d_out, int out_size, void* d_ws, size_t ws_size,
                              hipStream_t stream)
{
    const float* x_enc = (const float*)d_in[0];
    const int*   isamp = (const int*)d_in[1];
    const float* emb_W = (const float*)d_in[2];
    const float* emb_b = (const float*)d_in[3];
    const float* Wq = (const float*)d_in[4];
    const float* bq = (const float*)d_in[5];
    const float* Wk = (const float*)d_in[6];
    const float* bk = (const float*)d_in[7];
    const float* Wv = (const float*)d_in[8];
    const float* bv = (const float*)d_in[9];
    const float* Wo = (const float*)d_in[10];
    const float* bo = (const float*)d_in[11];
    const float* c1W = (const float*)d_in[12];
    const float* c1b = (const float*)d_in[13];
    const float* c2W = (const float*)d_in[14];
    const float* c2b = (const float*)d_in[15];
    const float* ln1g = (const float*)d_in[16];
    const float* ln1b = (const float*)d_in[17];
    const float* ln2g = (const float*)d_in[18];
    const float* ln2b = (const float*)d_in[19];
    const float* nfg  = (const float*)d_in[20];
    const float* nfb  = (const float*)d_in[21];
    const float* projW = (const float*)d_in[22];
    const float* projb = (const float*)d_in[23];
    (void)d_ws; (void)ws_size; (void)in_sizes; (void)n_in; (void)out_size;

    dim3 blk(256);
    emb_gemm<<<dim3(DM / 128, MROWS / 128), blk, 0, stream>>>(x_enc, emb_W, emb_b);

    for (int l = 0; l < 2; l++) {
        const float* Wq_l = Wq + (size_t)l * DM * HD;
        const float* Wk_l = Wk + (size_t)l * DM * HD;
        const float* Wv_l = Wv + (size_t)l * DM * HD;
        const float* Wo_l = Wo + (size_t)l * HD * DM;

        gt_gemm<<<dim3(4, 4, 8), blk, 0, stream>>>(Wq_l, Wk_l);
        wc_kernel<<<dim3(HH), blk, 0, stream>>>(Wq_l, Wk_l, bq + l * HD, bk + l * HD);
        y_mf<<<dim3(HD / 128, MROWS / 128), blk, 0, stream>>>(0);
        uv_kernel<<<dim3(MROWS / 4), blk, 0, stream>>>(0);

        sampm_kernel<<<dim3(MROWS / 4), blk, 0, stream>>>(isamp);
        topk_kernel<<<dim3(Bsz * HH), blk, 0, stream>>>(0);

        attn_scores<<<dim3(NBT, NCHUNK), blk, 0, stream>>>(0);
        attn_softmax<<<dim3(NBT), blk, 0, stream>>>(0);
        attn_ctx<<<dim3(NBT, NCHUNK), blk, 0, stream>>>(0);

        add_bias_kernel<<<dim3(MROWS), blk, 0, stream>>>(bo + l * DM);
        scatter_kernel<<<dim3(NBT), blk, 0, stream>>>(Wv_l, bv + l * HD, Wo_l);
        ln_kernel<<<dim3(MROWS / 4), blk, 0, stream>>>(ln1g + l * DM, ln1b + l * DM);

        ffn1_mf<<<dim3(DFF / 128, MROWS / 128), blk, 0, stream>>>(
            c1W + (size_t)l * DM * DFF, c1b + l * DFF);
        ffn2_mf<<<dim3(DM / 128, MROWS / 128), blk, 0, stream>>>(
            c2W + (size_t)l * DFF * DM, c2b + l * DM);
        ln_kernel<<<dim3(MROWS / 4), blk, 0, stream>>>(ln2g + l * DM, ln2b + l * DM);
    }

    final_kernel<<<dim3(Bsz), blk, 0, stream>>>(nfg, nfb, projW, projb, (float*)d_out);
}

// Round 15
// 821.613 us; speedup vs baseline: 2.1529x; 1.0335x over previous
//
#include <hip/hip_runtime.h>
#include <hip/hip_bf16.h>
#include <math.h>

typedef __hip_bfloat16 bf16;
typedef __attribute__((ext_vector_type(8))) short bf16x8;   // MFMA A/B frag
typedef __attribute__((ext_vector_type(8))) short short8v;  // 16B bf16 vector
typedef __attribute__((ext_vector_type(4))) float f32x4;    // MFMA C/D frag

// Problem constants
#define Bsz 4
#define Lseq 2048
#define DM 256       // d_model == per-head D
#define HH 8
#define HD 2048      // H * DM
#define DFF 1024
#define SK 40
#define NTOP 5
#define MROWS 8192   // B * L
#define NBT (Bsz * HH * NTOP)   // 160
#define NCHUNK 8

// ---------------------------------------------------------------------------
// Static device scratch. __align__(256) REQUIRED (float4 casts).
// score = y·x + u + v + c (G=Wq Wk^T factoring; Q/K never materialized).
// V never materialized either: ctx = (P@X)·Wv + bv  (ΣP=1).
__device__ __align__(256) float g_X  [MROWS * DM];    //   8 MB activations (fp32)
__device__ __align__(256) bf16  g_Xhi[MROWS * DM];    //   4 MB bf16(X)
__device__ __align__(256) bf16  g_Xlo[MROWS * DM];    //   4 MB bf16(X - hi)
__device__ __align__(256) float g_TMP[MROWS * DM];    //   8 MB residual accum
__device__ __align__(256) bf16  g_Yhi[MROWS * HD];    //  32 MB bf16(y)
__device__ __align__(256) bf16  g_Ylo[MROWS * HD];    //  32 MB bf16(y - hi)
__device__ __align__(256) bf16  g_HFb[MROWS * DFF];   //  16 MB FFN hidden (bf16)
__device__ __align__(256) bf16  g_GhiT[HD * DM];      //   1 MB G^T hi (n-major)
__device__ __align__(256) bf16  g_GloT[HD * DM];      //   1 MB G^T lo
__device__ __align__(256) float g_UV [MROWS * 16];    // [l][0..7]=u_h, [8..15]=v_h
__device__ __align__(256) float g_W12[DM * 16];
__device__ __align__(256) float g_C  [HH];
__device__ __align__(256) float g_MB [Bsz * HH * Lseq];
__device__ __align__(256) float g_SC [NBT * Lseq];
__device__ __align__(256) float g_CTXP[NBT * NCHUNK * DM];  // partial P@X
__device__ __align__(256) int   g_MTOP[NBT];

__device__ __forceinline__ float ld(const float* p, size_t i) { return p[i]; }
__device__ __forceinline__ float ld(const bf16* p, size_t i) { return __bfloat162float(p[i]); }
__device__ __forceinline__ float b2f(bf16 x) { return __bfloat162float(x); }
__device__ __forceinline__ void st(float* p, size_t i, float v) { p[i] = v; }
__device__ __forceinline__ void st(bf16* p, size_t i, float v) { p[i] = __float2bfloat16(v); }
__device__ __forceinline__ short f2bf(float v) {
    union { bf16 h; short s; } u; u.h = __float2bfloat16(v); return u.s;
}

// ---------------------------------------------------------------------------
// fp32 tiled GEMM, 128x128 tile, BK=16, 8x8 per thread (embedding only).
template<typename TA, typename TC, bool GELU, bool RES>
__device__ __forceinline__ void gemm_body(
    const TA* __restrict__ A, const float* __restrict__ W,
    const float* __restrict__ bias, const float* __restrict__ res,
    TC* __restrict__ C, int K, int ldw, int ldc, int bx, int by)
{
    const int BM = 128, BN = 128, BK = 16;
    __shared__ __align__(16) float As[BK][BM + 4];
    __shared__ __align__(16) float Bs[BK][BN];
    int tid = threadIdx.x;
    int tx = tid & 15, ty = tid >> 4;
    int row0 = by * BM, col0 = bx * BN;
    float acc[8][8] = {};
    for (int k0 = 0; k0 < K; k0 += BK) {
        #pragma unroll
        for (int i = 0; i < 8; i++) {
            int idx = tid + i * 256;
            int r = idx >> 4, c = idx & 15;
            As[c][r] = ld(A, (size_t)(row0 + r) * K + k0 + c);
        }
        #pragma unroll
        for (int i = 0; i < 8; i++) {
            int idx = tid + i * 256;
            int r = idx >> 7, c = idx & 127;
            Bs[r][c] = W[(size_t)(k0 + r) * ldw + col0 + c];
        }
        __syncthreads();
        #pragma unroll
        for (int kk = 0; kk < BK; kk++) {
            float4 a0 = *(const float4*)&As[kk][ty * 8];
            float4 a1 = *(const float4*)&As[kk][ty * 8 + 4];
            float4 b0 = *(const float4*)&Bs[kk][tx * 8];
            float4 b1 = *(const float4*)&Bs[kk][tx * 8 + 4];
            float av[8] = {a0.x, a0.y, a0.z, a0.w, a1.x, a1.y, a1.z, a1.w};
            float bv[8] = {b0.x, b0.y, b0.z, b0.w, b1.x, b1.y, b1.z, b1.w};
            #pragma unroll
            for (int i = 0; i < 8; i++)
                #pragma unroll
                for (int j = 0; j < 8; j++) acc[i][j] += av[i] * bv[j];
        }
        __syncthreads();
    }
    #pragma unroll
    for (int i = 0; i < 8; i++) {
        int r = row0 + ty * 8 + i;
        #pragma unroll
        for (int j = 0; j < 8; j++) {
            int c = col0 + tx * 8 + j;
            float v = acc[i][j] + bias[c];
            if (RES) v += res[(size_t)r * ldc + c];
            if (GELU) v = 0.5f * v * (1.0f + erff(v * 0.70710678118654752440f));
            st(C, (size_t)r * ldc + c, v);
        }
    }
}

// embedding: also emits Xhi/Xlo bf16 splits for the MFMA consumers.
__global__ __launch_bounds__(256) void emb_gemm(const float* __restrict__ A,
                                                const float* __restrict__ W,
                                                const float* __restrict__ bias)
{
    const int BM = 128;
    int tid = threadIdx.x;
    gemm_body<float, float, false, false>(A, W, bias, nullptr, g_X, 32, DM, DM,
                                          blockIdx.x, blockIdx.y);
    int row0 = blockIdx.y * BM, col0 = blockIdx.x * 128;
    for (int i = 0; i < 8; i++) {
        int idx = tid + i * 256;
        int r = row0 + (idx >> 7), c = col0 + (idx & 127);
        float v = g_X[(size_t)r * DM + c];
        bf16 hi = __float2bfloat16(v);
        g_Xhi[(size_t)r * DM + c] = hi;
        g_Xlo[(size_t)r * DM + c] = __float2bfloat16(v - __bfloat162float(hi));
    }
}

// ---------------------------------------------------------------------------
// G^T_h = (Wq_h @ Wk_h^T)^T, written pre-split bf16 (hi/lo), n-major [HD][DM].
__global__ __launch_bounds__(256) void gt_gemm(const float* __restrict__ Wq,
                                               const float* __restrict__ Wk)
{
    __shared__ float Aq[16][68];
    __shared__ float Ak[16][68];
    int h = blockIdx.z;
    int jt = blockIdx.x * 64, it = blockIdx.y * 64;
    int tid = threadIdx.x, tx = tid & 15, ty = tid >> 4;
    float acc[4][4] = {};
    for (int d0 = 0; d0 < DM; d0 += 16) {
        #pragma unroll
        for (int p = 0; p < 4; p++) {
            int idx = tid + p * 256;
            int i = idx >> 4, d = idx & 15;
            Aq[d][i] = Wq[(size_t)(it + i) * HD + h * DM + d0 + d];
            Ak[d][i] = Wk[(size_t)(jt + i) * HD + h * DM + d0 + d];
        }
        __syncthreads();
        #pragma unroll
        for (int d = 0; d < 16; d++) {
            float a[4], b[4];
            #pragma unroll
            for (int p = 0; p < 4; p++) { a[p] = Aq[d][ty * 4 + p]; b[p] = Ak[d][tx * 4 + p]; }
            #pragma unroll
            for (int i2 = 0; i2 < 4; i2++)
                #pragma unroll
                for (int j2 = 0; j2 < 4; j2++) acc[i2][j2] += a[i2] * b[j2];
        }
        __syncthreads();
    }
    #pragma unroll
    for (int i2 = 0; i2 < 4; i2++)
        #pragma unroll
        for (int j2 = 0; j2 < 4; j2++) {
            float v = acc[i2][j2];
            bf16 hi = __float2bfloat16(v);
            size_t gi = (size_t)(h * DM + jt + tx * 4 + j2) * DM + (it + ty * 4 + i2);
            g_GhiT[gi] = hi;
            g_GloT[gi] = __float2bfloat16(v - __bfloat162float(hi));
        }
}

// w1[i,h]=Wq_h[i,:]·bk_h, w2[i,h]=Wk_h[i,:]·bq_h, c[h]=bq_h·bk_h. grid 8.
__global__ __launch_bounds__(256) void wc_kernel(const float* __restrict__ Wq,
                                                 const float* __restrict__ Wk,
                                                 const float* __restrict__ bq,
                                                 const float* __restrict__ bk)
{
    __shared__ float red[256];
    int h = blockIdx.x, i = threadIdx.x;
    const float4* qr  = (const float4*)(Wq + (size_t)i * HD + h * DM);
    const float4* kr  = (const float4*)(Wk + (size_t)i * HD + h * DM);
    const float4* bkr = (const float4*)(bk + h * DM);
    const float4* bqr = (const float4*)(bq + h * DM);
    float s1 = 0.f, s2 = 0.f;
    for (int j = 0; j < DM / 4; j++) {
        float4 q4 = qr[j], k4 = kr[j], b1 = bkr[j], b2 = bqr[j];
        s1 += q4.x * b1.x + q4.y * b1.y + q4.z * b1.z + q4.w * b1.w;
        s2 += k4.x * b2.x + k4.y * b2.y + k4.z * b2.z + k4.w * b2.w;
    }
    g_W12[i * 16 + h] = s1;
    g_W12[i * 16 + 8 + h] = s2;
    red[i] = bq[h * DM + i] * bk[h * DM + i];
    __syncthreads();
    for (int s = 128; s > 0; s >>= 1) { if (i < s) red[i] += red[i + s]; __syncthreads(); }
    if (i == 0) g_C[h] = red[0];
}

// u[l,h]=x_l·w1[:,h], v[l,h]=x_l·w2[:,h]. One wave per row; grid MROWS/4.
__global__ __launch_bounds__(256) void uv_kernel(int dummy)
{
    (void)dummy;
    int w = threadIdx.x >> 6, lane = threadIdx.x & 63;
    int l = blockIdx.x * 4 + w;
    float wrf[4][16];
    #pragma unroll
    for (int r = 0; r < 4; r++) {
        const float4* wp = (const float4*)(g_W12 + (size_t)(lane * 4 + r) * 16);
        float4 a = wp[0], b = wp[1], c = wp[2], d = wp[3];
        wrf[r][0]=a.x; wrf[r][1]=a.y; wrf[r][2]=a.z; wrf[r][3]=a.w;
        wrf[r][4]=b.x; wrf[r][5]=b.y; wrf[r][6]=b.z; wrf[r][7]=b.w;
        wrf[r][8]=c.x; wrf[r][9]=c.y; wrf[r][10]=c.z; wrf[r][11]=c.w;
        wrf[r][12]=d.x; wrf[r][13]=d.y; wrf[r][14]=d.z; wrf[r][15]=d.w;
    }
    float4 x4 = ((const float4*)(g_X + (size_t)l * DM))[lane];
    float xv[4] = {x4.x, x4.y, x4.z, x4.w};
    float uv[16];
    #pragma unroll
    for (int k = 0; k < 16; k++) {
        float acc = xv[0] * wrf[0][k] + xv[1] * wrf[1][k]
                  + xv[2] * wrf[2][k] + xv[3] * wrf[3][k];
        #pragma unroll
        for (int off = 32; off > 0; off >>= 1) acc += __shfl_xor(acc, off, 64);
        uv[k] = acc;
    }
    if (lane == 0) {
        float* o = g_UV + (size_t)l * 16;
        *(float4*)(o + 0)  = make_float4(uv[0], uv[1], uv[2], uv[3]);
        *(float4*)(o + 4)  = make_float4(uv[4], uv[5], uv[6], uv[7]);
        *(float4*)(o + 8)  = make_float4(uv[8], uv[9], uv[10], uv[11]);
        *(float4*)(o + 12) = make_float4(uv[12], uv[13], uv[14], uv[15]);
    }
}

// ---------------------------------------------------------------------------
// y = X @ G via bf16x3 split MFMA; OUTPUT pre-split hi/lo bf16. 128x128, BK=32.
// (r13-proven 3-pass structure — kept verbatim.)
__global__ __launch_bounds__(256) void y_mf(int dummy)
{
    (void)dummy;
    __shared__ __align__(16) short As[128][40];
    __shared__ __align__(16) short Bs[128][40];
    int tid = threadIdx.x;
    int wid = tid >> 6, lane = tid & 63;
    int wm = wid >> 1, wn = wid & 1;
    int quad = lane >> 4, l16 = lane & 15;
    int row0 = blockIdx.y * 128, col0 = blockIdx.x * 128;
    f32x4 acc[4][4] = {};
    const short* Alist[3] = {(const short*)g_Xhi, (const short*)g_Xhi, (const short*)g_Xlo};
    const short* Blist[3] = {(const short*)g_GhiT, (const short*)g_GloT, (const short*)g_GhiT};
    #pragma unroll 1
    for (int pass = 0; pass < 3; pass++) {
        const short* A = Alist[pass];
        const short* B = Blist[pass];
        for (int k0 = 0; k0 < DM; k0 += 32) {
            __syncthreads();
            int r = tid >> 2, c = (tid & 3) * 8;
            #pragma unroll
            for (int p = 0; p < 2; p++) {
                *(short8v*)&As[r + p * 64][c] =
                    *(const short8v*)&A[(size_t)(row0 + r + p * 64) * DM + k0 + c];
                *(short8v*)&Bs[r + p * 64][c] =
                    *(const short8v*)&B[(size_t)(col0 + r + p * 64) * DM + k0 + c];
            }
            __syncthreads();
            bf16x8 af[4], bf_[4];
            #pragma unroll
            for (int mt = 0; mt < 4; mt++)
                af[mt] = *(const bf16x8*)&As[wm * 64 + mt * 16 + l16][quad * 8];
            #pragma unroll
            for (int nt = 0; nt < 4; nt++)
                bf_[nt] = *(const bf16x8*)&Bs[wn * 64 + nt * 16 + l16][quad * 8];
            #pragma unroll
            for (int mt = 0; mt < 4; mt++)
                #pragma unroll
                for (int nt = 0; nt < 4; nt++)
                    acc[mt][nt] = __builtin_amdgcn_mfma_f32_16x16x32_bf16(
                        af[mt], bf_[nt], acc[mt][nt], 0, 0, 0);
        }
    }
    #pragma unroll
    for (int mt = 0; mt < 4; mt++)
        #pragma unroll
        for (int nt = 0; nt < 4; nt++) {
            int col = col0 + wn * 64 + nt * 16 + l16;
            #pragma unroll
            for (int r = 0; r < 4; r++) {
                int row = row0 + wm * 64 + mt * 16 + quad * 4 + r;
                float v = acc[mt][nt][r];
                bf16 hi = __float2bfloat16(v);
                g_Yhi[(size_t)row * HD + col] = hi;
                g_Ylo[(size_t)row * HD + col] = __float2bfloat16(v - __bfloat162float(hi));
            }
        }
}

// ---------------------------------------------------------------------------
// bf16 MFMA GEMM with RAW bf16 A (no cvt) + fp32 W cvt-staging. 128x128, BK=32.
// r13-proven template, extended minimally: [kbeg,kend) K-range + ATOMIC epilogue
// (for ffn2 split-K; bias/res pre-applied into C via add_bias_kernel).
template<typename TC, bool GELU, bool RES, bool ATOMIC>
__device__ __forceinline__ void mf_gemm_bfA(
    const bf16* __restrict__ A, const float* __restrict__ W,
    const float* __restrict__ bias, const float* __restrict__ res,
    TC* __restrict__ C, int K, int kbeg, int kend, int ldw, int ldc,
    int bx, int by)
{
    __shared__ __align__(16) short As[128][40];
    __shared__ __align__(16) short Bs[128][40];
    int tid = threadIdx.x;
    int wid = tid >> 6, lane = tid & 63;
    int wm = wid >> 1, wn = wid & 1;
    int quad = lane >> 4, l16 = lane & 15;
    int row0 = by * 128, col0 = bx * 128;
    f32x4 acc[4][4] = {};
    for (int k0 = kbeg; k0 < kend; k0 += 32) {
        // A raw bf16: 128 rows x 32 k; thread -> row tid&127, chunks of 8
        int r = tid & 127, cb = (tid >> 7) * 8;
        #pragma unroll
        for (int i = 0; i < 2; i++) {
            int c = cb + i * 16;
            *(short8v*)&As[r][c] =
                *(const short8v*)&((const short*)A)[(size_t)(row0 + r) * K + k0 + c];
        }
        int bk = tid >> 5, bn = (tid & 31) * 4;
        #pragma unroll
        for (int i = 0; i < 4; i++) {
            int kk = bk + i * 8;
            float4 v = *(const float4*)&W[(size_t)(k0 + kk) * ldw + col0 + bn];
            Bs[bn + 0][kk] = f2bf(v.x);
            Bs[bn + 1][kk] = f2bf(v.y);
            Bs[bn + 2][kk] = f2bf(v.z);
            Bs[bn + 3][kk] = f2bf(v.w);
        }
        __syncthreads();
        bf16x8 af[4], bf_[4];
        #pragma unroll
        for (int mt = 0; mt < 4; mt++)
            af[mt] = *(const bf16x8*)&As[wm * 64 + mt * 16 + l16][quad * 8];
        #pragma unroll
        for (int nt = 0; nt < 4; nt++)
            bf_[nt] = *(const bf16x8*)&Bs[wn * 64 + nt * 16 + l16][quad * 8];
        #pragma unroll
        for (int mt = 0; mt < 4; mt++)
            #pragma unroll
            for (int nt = 0; nt < 4; nt++)
                acc[mt][nt] = __builtin_amdgcn_mfma_f32_16x16x32_bf16(
                    af[mt], bf_[nt], acc[mt][nt], 0, 0, 0);
        __syncthreads();
    }
    #pragma unroll
    for (int mt = 0; mt < 4; mt++) {
        #pragma unroll
        for (int nt = 0; nt < 4; nt++) {
            int col = col0 + wn * 64 + nt * 16 + l16;
            float bv = ATOMIC ? 0.f : bias[col];
            #pragma unroll
            for (int r = 0; r < 4; r++) {
                int row = row0 + wm * 64 + mt * 16 + quad * 4 + r;
                float v = acc[mt][nt][r] + bv;
                if (RES) v += res[(size_t)row * ldc + col];
                if (GELU) v = 0.5f * v * (1.0f + erff(v * 0.70710678118654752440f));
                if (ATOMIC) atomicAdd((float*)&C[(size_t)row * ldc + col], v);
                else st(C, (size_t)row * ldc + col, v);
            }
        }
    }
}

// FFN1: g_HFb(bf16) = gelu(Xhi @ c1W + c1b)
__global__ __launch_bounds__(256) void ffn1_mf(const float* __restrict__ W,
                                               const float* __restrict__ bias) {
    mf_gemm_bfA<bf16, true, false, false>(g_Xhi, W, bias, nullptr, g_HFb,
                                          DM, 0, DM, DFF, DFF,
                                          blockIdx.x, blockIdx.y);
}
// FFN2 split-K x4: TMP += partial(HFb @ c2W) atomically. TMP pre-init = X + c2b.
// grid (DM/128, MROWS/128, 4); z = K-chunk of 256.
__global__ __launch_bounds__(256) void ffn2_mf(const float* __restrict__ W,
                                               const float* __restrict__ bias) {
    int kbeg = blockIdx.z * 256;
    mf_gemm_bfA<float, false, false, true>(g_HFb, W, bias, nullptr, g_TMP,
                                           DFF, kbeg, kbeg + 256, DM, DM,
                                           blockIdx.x, blockIdx.y);
}

// ---------------------------------------------------------------------------
// Sampled scores + sparsity M via MFMA. ONE WAVE per (b,l), kk-outer pipelined.
__global__ __launch_bounds__(256) void sampm_kernel(const int* __restrict__ idx)
{
    int wly = threadIdx.x >> 6, lane = threadIdx.x & 63;
    int bl = blockIdx.x * 4 + wly;        // b*Lseq + l
    int b = bl >> 11, l = bl & (Lseq - 1);
    int quad = lane >> 4, l16 = lane & 15;

    const short* yh = (const short*)g_Yhi + (size_t)bl * HD + (l16 & 7) * DM;
    const short* yl = (const short*)g_Ylo + (size_t)bl * HD + (l16 & 7) * DM;
    bf16x8 ah[8], al[8];
    #pragma unroll
    for (int kk = 0; kk < 8; kk++) {
        ah[kk] = *(const bf16x8*)&yh[kk * 32 + quad * 8];
        al[kk] = *(const bf16x8*)&yl[kk * 32 + quad * 8];
    }
    int myidx = idx[l * SK + (lane < SK ? lane : SK - 1)] & (Lseq - 1);

    const short* xh[3];
    const short* xl[3];
    float4 v4[3];
    #pragma unroll
    for (int t = 0; t < 3; t++) {
        int su = t * 16 + l16; if (su >= SK) su = SK - 1;
        int s = __shfl(myidx, su, 64);
        xh[t] = (const short*)g_Xhi + (size_t)(b * Lseq + s) * DM;
        xl[t] = (const short*)g_Xlo + (size_t)(b * Lseq + s) * DM;
        v4[t] = *(const float4*)(g_UV + (size_t)(b * Lseq + s) * 16 + 8 + (quad & 1) * 4);
    }
    f32x4 acc[3] = {};
    #pragma unroll
    for (int kk = 0; kk < 8; kk++) {
        #pragma unroll
        for (int t = 0; t < 3; t++) {
            bf16x8 bh  = *(const bf16x8*)&xh[t][kk * 32 + quad * 8];
            bf16x8 blo = *(const bf16x8*)&xl[t][kk * 32 + quad * 8];
            acc[t] = __builtin_amdgcn_mfma_f32_16x16x32_bf16(ah[kk], bh,  acc[t], 0, 0, 0);
            acc[t] = __builtin_amdgcn_mfma_f32_16x16x32_bf16(al[kk], bh,  acc[t], 0, 0, 0);
            acc[t] = __builtin_amdgcn_mfma_f32_16x16x32_bf16(ah[kk], blo, acc[t], 0, 0, 0);
        }
    }
    float mxs[4] = {-INFINITY, -INFINITY, -INFINITY, -INFINITY};
    float sms[4] = {0.f, 0.f, 0.f, 0.f};
    #pragma unroll
    for (int t = 0; t < 3; t++) {
        int u = t * 16 + l16;
        bool valid = u < SK;
        float vv[4] = {v4[t].x, v4[t].y, v4[t].z, v4[t].w};
        #pragma unroll
        for (int r = 0; r < 4; r++) {
            float sc = acc[t][r] + vv[r];
            if (valid) { mxs[r] = fmaxf(mxs[r], sc); sms[r] += sc; }
        }
    }
    #pragma unroll
    for (int off = 1; off <= 8; off <<= 1)
        #pragma unroll
        for (int r = 0; r < 4; r++) {
            mxs[r] = fmaxf(mxs[r], __shfl_xor(mxs[r], off, 64));
            sms[r] += __shfl_xor(sms[r], off, 64);
        }
    if (quad < 2 && l16 < 4) {
        int h = quad * 4 + l16;
        float mx = (l16 == 0) ? mxs[0] : (l16 == 1) ? mxs[1] : (l16 == 2) ? mxs[2] : mxs[3];
        float sm = (l16 == 0) ? sms[0] : (l16 == 1) ? sms[1] : (l16 == 2) ? sms[2] : sms[3];
        float uu = g_UV[(size_t)bl * 16 + h];
        float cc = g_C[h];
        g_MB[(size_t)(b * HH + h) * Lseq + l] =
            (mx + uu + cc) - (sm + (float)SK * (uu + cc)) * (1.0f / (float)Lseq);
    }
}

// ---------------------------------------------------------------------------
// Top-5 per (b,h): grid 32. 5 masked argmax passes (ties -> lower index).
__global__ __launch_bounds__(256) void topk_kernel(int dummy)
{
    (void)dummy;
    __shared__ float vals[Lseq];
    __shared__ float rv[256];
    __shared__ int ri[256];
    int bh = blockIdx.x, tid = threadIdx.x;
    for (int i = tid; i < Lseq; i += 256) vals[i] = g_MB[bh * Lseq + i];
    __syncthreads();
    for (int t = 0; t < NTOP; t++) {
        float bv = -INFINITY; int bi = Lseq - 1;
        for (int i = tid; i < Lseq; i += 256) {
            float v = vals[i];
            if (v > bv || (v == bv && i < bi)) { bv = v; bi = i; }
        }
        rv[tid] = bv; ri[tid] = bi;
        __syncthreads();
        for (int s = 128; s > 0; s >>= 1) {
            if (tid < s) {
                float ov = rv[tid + s]; int oi = ri[tid + s];
                if (ov > rv[tid] || (ov == rv[tid] && oi < ri[tid])) { rv[tid] = ov; ri[tid] = oi; }
            }
            __syncthreads();
        }
        if (tid == 0) { g_MTOP[bh * NTOP + t] = ri[0]; vals[ri[0] & (Lseq - 1)] = -INFINITY; }
        __syncthreads();
    }
}

// ---------------------------------------------------------------------------
// Scores for top queries via y·x + affine: grid (NBT, NCHUNK). Thread = key.
__global__ __launch_bounds__(256) void attn_scores(int dummy)
{
    (void)dummy;
    __shared__ __align__(16) float ys[DM];
    int bt = blockIdx.x, chunk = blockIdx.y, tid = threadIdx.x;
    int bh = bt / NTOP;
    int b = bh >> 3, h = bh & 7;
    int ltop = g_MTOP[bt] & (Lseq - 1);
    size_t yi = (size_t)(b * Lseq + ltop) * HD + h * DM + tid;
    ys[tid] = b2f(g_Yhi[yi]) + b2f(g_Ylo[yi]);
    __syncthreads();
    float uu = g_UV[(size_t)(b * Lseq + ltop) * 16 + h];
    float cc = g_C[h];
    int j = chunk * 256 + tid;
    const float4* xrow = (const float4*)(g_X + (size_t)(b * Lseq + j) * DM);
    float acc = 0.f;
    for (int d4 = 0; d4 < DM / 4; d4++) {
        float4 xf = xrow[d4];
        float4 yf = ((const float4*)ys)[d4];
        acc += yf.x * xf.x + yf.y * xf.y + yf.z * xf.z + yf.w * xf.w;
    }
    float vv = g_UV[(size_t)(b * Lseq + j) * 16 + 8 + h];
    g_SC[(size_t)bt * Lseq + j] = acc + uu + vv + cc;
}

// Softmax in place over g_SC row: grid NBT.
__global__ __launch_bounds__(256) void attn_softmax(int dummy)
{
    (void)dummy;
    __shared__ float sc[Lseq];
    __shared__ float red[256];
    int bt = blockIdx.x, tid = threadIdx.x;
    for (int i = tid; i < Lseq; i += 256) sc[i] = g_SC[(size_t)bt * Lseq + i];
    __syncthreads();
    float m = -INFINITY;
    for (int i = tid; i < Lseq; i += 256) m = fmaxf(m, sc[i]);
    red[tid] = m; __syncthreads();
    for (int s = 128; s > 0; s >>= 1) { if (tid < s) red[tid] = fmaxf(red[tid], red[tid + s]); __syncthreads(); }
    m = red[0]; __syncthreads();
    float sum = 0.f;
    for (int i = tid; i < Lseq; i += 256) { float e = expf(sc[i] - m); sc[i] = e; sum += e; }
    red[tid] = sum; __syncthreads();
    for (int s = 128; s > 0; s >>= 1) { if (tid < s) red[tid] += red[tid + s]; __syncthreads(); }
    float inv = 1.0f / red[0]; __syncthreads();
    for (int i = tid; i < Lseq; i += 256) g_SC[(size_t)bt * Lseq + i] = sc[i] * inv;
}

// Partial P@X over one key chunk: grid (NBT, NCHUNK). Thread = dim.
__global__ __launch_bounds__(256) void attn_ctx(int dummy)
{
    (void)dummy;
    __shared__ float ps[256];
    int bt = blockIdx.x, chunk = blockIdx.y, tid = threadIdx.x;
    int bh = bt / NTOP;
    int b = bh >> 3;
    int j0 = chunk * 256;
    ps[tid] = g_SC[(size_t)bt * Lseq + j0 + tid];
    __syncthreads();
    float accv = 0.f;
    const float* xbase = g_X + ((size_t)(b * Lseq + j0)) * DM + tid;
    for (int j = 0; j < 256; j++) accv += ps[j] * xbase[(size_t)j * DM];
    g_CTXP[((size_t)bt * NCHUNK + chunk) * DM + tid] = accv;
}

// ---------------------------------------------------------------------------
// g_TMP = g_X + broadcast(bias[DM]) — attention bo AND ffn2's c2b pre-init.
__global__ __launch_bounds__(256) void add_bias_kernel(const float* __restrict__ bo)
{
    int i = blockIdx.x * 256 + threadIdx.x;
    g_TMP[i] = g_X[i] + bo[i & (DM - 1)];
}

// Reduce PX partials; ctx = PX@Wv_h + bv_h; out = ctx@Wo_h; scatter-add.
__global__ __launch_bounds__(256) void scatter_kernel(const float* __restrict__ Wv_l,
                                                      const float* __restrict__ bv_l,
                                                      const float* __restrict__ Wo_l)
{
    __shared__ float px[DM];
    __shared__ float cs[DM];
    int bt = blockIdx.x, tid = threadIdx.x;
    int bh = bt / NTOP;
    int b = bh >> 3, h = bh & 7;
    float s = 0.f;
    #pragma unroll
    for (int c = 0; c < NCHUNK; c++) s += g_CTXP[((size_t)bt * NCHUNK + c) * DM + tid];
    px[tid] = s;
    __syncthreads();
    float acc = 0.f;
    const float* wv = Wv_l + h * DM + tid;
    for (int d = 0; d < DM; d++) acc += px[d] * wv[(size_t)d * HD];
    cs[tid] = acc + bv_l[h * DM + tid];
    __syncthreads();
    float acc2 = 0.f;
    const float* wo = Wo_l + (size_t)(h * DM) * DM + tid;
    for (int e = 0; e < DM; e++) acc2 += cs[e] * wo[(size_t)e * DM];
    int row = g_MTOP[bt] & (Lseq - 1);
    atomicAdd(&g_TMP[((size_t)(b * Lseq) + row) * DM + tid], acc2);
}

// ---------------------------------------------------------------------------
// LayerNorm g_TMP -> g_X (+ Xhi/Xlo bf16 splits), one wave per row of 256.
__global__ __launch_bounds__(256) void ln_kernel(const float* __restrict__ g,
                                                 const float* __restrict__ bb)
{
    int wid = blockIdx.x * 4 + (threadIdx.x >> 6);
    if (wid >= MROWS) return;
    int lane = threadIdx.x & 63;
    const float4* row = (const float4*)(g_TMP + (size_t)wid * DM);
    float4 v = row[lane];
    float s = v.x + v.y + v.z + v.w;
    #pragma unroll
    for (int off = 32; off > 0; off >>= 1) s += __shfl_down(s, off, 64);
    s = __shfl(s, 0, 64);
    float mean = s * (1.f / DM);
    float4 d = {v.x - mean, v.y - mean, v.z - mean, v.w - mean};
    float q = d.x * d.x + d.y * d.y + d.z * d.z + d.w * d.w;
    #pragma unroll
    for (int off = 32; off > 0; off >>= 1) q += __shfl_down(q, off, 64);
    q = __shfl(q, 0, 64);
    float inv = rsqrtf(q * (1.f / DM) + 1e-5f);
    int c = lane * 4;
    float4 o;
    o.x = d.x * inv * g[c + 0] + bb[c + 0];
    o.y = d.y * inv * g[c + 1] + bb[c + 1];
    o.z = d.z * inv * g[c + 2] + bb[c + 2];
    o.w = d.w * inv * g[c + 3] + bb[c + 3];
    ((float4*)(g_X + (size_t)wid * DM))[lane] = o;
    float ov[4] = {o.x, o.y, o.z, o.w};
    short hi[4], lo[4];
    #pragma unroll
    for (int t = 0; t < 4; t++) {
        bf16 hb = __float2bfloat16(ov[t]);
        hi[t] = *(short*)&hb;
        bf16 lb = __float2bfloat16(ov[t] - __bfloat162float(hb));
        lo[t] = *(short*)&lb;
    }
    *(short4*)((short*)g_Xhi + (size_t)wid * DM + c) = make_short4(hi[0], hi[1], hi[2], hi[3]);
    *(short4*)((short*)g_Xlo + (size_t)wid * DM + c) = make_short4(lo[0], lo[1], lo[2], lo[3]);
}

// ---------------------------------------------------------------------------
__global__ __launch_bounds__(256) void final_kernel(
    const float* __restrict__ g, const float* __restrict__ bb,
    const float* __restrict__ pw, const float* __restrict__ pb,
    float* __restrict__ out)
{
    __shared__ float red[256];
    int b = blockIdx.x, tid = threadIdx.x;
    const float* row = g_X + ((size_t)(b * Lseq + Lseq - 1)) * DM;
    float v = row[tid];
    red[tid] = v; __syncthreads();
    for (int s = 128; s > 0; s >>= 1) { if (tid < s) red[tid] += red[tid + s]; __syncthreads(); }
    float mean = red[0] * (1.f / DM); __syncthreads();
    float d = v - mean;
    red[tid] = d * d; __syncthreads();
    for (int s = 128; s > 0; s >>= 1) { if (tid < s) red[tid] += red[tid + s]; __syncthreads(); }
    float var = red[0] * (1.f / DM); __syncthreads();
    float xn = d * rsqrtf(var + 1e-5f) * g[tid] + bb[tid];
    red[tid] = xn * pw[tid]; __syncthreads();
    for (int s = 128; s > 0; s >>= 1) { if (tid < s) red[tid] += red[tid + s]; __syncthreads(); }
    if (tid == 0) out[b] = red[0] + pb[0];
}

// ---------------------------------------------------------------------------
extern "C" void kernel_launch(void* const* d_in, const int* in_sizes, int n_in,
                              void* d_out, int out_size, void* d_ws, size_t ws_size,
                              hipStream_t stream)
{
    const float* x_enc = (const float*)d_in[0];
    const int*   isamp = (const int*)d_in[1];
    const float* emb_W = (const float*)d_in[2];
    const float* emb_b = (const float*)d_in[3];
    const float* Wq = (const float*)d_in[4];
    const float* bq = (const float*)d_in[5];
    const float* Wk = (const float*)d_in[6];
    const float* bk = (const float*)d_in[7];
    const float* Wv = (const float*)d_in[8];
    const float* bv = (const float*)d_in[9];
    const float* Wo = (const float*)d_in[10];
    const float* bo = (const float*)d_in[11];
    const float* c1W = (const float*)d_in[12];
    const float* c1b = (const float*)d_in[13];
    const float* c2W = (const float*)d_in[14];
    const float* c2b = (const float*)d_in[15];
    const float* ln1g = (const float*)d_in[16];
    const float* ln1b = (const float*)d_in[17];
    const float* ln2g = (const float*)d_in[18];
    const float* ln2b = (const float*)d_in[19];
    const float* nfg  = (const float*)d_in[20];
    const float* nfb  = (const float*)d_in[21];
    const float* projW = (const float*)d_in[22];
    const float* projb = (const float*)d_in[23];
    (void)d_ws; (void)ws_size; (void)in_sizes; (void)n_in; (void)out_size;

    dim3 blk(256);
    emb_gemm<<<dim3(DM / 128, MROWS / 128), blk, 0, stream>>>(x_enc, emb_W, emb_b);

    for (int l = 0; l < 2; l++) {
        const float* Wq_l = Wq + (size_t)l * DM * HD;
        const float* Wk_l = Wk + (size_t)l * DM * HD;
        const float* Wv_l = Wv + (size_t)l * DM * HD;
        const float* Wo_l = Wo + (size_t)l * HD * DM;

        gt_gemm<<<dim3(4, 4, 8), blk, 0, stream>>>(Wq_l, Wk_l);
        wc_kernel<<<dim3(HH), blk, 0, stream>>>(Wq_l, Wk_l, bq + l * HD, bk + l * HD);
        y_mf<<<dim3(HD / 128, MROWS / 128), blk, 0, stream>>>(0);
        uv_kernel<<<dim3(MROWS / 4), blk, 0, stream>>>(0);

        sampm_kernel<<<dim3(MROWS / 4), blk, 0, stream>>>(isamp);
        topk_kernel<<<dim3(Bsz * HH), blk, 0, stream>>>(0);

        attn_scores<<<dim3(NBT, NCHUNK), blk, 0, stream>>>(0);
        attn_softmax<<<dim3(NBT), blk, 0, stream>>>(0);
        attn_ctx<<<dim3(NBT, NCHUNK), blk, 0, stream>>>(0);

        add_bias_kernel<<<dim3(MROWS), blk, 0, stream>>>(bo + l * DM);
        scatter_kernel<<<dim3(NBT), blk, 0, stream>>>(Wv_l, bv + l * HD, Wo_l);
        ln_kernel<<<dim3(MROWS / 4), blk, 0, stream>>>(ln1g + l * DM, ln1b + l * DM);

        ffn1_mf<<<dim3(DFF / 128, MROWS / 128), blk, 0, stream>>>(
            c1W + (size_t)l * DM * DFF, c1b + l * DFF);
        add_bias_kernel<<<dim3(MROWS), blk, 0, stream>>>(c2b + l * DM);  // TMP = X + c2b
        ffn2_mf<<<dim3(DM / 128, MROWS / 128, 4), blk, 0, stream>>>(
            c2W + (size_t)l * DFF * DM, c2b + l * DM);
        ln_kernel<<<dim3(MROWS / 4), blk, 0, stream>>>(ln2g + l * DM, ln2b + l * DM);
    }

    final_kernel<<<dim3(Bsz), blk, 0, stream>>>(nfg, nfb, projW, projb, (float*)d_out);
}

// Round 16
// 798.129 us; speedup vs baseline: 2.2163x; 1.0294x over previous
//
#include <hip/hip_runtime.h>
#include <hip/hip_bf16.h>
#include <math.h>

typedef __hip_bfloat16 bf16;
typedef __attribute__((ext_vector_type(8))) short bf16x8;   // MFMA A/B frag
typedef __attribute__((ext_vector_type(8))) short short8v;  // 16B bf16 vector
typedef __attribute__((ext_vector_type(4))) float f32x4;    // MFMA C/D frag

// Problem constants
#define Bsz 4
#define Lseq 2048
#define DM 256       // d_model == per-head D
#define HH 8
#define HD 2048      // H * DM
#define DFF 1024
#define SK 40
#define NTOP 5
#define MROWS 8192   // B * L
#define NBT (Bsz * HH * NTOP)   // 160
#define NCHUNK 8

// ---------------------------------------------------------------------------
// Static device scratch. __align__(256) REQUIRED (float4 casts).
// score = y·x + u + v + c (G=Wq Wk^T factoring; Q/K never materialized).
// V never materialized either: ctx = (P@X)·Wv + bv  (ΣP=1).
__device__ __align__(256) float g_X  [MROWS * DM];    //   8 MB activations (fp32)
__device__ __align__(256) bf16  g_Xhi[MROWS * DM];    //   4 MB bf16(X)
__device__ __align__(256) bf16  g_Xlo[MROWS * DM];    //   4 MB bf16(X - hi)
__device__ __align__(256) float g_TMP[MROWS * DM];    //   8 MB residual accum
__device__ __align__(256) bf16  g_Yhi[MROWS * HD];    //  32 MB bf16(y)
__device__ __align__(256) bf16  g_Ylo[MROWS * HD];    //  32 MB bf16(y - hi)
__device__ __align__(256) bf16  g_HFb[MROWS * DFF];   //  16 MB FFN hidden (bf16)
__device__ __align__(256) bf16  g_GhiT[HD * DM];      //   1 MB G^T hi (n-major)
__device__ __align__(256) bf16  g_GloT[HD * DM];      //   1 MB G^T lo
__device__ __align__(256) float g_UV [MROWS * 16];    // [l][0..7]=u_h, [8..15]=v_h
__device__ __align__(256) float g_W12[DM * 16];
__device__ __align__(256) float g_C  [HH];
__device__ __align__(256) float g_MB [Bsz * HH * Lseq];
__device__ __align__(256) float g_SC [NBT * Lseq];
__device__ __align__(256) float g_CTXP[NBT * NCHUNK * DM];  // partial P@X
__device__ __align__(256) int   g_MTOP[NBT];

__device__ __forceinline__ float ld(const float* p, size_t i) { return p[i]; }
__device__ __forceinline__ float ld(const bf16* p, size_t i) { return __bfloat162float(p[i]); }
__device__ __forceinline__ float b2f(bf16 x) { return __bfloat162float(x); }
__device__ __forceinline__ void st(float* p, size_t i, float v) { p[i] = v; }
__device__ __forceinline__ void st(bf16* p, size_t i, float v) { p[i] = __float2bfloat16(v); }
__device__ __forceinline__ short f2bf(float v) {
    union { bf16 h; short s; } u; u.h = __float2bfloat16(v); return u.s;
}

// ---------------------------------------------------------------------------
// fp32 tiled GEMM, 128x128 tile, BK=16, 8x8 per thread (embedding only).
template<typename TA, typename TC, bool GELU, bool RES>
__device__ __forceinline__ void gemm_body(
    const TA* __restrict__ A, const float* __restrict__ W,
    const float* __restrict__ bias, const float* __restrict__ res,
    TC* __restrict__ C, int K, int ldw, int ldc, int bx, int by)
{
    const int BM = 128, BN = 128, BK = 16;
    __shared__ __align__(16) float As[BK][BM + 4];
    __shared__ __align__(16) float Bs[BK][BN];
    int tid = threadIdx.x;
    int tx = tid & 15, ty = tid >> 4;
    int row0 = by * BM, col0 = bx * BN;
    float acc[8][8] = {};
    for (int k0 = 0; k0 < K; k0 += BK) {
        #pragma unroll
        for (int i = 0; i < 8; i++) {
            int idx = tid + i * 256;
            int r = idx >> 4, c = idx & 15;
            As[c][r] = ld(A, (size_t)(row0 + r) * K + k0 + c);
        }
        #pragma unroll
        for (int i = 0; i < 8; i++) {
            int idx = tid + i * 256;
            int r = idx >> 7, c = idx & 127;
            Bs[r][c] = W[(size_t)(k0 + r) * ldw + col0 + c];
        }
        __syncthreads();
        #pragma unroll
        for (int kk = 0; kk < BK; kk++) {
            float4 a0 = *(const float4*)&As[kk][ty * 8];
            float4 a1 = *(const float4*)&As[kk][ty * 8 + 4];
            float4 b0 = *(const float4*)&Bs[kk][tx * 8];
            float4 b1 = *(const float4*)&Bs[kk][tx * 8 + 4];
            float av[8] = {a0.x, a0.y, a0.z, a0.w, a1.x, a1.y, a1.z, a1.w};
            float bv[8] = {b0.x, b0.y, b0.z, b0.w, b1.x, b1.y, b1.z, b1.w};
            #pragma unroll
            for (int i = 0; i < 8; i++)
                #pragma unroll
                for (int j = 0; j < 8; j++) acc[i][j] += av[i] * bv[j];
        }
        __syncthreads();
    }
    #pragma unroll
    for (int i = 0; i < 8; i++) {
        int r = row0 + ty * 8 + i;
        #pragma unroll
        for (int j = 0; j < 8; j++) {
            int c = col0 + tx * 8 + j;
            float v = acc[i][j] + bias[c];
            if (RES) v += res[(size_t)r * ldc + c];
            if (GELU) v = 0.5f * v * (1.0f + erff(v * 0.70710678118654752440f));
            st(C, (size_t)r * ldc + c, v);
        }
    }
}

// embedding: also emits Xhi/Xlo bf16 splits for the MFMA consumers.
__global__ __launch_bounds__(256) void emb_gemm(const float* __restrict__ A,
                                                const float* __restrict__ W,
                                                const float* __restrict__ bias)
{
    const int BM = 128;
    int tid = threadIdx.x;
    gemm_body<float, float, false, false>(A, W, bias, nullptr, g_X, 32, DM, DM,
                                          blockIdx.x, blockIdx.y);
    int row0 = blockIdx.y * BM, col0 = blockIdx.x * 128;
    for (int i = 0; i < 8; i++) {
        int idx = tid + i * 256;
        int r = row0 + (idx >> 7), c = col0 + (idx & 127);
        float v = g_X[(size_t)r * DM + c];
        bf16 hi = __float2bfloat16(v);
        g_Xhi[(size_t)r * DM + c] = hi;
        g_Xlo[(size_t)r * DM + c] = __float2bfloat16(v - __bfloat162float(hi));
    }
}

// ---------------------------------------------------------------------------
// G^T_h = (Wq_h @ Wk_h^T)^T, written pre-split bf16 (hi/lo), n-major [HD][DM].
__global__ __launch_bounds__(256) void gt_gemm(const float* __restrict__ Wq,
                                               const float* __restrict__ Wk)
{
    __shared__ float Aq[16][68];
    __shared__ float Ak[16][68];
    int h = blockIdx.z;
    int jt = blockIdx.x * 64, it = blockIdx.y * 64;
    int tid = threadIdx.x, tx = tid & 15, ty = tid >> 4;
    float acc[4][4] = {};
    for (int d0 = 0; d0 < DM; d0 += 16) {
        #pragma unroll
        for (int p = 0; p < 4; p++) {
            int idx = tid + p * 256;
            int i = idx >> 4, d = idx & 15;
            Aq[d][i] = Wq[(size_t)(it + i) * HD + h * DM + d0 + d];
            Ak[d][i] = Wk[(size_t)(jt + i) * HD + h * DM + d0 + d];
        }
        __syncthreads();
        #pragma unroll
        for (int d = 0; d < 16; d++) {
            float a[4], b[4];
            #pragma unroll
            for (int p = 0; p < 4; p++) { a[p] = Aq[d][ty * 4 + p]; b[p] = Ak[d][tx * 4 + p]; }
            #pragma unroll
            for (int i2 = 0; i2 < 4; i2++)
                #pragma unroll
                for (int j2 = 0; j2 < 4; j2++) acc[i2][j2] += a[i2] * b[j2];
        }
        __syncthreads();
    }
    #pragma unroll
    for (int i2 = 0; i2 < 4; i2++)
        #pragma unroll
        for (int j2 = 0; j2 < 4; j2++) {
            float v = acc[i2][j2];
            bf16 hi = __float2bfloat16(v);
            size_t gi = (size_t)(h * DM + jt + tx * 4 + j2) * DM + (it + ty * 4 + i2);
            g_GhiT[gi] = hi;
            g_GloT[gi] = __float2bfloat16(v - __bfloat162float(hi));
        }
}

// w1[i,h]=Wq_h[i,:]·bk_h, w2[i,h]=Wk_h[i,:]·bq_h, c[h]=bq_h·bk_h. grid 8.
__global__ __launch_bounds__(256) void wc_kernel(const float* __restrict__ Wq,
                                                 const float* __restrict__ Wk,
                                                 const float* __restrict__ bq,
                                                 const float* __restrict__ bk)
{
    __shared__ float red[256];
    int h = blockIdx.x, i = threadIdx.x;
    const float4* qr  = (const float4*)(Wq + (size_t)i * HD + h * DM);
    const float4* kr  = (const float4*)(Wk + (size_t)i * HD + h * DM);
    const float4* bkr = (const float4*)(bk + h * DM);
    const float4* bqr = (const float4*)(bq + h * DM);
    float s1 = 0.f, s2 = 0.f;
    for (int j = 0; j < DM / 4; j++) {
        float4 q4 = qr[j], k4 = kr[j], b1 = bkr[j], b2 = bqr[j];
        s1 += q4.x * b1.x + q4.y * b1.y + q4.z * b1.z + q4.w * b1.w;
        s2 += k4.x * b2.x + k4.y * b2.y + k4.z * b2.z + k4.w * b2.w;
    }
    g_W12[i * 16 + h] = s1;
    g_W12[i * 16 + 8 + h] = s2;
    red[i] = bq[h * DM + i] * bk[h * DM + i];
    __syncthreads();
    for (int s = 128; s > 0; s >>= 1) { if (i < s) red[i] += red[i + s]; __syncthreads(); }
    if (i == 0) g_C[h] = red[0];
}

// u[l,h]=x_l·w1[:,h], v[l,h]=x_l·w2[:,h]. One wave per row; grid MROWS/4.
__global__ __launch_bounds__(256) void uv_kernel(int dummy)
{
    (void)dummy;
    int w = threadIdx.x >> 6, lane = threadIdx.x & 63;
    int l = blockIdx.x * 4 + w;
    float wrf[4][16];
    #pragma unroll
    for (int r = 0; r < 4; r++) {
        const float4* wp = (const float4*)(g_W12 + (size_t)(lane * 4 + r) * 16);
        float4 a = wp[0], b = wp[1], c = wp[2], d = wp[3];
        wrf[r][0]=a.x; wrf[r][1]=a.y; wrf[r][2]=a.z; wrf[r][3]=a.w;
        wrf[r][4]=b.x; wrf[r][5]=b.y; wrf[r][6]=b.z; wrf[r][7]=b.w;
        wrf[r][8]=c.x; wrf[r][9]=c.y; wrf[r][10]=c.z; wrf[r][11]=c.w;
        wrf[r][12]=d.x; wrf[r][13]=d.y; wrf[r][14]=d.z; wrf[r][15]=d.w;
    }
    float4 x4 = ((const float4*)(g_X + (size_t)l * DM))[lane];
    float xv[4] = {x4.x, x4.y, x4.z, x4.w};
    float uv[16];
    #pragma unroll
    for (int k = 0; k < 16; k++) {
        float acc = xv[0] * wrf[0][k] + xv[1] * wrf[1][k]
                  + xv[2] * wrf[2][k] + xv[3] * wrf[3][k];
        #pragma unroll
        for (int off = 32; off > 0; off >>= 1) acc += __shfl_xor(acc, off, 64);
        uv[k] = acc;
    }
    if (lane == 0) {
        float* o = g_UV + (size_t)l * 16;
        *(float4*)(o + 0)  = make_float4(uv[0], uv[1], uv[2], uv[3]);
        *(float4*)(o + 4)  = make_float4(uv[4], uv[5], uv[6], uv[7]);
        *(float4*)(o + 8)  = make_float4(uv[8], uv[9], uv[10], uv[11]);
        *(float4*)(o + 12) = make_float4(uv[12], uv[13], uv[14], uv[15]);
    }
}

// ---------------------------------------------------------------------------
// y = X @ G via bf16x3 split MFMA, SINGLE k-sweep (round-16: Xhi/Xlo/GhiT/GloT
// staged together in 40 KB LDS; r15's 3-pass version re-staged everything 3x
// and was the inferred ~55us/layer item). OUTPUT pre-split hi/lo bf16.
__global__ __launch_bounds__(256) void y_mf(int dummy)
{
    (void)dummy;
    __shared__ __align__(16) short Ah[128][40];
    __shared__ __align__(16) short Al[128][40];
    __shared__ __align__(16) short Bh[128][40];
    __shared__ __align__(16) short Bl[128][40];
    int tid = threadIdx.x;
    int wid = tid >> 6, lane = tid & 63;
    int wm = wid >> 1, wn = wid & 1;
    int quad = lane >> 4, l16 = lane & 15;
    int row0 = blockIdx.y * 128, col0 = blockIdx.x * 128;
    f32x4 acc[4][4] = {};
    for (int k0 = 0; k0 < DM; k0 += 32) {
        int r = tid >> 2, c = (tid & 3) * 8;
        #pragma unroll
        for (int p = 0; p < 2; p++) {
            int rr = r + p * 64;
            *(short8v*)&Ah[rr][c] = *(const short8v*)&((const short*)g_Xhi)[(size_t)(row0 + rr) * DM + k0 + c];
            *(short8v*)&Al[rr][c] = *(const short8v*)&((const short*)g_Xlo)[(size_t)(row0 + rr) * DM + k0 + c];
            *(short8v*)&Bh[rr][c] = *(const short8v*)&((const short*)g_GhiT)[(size_t)(col0 + rr) * DM + k0 + c];
            *(short8v*)&Bl[rr][c] = *(const short8v*)&((const short*)g_GloT)[(size_t)(col0 + rr) * DM + k0 + c];
        }
        __syncthreads();
        bf16x8 afh[4], afl[4], bfh[4], bfl[4];
        #pragma unroll
        for (int mt = 0; mt < 4; mt++) {
            afh[mt] = *(const bf16x8*)&Ah[wm * 64 + mt * 16 + l16][quad * 8];
            afl[mt] = *(const bf16x8*)&Al[wm * 64 + mt * 16 + l16][quad * 8];
        }
        #pragma unroll
        for (int nt = 0; nt < 4; nt++) {
            bfh[nt] = *(const bf16x8*)&Bh[wn * 64 + nt * 16 + l16][quad * 8];
            bfl[nt] = *(const bf16x8*)&Bl[wn * 64 + nt * 16 + l16][quad * 8];
        }
        #pragma unroll
        for (int mt = 0; mt < 4; mt++)
            #pragma unroll
            for (int nt = 0; nt < 4; nt++) {
                acc[mt][nt] = __builtin_amdgcn_mfma_f32_16x16x32_bf16(afh[mt], bfh[nt], acc[mt][nt], 0, 0, 0);
                acc[mt][nt] = __builtin_amdgcn_mfma_f32_16x16x32_bf16(afh[mt], bfl[nt], acc[mt][nt], 0, 0, 0);
                acc[mt][nt] = __builtin_amdgcn_mfma_f32_16x16x32_bf16(afl[mt], bfh[nt], acc[mt][nt], 0, 0, 0);
            }
        __syncthreads();
    }
    #pragma unroll
    for (int mt = 0; mt < 4; mt++)
        #pragma unroll
        for (int nt = 0; nt < 4; nt++) {
            int col = col0 + wn * 64 + nt * 16 + l16;
            #pragma unroll
            for (int r = 0; r < 4; r++) {
                int row = row0 + wm * 64 + mt * 16 + quad * 4 + r;
                float v = acc[mt][nt][r];
                bf16 hi = __float2bfloat16(v);
                g_Yhi[(size_t)row * HD + col] = hi;
                g_Ylo[(size_t)row * HD + col] = __float2bfloat16(v - __bfloat162float(hi));
            }
        }
}

// ---------------------------------------------------------------------------
// bf16 MFMA GEMM with RAW bf16 A (no cvt) + fp32 W cvt-staging. 128x128, BK=32.
// r13-proven template + [kbeg,kend) K-range + ATOMIC epilogue (ffn2 split-K).
template<typename TC, bool GELU, bool RES, bool ATOMIC>
__device__ __forceinline__ void mf_gemm_bfA(
    const bf16* __restrict__ A, const float* __restrict__ W,
    const float* __restrict__ bias, const float* __restrict__ res,
    TC* __restrict__ C, int K, int kbeg, int kend, int ldw, int ldc,
    int bx, int by)
{
    __shared__ __align__(16) short As[128][40];
    __shared__ __align__(16) short Bs[128][40];
    int tid = threadIdx.x;
    int wid = tid >> 6, lane = tid & 63;
    int wm = wid >> 1, wn = wid & 1;
    int quad = lane >> 4, l16 = lane & 15;
    int row0 = by * 128, col0 = bx * 128;
    f32x4 acc[4][4] = {};
    for (int k0 = kbeg; k0 < kend; k0 += 32) {
        int r = tid & 127, cb = (tid >> 7) * 8;
        #pragma unroll
        for (int i = 0; i < 2; i++) {
            int c = cb + i * 16;
            *(short8v*)&As[r][c] =
                *(const short8v*)&((const short*)A)[(size_t)(row0 + r) * K + k0 + c];
        }
        int bk = tid >> 5, bn = (tid & 31) * 4;
        #pragma unroll
        for (int i = 0; i < 4; i++) {
            int kk = bk + i * 8;
            float4 v = *(const float4*)&W[(size_t)(k0 + kk) * ldw + col0 + bn];
            Bs[bn + 0][kk] = f2bf(v.x);
            Bs[bn + 1][kk] = f2bf(v.y);
            Bs[bn + 2][kk] = f2bf(v.z);
            Bs[bn + 3][kk] = f2bf(v.w);
        }
        __syncthreads();
        bf16x8 af[4], bf_[4];
        #pragma unroll
        for (int mt = 0; mt < 4; mt++)
            af[mt] = *(const bf16x8*)&As[wm * 64 + mt * 16 + l16][quad * 8];
        #pragma unroll
        for (int nt = 0; nt < 4; nt++)
            bf_[nt] = *(const bf16x8*)&Bs[wn * 64 + nt * 16 + l16][quad * 8];
        #pragma unroll
        for (int mt = 0; mt < 4; mt++)
            #pragma unroll
            for (int nt = 0; nt < 4; nt++)
                acc[mt][nt] = __builtin_amdgcn_mfma_f32_16x16x32_bf16(
                    af[mt], bf_[nt], acc[mt][nt], 0, 0, 0);
        __syncthreads();
    }
    #pragma unroll
    for (int mt = 0; mt < 4; mt++) {
        #pragma unroll
        for (int nt = 0; nt < 4; nt++) {
            int col = col0 + wn * 64 + nt * 16 + l16;
            float bv = ATOMIC ? 0.f : bias[col];
            #pragma unroll
            for (int r = 0; r < 4; r++) {
                int row = row0 + wm * 64 + mt * 16 + quad * 4 + r;
                float v = acc[mt][nt][r] + bv;
                if (RES) v += res[(size_t)row * ldc + col];
                if (GELU) v = 0.5f * v * (1.0f + erff(v * 0.70710678118654752440f));
                if (ATOMIC) atomicAdd((float*)&C[(size_t)row * ldc + col], v);
                else st(C, (size_t)row * ldc + col, v);
            }
        }
    }
}

// FFN1: g_HFb(bf16) = gelu(Xhi @ c1W + c1b)
__global__ __launch_bounds__(256) void ffn1_mf(const float* __restrict__ W,
                                               const float* __restrict__ bias) {
    mf_gemm_bfA<bf16, true, false, false>(g_Xhi, W, bias, nullptr, g_HFb,
                                          DM, 0, DM, DFF, DFF,
                                          blockIdx.x, blockIdx.y);
}
// FFN2 split-K x4: TMP += partial(HFb @ c2W) atomically. TMP pre-init = X + c2b.
__global__ __launch_bounds__(256) void ffn2_mf(const float* __restrict__ W,
                                               const float* __restrict__ bias) {
    int kbeg = blockIdx.z * 256;
    mf_gemm_bfA<float, false, false, true>(g_HFb, W, bias, nullptr, g_TMP,
                                           DFF, kbeg, kbeg + 256, DM, DM,
                                           blockIdx.x, blockIdx.y);
}

// ---------------------------------------------------------------------------
// Sampled scores + sparsity M via MFMA. ONE WAVE per (b,l), kk-outer pipelined.
__global__ __launch_bounds__(256) void sampm_kernel(const int* __restrict__ idx)
{
    int wly = threadIdx.x >> 6, lane = threadIdx.x & 63;
    int bl = blockIdx.x * 4 + wly;        // b*Lseq + l
    int b = bl >> 11, l = bl & (Lseq - 1);
    int quad = lane >> 4, l16 = lane & 15;

    const short* yh = (const short*)g_Yhi + (size_t)bl * HD + (l16 & 7) * DM;
    const short* yl = (const short*)g_Ylo + (size_t)bl * HD + (l16 & 7) * DM;
    bf16x8 ah[8], al[8];
    #pragma unroll
    for (int kk = 0; kk < 8; kk++) {
        ah[kk] = *(const bf16x8*)&yh[kk * 32 + quad * 8];
        al[kk] = *(const bf16x8*)&yl[kk * 32 + quad * 8];
    }
    int myidx = idx[l * SK + (lane < SK ? lane : SK - 1)] & (Lseq - 1);

    const short* xh[3];
    const short* xl[3];
    float4 v4[3];
    #pragma unroll
    for (int t = 0; t < 3; t++) {
        int su = t * 16 + l16; if (su >= SK) su = SK - 1;
        int s = __shfl(myidx, su, 64);
        xh[t] = (const short*)g_Xhi + (size_t)(b * Lseq + s) * DM;
        xl[t] = (const short*)g_Xlo + (size_t)(b * Lseq + s) * DM;
        v4[t] = *(const float4*)(g_UV + (size_t)(b * Lseq + s) * 16 + 8 + (quad & 1) * 4);
    }
    f32x4 acc[3] = {};
    #pragma unroll
    for (int kk = 0; kk < 8; kk++) {
        #pragma unroll
        for (int t = 0; t < 3; t++) {
            bf16x8 bh  = *(const bf16x8*)&xh[t][kk * 32 + quad * 8];
            bf16x8 blo = *(const bf16x8*)&xl[t][kk * 32 + quad * 8];
            acc[t] = __builtin_amdgcn_mfma_f32_16x16x32_bf16(ah[kk], bh,  acc[t], 0, 0, 0);
            acc[t] = __builtin_amdgcn_mfma_f32_16x16x32_bf16(al[kk], bh,  acc[t], 0, 0, 0);
            acc[t] = __builtin_amdgcn_mfma_f32_16x16x32_bf16(ah[kk], blo, acc[t], 0, 0, 0);
        }
    }
    float mxs[4] = {-INFINITY, -INFINITY, -INFINITY, -INFINITY};
    float sms[4] = {0.f, 0.f, 0.f, 0.f};
    #pragma unroll
    for (int t = 0; t < 3; t++) {
        int u = t * 16 + l16;
        bool valid = u < SK;
        float vv[4] = {v4[t].x, v4[t].y, v4[t].z, v4[t].w};
        #pragma unroll
        for (int r = 0; r < 4; r++) {
            float sc = acc[t][r] + vv[r];
            if (valid) { mxs[r] = fmaxf(mxs[r], sc); sms[r] += sc; }
        }
    }
    #pragma unroll
    for (int off = 1; off <= 8; off <<= 1)
        #pragma unroll
        for (int r = 0; r < 4; r++) {
            mxs[r] = fmaxf(mxs[r], __shfl_xor(mxs[r], off, 64));
            sms[r] += __shfl_xor(sms[r], off, 64);
        }
    if (quad < 2 && l16 < 4) {
        int h = quad * 4 + l16;
        float mx = (l16 == 0) ? mxs[0] : (l16 == 1) ? mxs[1] : (l16 == 2) ? mxs[2] : mxs[3];
        float sm = (l16 == 0) ? sms[0] : (l16 == 1) ? sms[1] : (l16 == 2) ? sms[2] : sms[3];
        float uu = g_UV[(size_t)bl * 16 + h];
        float cc = g_C[h];
        g_MB[(size_t)(b * HH + h) * Lseq + l] =
            (mx + uu + cc) - (sm + (float)SK * (uu + cc)) * (1.0f / (float)Lseq);
    }
}

// ---------------------------------------------------------------------------
// Top-5 per (b,h): grid 32. 5 masked argmax passes (ties -> lower index).
__global__ __launch_bounds__(256) void topk_kernel(int dummy)
{
    (void)dummy;
    __shared__ float vals[Lseq];
    __shared__ float rv[256];
    __shared__ int ri[256];
    int bh = blockIdx.x, tid = threadIdx.x;
    for (int i = tid; i < Lseq; i += 256) vals[i] = g_MB[bh * Lseq + i];
    __syncthreads();
    for (int t = 0; t < NTOP; t++) {
        float bv = -INFINITY; int bi = Lseq - 1;
        for (int i = tid; i < Lseq; i += 256) {
            float v = vals[i];
            if (v > bv || (v == bv && i < bi)) { bv = v; bi = i; }
        }
        rv[tid] = bv; ri[tid] = bi;
        __syncthreads();
        for (int s = 128; s > 0; s >>= 1) {
            if (tid < s) {
                float ov = rv[tid + s]; int oi = ri[tid + s];
                if (ov > rv[tid] || (ov == rv[tid] && oi < ri[tid])) { rv[tid] = ov; ri[tid] = oi; }
            }
            __syncthreads();
        }
        if (tid == 0) { g_MTOP[bh * NTOP + t] = ri[0]; vals[ri[0] & (Lseq - 1)] = -INFINITY; }
        __syncthreads();
    }
}

// ---------------------------------------------------------------------------
// Scores for top queries via y·x + affine: grid (NBT, NCHUNK). Thread = key.
__global__ __launch_bounds__(256) void attn_scores(int dummy)
{
    (void)dummy;
    __shared__ __align__(16) float ys[DM];
    int bt = blockIdx.x, chunk = blockIdx.y, tid = threadIdx.x;
    int bh = bt / NTOP;
    int b = bh >> 3, h = bh & 7;
    int ltop = g_MTOP[bt] & (Lseq - 1);
    size_t yi = (size_t)(b * Lseq + ltop) * HD + h * DM + tid;
    ys[tid] = b2f(g_Yhi[yi]) + b2f(g_Ylo[yi]);
    __syncthreads();
    float uu = g_UV[(size_t)(b * Lseq + ltop) * 16 + h];
    float cc = g_C[h];
    int j = chunk * 256 + tid;
    const float4* xrow = (const float4*)(g_X + (size_t)(b * Lseq + j) * DM);
    float acc = 0.f;
    for (int d4 = 0; d4 < DM / 4; d4++) {
        float4 xf = xrow[d4];
        float4 yf = ((const float4*)ys)[d4];
        acc += yf.x * xf.x + yf.y * xf.y + yf.z * xf.z + yf.w * xf.w;
    }
    float vv = g_UV[(size_t)(b * Lseq + j) * 16 + 8 + h];
    g_SC[(size_t)bt * Lseq + j] = acc + uu + vv + cc;
}

// Softmax in place over g_SC row: grid NBT.
__global__ __launch_bounds__(256) void attn_softmax(int dummy)
{
    (void)dummy;
    __shared__ float sc[Lseq];
    __shared__ float red[256];
    int bt = blockIdx.x, tid = threadIdx.x;
    for (int i = tid; i < Lseq; i += 256) sc[i] = g_SC[(size_t)bt * Lseq + i];
    __syncthreads();
    float m = -INFINITY;
    for (int i = tid; i < Lseq; i += 256) m = fmaxf(m, sc[i]);
    red[tid] = m; __syncthreads();
    for (int s = 128; s > 0; s >>= 1) { if (tid < s) red[tid] = fmaxf(red[tid], red[tid + s]); __syncthreads(); }
    m = red[0]; __syncthreads();
    float sum = 0.f;
    for (int i = tid; i < Lseq; i += 256) { float e = expf(sc[i] - m); sc[i] = e; sum += e; }
    red[tid] = sum; __syncthreads();
    for (int s = 128; s > 0; s >>= 1) { if (tid < s) red[tid] += red[tid + s]; __syncthreads(); }
    float inv = 1.0f / red[0]; __syncthreads();
    for (int i = tid; i < Lseq; i += 256) g_SC[(size_t)bt * Lseq + i] = sc[i] * inv;
}

// Partial P@X over one key chunk: grid (NBT, NCHUNK). Thread = dim.
__global__ __launch_bounds__(256) void attn_ctx(int dummy)
{
    (void)dummy;
    __shared__ float ps[256];
    int bt = blockIdx.x, chunk = blockIdx.y, tid = threadIdx.x;
    int bh = bt / NTOP;
    int b = bh >> 3;
    int j0 = chunk * 256;
    ps[tid] = g_SC[(size_t)bt * Lseq + j0 + tid];
    __syncthreads();
    float accv = 0.f;
    const float* xbase = g_X + ((size_t)(b * Lseq + j0)) * DM + tid;
    for (int j = 0; j < 256; j++) accv += ps[j] * xbase[(size_t)j * DM];
    g_CTXP[((size_t)bt * NCHUNK + chunk) * DM + tid] = accv;
}

// ---------------------------------------------------------------------------
// g_TMP = g_X + broadcast(bias[DM]) — attention bo AND ffn2's c2b pre-init.
__global__ __launch_bounds__(256) void add_bias_kernel(const float* __restrict__ bo)
{
    int i = blockIdx.x * 256 + threadIdx.x;
    g_TMP[i] = g_X[i] + bo[i & (DM - 1)];
}

// Reduce PX partials; ctx = PX@Wv_h + bv_h; out = ctx@Wo_h; scatter-add.
__global__ __launch_bounds__(256) void scatter_kernel(const float* __restrict__ Wv_l,
                                                      const float* __restrict__ bv_l,
                                                      const float* __restrict__ Wo_l)
{
    __shared__ float px[DM];
    __shared__ float cs[DM];
    int bt = blockIdx.x, tid = threadIdx.x;
    int bh = bt / NTOP;
    int b = bh >> 3, h = bh & 7;
    float s = 0.f;
    #pragma unroll
    for (int c = 0; c < NCHUNK; c++) s += g_CTXP[((size_t)bt * NCHUNK + c) * DM + tid];
    px[tid] = s;
    __syncthreads();
    float acc = 0.f;
    const float* wv = Wv_l + h * DM + tid;
    for (int d = 0; d < DM; d++) acc += px[d] * wv[(size_t)d * HD];
    cs[tid] = acc + bv_l[h * DM + tid];
    __syncthreads();
    float acc2 = 0.f;
    const float* wo = Wo_l + (size_t)(h * DM) * DM + tid;
    for (int e = 0; e < DM; e++) acc2 += cs[e] * wo[(size_t)e * DM];
    int row = g_MTOP[bt] & (Lseq - 1);
    atomicAdd(&g_TMP[((size_t)(b * Lseq) + row) * DM + tid], acc2);
}

// ---------------------------------------------------------------------------
// LayerNorm g_TMP -> g_X (+ Xhi/Xlo bf16 splits), one wave per row of 256.
__global__ __launch_bounds__(256) void ln_kernel(const float* __restrict__ g,
                                                 const float* __restrict__ bb)
{
    int wid = blockIdx.x * 4 + (threadIdx.x >> 6);
    if (wid >= MROWS) return;
    int lane = threadIdx.x & 63;
    const float4* row = (const float4*)(g_TMP + (size_t)wid * DM);
    float4 v = row[lane];
    float s = v.x + v.y + v.z + v.w;
    #pragma unroll
    for (int off = 32; off > 0; off >>= 1) s += __shfl_down(s, off, 64);
    s = __shfl(s, 0, 64);
    float mean = s * (1.f / DM);
    float4 d = {v.x - mean, v.y - mean, v.z - mean, v.w - mean};
    float q = d.x * d.x + d.y * d.y + d.z * d.z + d.w * d.w;
    #pragma unroll
    for (int off = 32; off > 0; off >>= 1) q += __shfl_down(q, off, 64);
    q = __shfl(q, 0, 64);
    float inv = rsqrtf(q * (1.f / DM) + 1e-5f);
    int c = lane * 4;
    float4 o;
    o.x = d.x * inv * g[c + 0] + bb[c + 0];
    o.y = d.y * inv * g[c + 1] + bb[c + 1];
    o.z = d.z * inv * g[c + 2] + bb[c + 2];
    o.w = d.w * inv * g[c + 3] + bb[c + 3];
    ((float4*)(g_X + (size_t)wid * DM))[lane] = o;
    float ov[4] = {o.x, o.y, o.z, o.w};
    short hi[4], lo[4];
    #pragma unroll
    for (int t = 0; t < 4; t++) {
        bf16 hb = __float2bfloat16(ov[t]);
        hi[t] = *(short*)&hb;
        bf16 lb = __float2bfloat16(ov[t] - __bfloat162float(hb));
        lo[t] = *(short*)&lb;
    }
    *(short4*)((short*)g_Xhi + (size_t)wid * DM + c) = make_short4(hi[0], hi[1], hi[2], hi[3]);
    *(short4*)((short*)g_Xlo + (size_t)wid * DM + c) = make_short4(lo[0], lo[1], lo[2], lo[3]);
}

// ---------------------------------------------------------------------------
__global__ __launch_bounds__(256) void final_kernel(
    const float* __restrict__ g, const float* __restrict__ bb,
    const float* __restrict__ pw, const float* __restrict__ pb,
    float* __restrict__ out)
{
    __shared__ float red[256];
    int b = blockIdx.x, tid = threadIdx.x;
    const float* row = g_X + ((size_t)(b * Lseq + Lseq - 1)) * DM;
    float v = row[tid];
    red[tid] = v; __syncthreads();
    for (int s = 128; s > 0; s >>= 1) { if (tid < s) red[tid] += red[tid + s]; __syncthreads(); }
    float mean = red[0] * (1.f / DM); __syncthreads();
    float d = v - mean;
    red[tid] = d * d; __syncthreads();
    for (int s = 128; s > 0; s >>= 1) { if (tid < s) red[tid] += red[tid + s]; __syncthreads(); }
    float var = red[0] * (1.f / DM); __syncthreads();
    float xn = d * rsqrtf(var + 1e-5f) * g[tid] + bb[tid];
    red[tid] = xn * pw[tid]; __syncthreads();
    for (int s = 128; s > 0; s >>= 1) { if (tid < s) red[tid] += red[tid + s]; __syncthreads(); }
    if (tid == 0) out[b] = red[0] + pb[0];
}

// ---------------------------------------------------------------------------
extern "C" void kernel_launch(void* const* d_in, const int* in_sizes, int n_in,
                              void* d_out, int out_size, void* d_ws, size_t ws_size,
                              hipStream_t stream)
{
    const float* x_enc = (const float*)d_in[0];
    const int*   isamp = (const int*)d_in[1];
    const float* emb_W = (const float*)d_in[2];
    const float* emb_b = (const float*)d_in[3];
    const float* Wq = (const float*)d_in[4];
    const float* bq = (const float*)d_in[5];
    const float* Wk = (const float*)d_in[6];
    const float* bk = (const float*)d_in[7];
    const float* Wv = (const float*)d_in[8];
    const float* bv = (const float*)d_in[9];
    const float* Wo = (const float*)d_in[10];
    const float* bo = (const float*)d_in[11];
    const float* c1W = (const float*)d_in[12];
    const float* c1b = (const float*)d_in[13];
    const float* c2W = (const float*)d_in[14];
    const float* c2b = (const float*)d_in[15];
    const float* ln1g = (const float*)d_in[16];
    const float* ln1b = (const float*)d_in[17];
    const float* ln2g = (const float*)d_in[18];
    const float* ln2b = (const float*)d_in[19];
    const float* nfg  = (const float*)d_in[20];
    const float* nfb  = (const float*)d_in[21];
    const float* projW = (const float*)d_in[22];
    const float* projb = (const float*)d_in[23];
    (void)d_ws; (void)ws_size; (void)in_sizes; (void)n_in; (void)out_size;

    dim3 blk(256);
    emb_gemm<<<dim3(DM / 128, MROWS / 128), blk, 0, stream>>>(x_enc, emb_W, emb_b);

    for (int l = 0; l < 2; l++) {
        const float* Wq_l = Wq + (size_t)l * DM * HD;
        const float* Wk_l = Wk + (size_t)l * DM * HD;
        const float* Wv_l = Wv + (size_t)l * DM * HD;
        const float* Wo_l = Wo + (size_t)l * HD * DM;

        gt_gemm<<<dim3(4, 4, 8), blk, 0, stream>>>(Wq_l, Wk_l);
        wc_kernel<<<dim3(HH), blk, 0, stream>>>(Wq_l, Wk_l, bq + l * HD, bk + l * HD);
        y_mf<<<dim3(HD / 128, MROWS / 128), blk, 0, stream>>>(0);
        uv_kernel<<<dim3(MROWS / 4), blk, 0, stream>>>(0);

        sampm_kernel<<<dim3(MROWS / 4), blk, 0, stream>>>(isamp);
        topk_kernel<<<dim3(Bsz * HH), blk, 0, stream>>>(0);

        attn_scores<<<dim3(NBT, NCHUNK), blk, 0, stream>>>(0);
        attn_softmax<<<dim3(NBT), blk, 0, stream>>>(0);
        attn_ctx<<<dim3(NBT, NCHUNK), blk, 0, stream>>>(0);

        add_bias_kernel<<<dim3(MROWS), blk, 0, stream>>>(bo + l * DM);
        scatter_kernel<<<dim3(NBT), blk, 0, stream>>>(Wv_l, bv + l * HD, Wo_l);
        ln_kernel<<<dim3(MROWS / 4), blk, 0, stream>>>(ln1g + l * DM, ln1b + l * DM);

        ffn1_mf<<<dim3(DFF / 128, MROWS / 128), blk, 0, stream>>>(
            c1W + (size_t)l * DM * DFF, c1b + l * DFF);
        add_bias_kernel<<<dim3(MROWS), blk, 0, stream>>>(c2b + l * DM);  // TMP = X + c2b
        ffn2_mf<<<dim3(DM / 128, MROWS / 128, 4), blk, 0, stream>>>(
            c2W + (size_t)l * DFF * DM, c2b + l * DM);
        ln_kernel<<<dim3(MROWS / 4), blk, 0, stream>>>(ln2g + l * DM, ln2b + l * DM);
    }

    final_kernel<<<dim3(Bsz), blk, 0, stream>>>(nfg, nfb, projW, projb, (float*)d_out);
}